// Round 1
// baseline (22994.330 us; speedup 1.0000x reference)
//
#include <hip/hip_runtime.h>
#include <math.h>

#define B_   8
#define L_   512
#define MTOK 4096           // B_*L_
#define D_   768
#define NH_  12
#define DH_  64
#define DFF_ 3072
#define NL_  12

// ---------------------------------------------------------------------------
// box sinusoid embedding: out[t, c*192 + 2j + s] = s? sin : cos (box[t,c]*theta_j)
// theta_j = 10000^(-j/96)
__global__ void k_box_sin(float* __restrict__ out, const float* __restrict__ box) {
    int idx = blockIdx.x * blockDim.x + threadIdx.x;
    if (idx >= MTOK * D_) return;
    int t = idx / D_, d = idx % D_;
    int c = d / 192, r = d % 192, j = r >> 1;
    float theta = expf(-(float)j * (9.210340371976184f / 96.0f)); // ln(1e4)/96
    float ang = box[t * 4 + c] * theta;
    out[idx] = (r & 1) ? sinf(ang) : cosf(ang);
}

// ---------------------------------------------------------------------------
// RMSNorm: one block (256 thr) per token
__global__ __launch_bounds__(256) void k_rmsnorm(float* __restrict__ out,
                                                 const float* __restrict__ in,
                                                 const float* __restrict__ w) {
    int t = blockIdx.x;
    const float* x = in + (size_t)t * D_;
    float ss = 0.f;
    for (int i = threadIdx.x; i < D_; i += 256) { float v = x[i]; ss += v * v; }
    for (int off = 32; off > 0; off >>= 1) ss += __shfl_down(ss, off);
    __shared__ float red[4];
    int wid = threadIdx.x >> 6, lane = threadIdx.x & 63;
    if (lane == 0) red[wid] = ss;
    __syncthreads();
    float tot = red[0] + red[1] + red[2] + red[3];
    float inv = rsqrtf(tot / (float)D_ + 1e-6f);
    for (int i = threadIdx.x; i < D_; i += 256)
        out[(size_t)t * D_ + i] = x[i] * inv * w[i];
}

// ---------------------------------------------------------------------------
// RoPE in place on a (MTOK, 768) buffer viewed as (b, l, 12 heads, 64)
__global__ void k_rope(float* __restrict__ x) {
    int idx = blockIdx.x * blockDim.x + threadIdx.x;  // over MTOK * 384 pairs
    if (idx >= MTOK * (D_ / 2)) return;
    int t = idx / (D_ / 2);
    int r = idx % (D_ / 2);
    int head = r / 32, j = r % 32;
    int l = t % L_;
    float theta = expf(-(float)j * (9.210340371976184f / 32.0f)); // 1e4^(-j/32)
    float ang = (float)l * theta;
    float s, c;
    sincosf(ang, &s, &c);
    size_t base = (size_t)t * D_ + head * 64 + 2 * j;
    float xr = x[base], xi = x[base + 1];
    x[base]     = xr * c - xi * s;
    x[base + 1] = xr * s + xi * c;
}

// ---------------------------------------------------------------------------
// Tiled fp32 GEMM: C[M,N] (ld=N) = A[M,K] @ B[K,N], guarded on N.
// MODE 0: C = acc (+bias)   MODE 1: C += acc (+bias)   MODE 2: C = silu(C)*acc
// M multiple of 64, K multiple of 16 (true for all call sites).
template <int MODE>
__global__ __launch_bounds__(256) void k_gemm(float* __restrict__ C,
                                              const float* __restrict__ A,
                                              const float* __restrict__ Bm,
                                              const float* __restrict__ bias,
                                              int M, int N, int K) {
    __shared__ float As[16][68];   // A^T tile: As[k][m], padded stride 68
    __shared__ float Bs[16][68];   // Bs[k][n]
    int tid = threadIdx.x;
    int row0 = blockIdx.y * 64, col0 = blockIdx.x * 64;
    int ty = tid / 16, tx = tid % 16;

    int ar = tid / 4;            // 0..63 (A row within tile)
    int ac = (tid % 4) * 4;      // 0,4,8,12 (A col within k-tile)
    int br = tid / 16;           // 0..15 (B row within k-tile)
    int bc = (tid % 16) * 4;     // 0..60 (B col within tile)

    float acc[4][4] = {};
    for (int kt = 0; kt < K; kt += 16) {
        const float* ap = A + (size_t)(row0 + ar) * K + kt + ac;
        float4 av = *reinterpret_cast<const float4*>(ap);
        As[ac + 0][ar] = av.x; As[ac + 1][ar] = av.y;
        As[ac + 2][ar] = av.z; As[ac + 3][ar] = av.w;

        int gb = col0 + bc;
        const float* bp = Bm + (size_t)(kt + br) * N + gb;
        if (gb + 3 < N) {
            float4 bv = *reinterpret_cast<const float4*>(bp);
            Bs[br][bc] = bv.x; Bs[br][bc + 1] = bv.y;
            Bs[br][bc + 2] = bv.z; Bs[br][bc + 3] = bv.w;
        } else {
            #pragma unroll
            for (int j = 0; j < 4; ++j)
                Bs[br][bc + j] = (gb + j < N) ? bp[j] : 0.0f;
        }
        __syncthreads();
        #pragma unroll
        for (int k = 0; k < 16; ++k) {
            float4 a4 = *reinterpret_cast<const float4*>(&As[k][ty * 4]);
            float4 b4 = *reinterpret_cast<const float4*>(&Bs[k][tx * 4]);
            float a[4] = {a4.x, a4.y, a4.z, a4.w};
            float b[4] = {b4.x, b4.y, b4.z, b4.w};
            #pragma unroll
            for (int i = 0; i < 4; ++i)
                #pragma unroll
                for (int j = 0; j < 4; ++j) acc[i][j] += a[i] * b[j];
        }
        __syncthreads();
    }
    #pragma unroll
    for (int i = 0; i < 4; ++i) {
        int m = row0 + ty * 4 + i;
        #pragma unroll
        for (int j = 0; j < 4; ++j) {
            int n = col0 + tx * 4 + j;
            if (n < N) {
                float v = acc[i][j];
                if (bias) v += bias[n];
                size_t off = (size_t)m * N + n;
                if (MODE == 0)      C[off] = v;
                else if (MODE == 1) C[off] += v;
                else {
                    float g = C[off];
                    C[off] = (g / (1.0f + expf(-g))) * v;
                }
            }
        }
    }
}

// ---------------------------------------------------------------------------
// Causal attention, one wave per (query row, batch*head).
// q,k,v: (MTOK, 768) with head hh at cols [hh*64, hh*64+64). o: same layout.
__global__ __launch_bounds__(64) void k_attn(float* __restrict__ o,
                                             const float* __restrict__ q,
                                             const float* __restrict__ k,
                                             const float* __restrict__ v) {
    int l  = blockIdx.x;          // query position 0..511
    int bh = blockIdx.y;          // b*12 + h
    int b  = bh / NH_, hh = bh % NH_;
    int lane = threadIdx.x;

    __shared__ float qs[DH_];
    __shared__ float sc[L_];

    size_t rowq = ((size_t)(b * L_ + l)) * D_ + hh * DH_;
    qs[lane] = q[rowq + lane];
    __syncthreads();

    for (int m = lane; m <= l; m += 64) {
        const float* kr = k + ((size_t)(b * L_ + m)) * D_ + hh * DH_;
        float s = 0.f;
        #pragma unroll
        for (int d = 0; d < DH_; ++d) s += qs[d] * kr[d];
        sc[m] = s * 0.125f;       // / sqrt(64)
    }
    __syncthreads();

    float mx = -INFINITY;
    for (int m = lane; m <= l; m += 64) mx = fmaxf(mx, sc[m]);
    #pragma unroll
    for (int msk = 32; msk; msk >>= 1) mx = fmaxf(mx, __shfl_xor(mx, msk));

    float sum = 0.f;
    for (int m = lane; m <= l; m += 64) {
        float e = expf(sc[m] - mx);
        sc[m] = e;
        sum += e;
    }
    #pragma unroll
    for (int msk = 32; msk; msk >>= 1) sum += __shfl_xor(sum, msk);
    __syncthreads();

    float inv = 1.0f / sum;
    float acc = 0.f;
    for (int m = 0; m <= l; ++m)
        acc += sc[m] * v[((size_t)(b * L_ + m)) * D_ + hh * DH_ + lane];
    o[rowq + lane] = acc * inv;
}

// ---------------------------------------------------------------------------
extern "C" void kernel_launch(void* const* d_in, const int* in_sizes, int n_in,
                              void* d_out, int out_size, void* d_ws, size_t ws_size,
                              hipStream_t stream) {
    const float* patch        = (const float*)d_in[0];
    const float* box          = (const float*)d_in[1];
    const float* patch_W      = (const float*)d_in[2];
    const float* patch_b      = (const float*)d_in[3];
    const float* box_W        = (const float*)d_in[4];
    const float* box_b        = (const float*)d_in[5];
    const float* Wq           = (const float*)d_in[6];
    const float* Wk           = (const float*)d_in[7];
    const float* Wv           = (const float*)d_in[8];
    const float* Wo           = (const float*)d_in[9];
    const float* attn_norm_w  = (const float*)d_in[10];
    const float* gate_W       = (const float*)d_in[11];
    const float* hidden_W     = (const float*)d_in[12];
    const float* ffn_out_W    = (const float*)d_in[13];
    const float* ffn_norm_w   = (const float*)d_in[14];
    const float* reward_norm_w= (const float*)d_in[15];
    const float* reward_W     = (const float*)d_in[16];
    const float* reward_b     = (const float*)d_in[17];
    const float* label_norm_w = (const float*)d_in[18];
    const float* label_W      = (const float*)d_in[19];
    const float* label_b      = (const float*)d_in[20];
    const float* box_norm_w   = (const float*)d_in[21];
    const float* boxh_W       = (const float*)d_in[22];
    const float* boxh_b       = (const float*)d_in[23];

    const size_t TD = (size_t)MTOK * D_;          // 3,145,728
    float* ws = (float*)d_ws;
    float* h    = ws;
    float* hn   = h + TD;
    float* q    = hn + TD;
    float* kk   = q + TD;
    float* v    = kk + TD;
    float* o    = v + TD;
    float* gate = o + TD;                          // MTOK * DFF_

    dim3 blk(256);
    dim3 g768((D_ + 63) / 64, MTOK / 64);          // (12, 64)
    dim3 g3072((DFF_ + 63) / 64, MTOK / 64);       // (48, 64)

    // ---- embedding: x = patch@patch_W + patch_b + box_sin@box_W + box_b
    k_box_sin<<<(MTOK * D_ + 255) / 256, blk, 0, stream>>>(q, box);
    k_gemm<0><<<g768, blk, 0, stream>>>(h, patch, patch_W, patch_b, MTOK, D_, D_);
    k_gemm<1><<<g768, blk, 0, stream>>>(h, q, box_W, box_b, MTOK, D_, D_);

    // ---- transformer layers
    for (int ly = 0; ly < NL_; ++ly) {
        const float* wq  = Wq + (size_t)ly * D_ * D_;
        const float* wk  = Wk + (size_t)ly * D_ * D_;
        const float* wv  = Wv + (size_t)ly * D_ * D_;
        const float* wo  = Wo + (size_t)ly * D_ * D_;
        const float* anw = attn_norm_w + (size_t)ly * D_;
        const float* gw  = gate_W + (size_t)ly * D_ * DFF_;
        const float* hw  = hidden_W + (size_t)ly * D_ * DFF_;
        const float* ow  = ffn_out_W + (size_t)ly * DFF_ * D_;
        const float* fnw = ffn_norm_w + (size_t)ly * D_;

        k_rmsnorm<<<MTOK, blk, 0, stream>>>(hn, h, anw);
        k_gemm<0><<<g768, blk, 0, stream>>>(q,  hn, wq, nullptr, MTOK, D_, D_);
        k_gemm<0><<<g768, blk, 0, stream>>>(kk, hn, wk, nullptr, MTOK, D_, D_);
        k_gemm<0><<<g768, blk, 0, stream>>>(v,  hn, wv, nullptr, MTOK, D_, D_);
        k_rope<<<(MTOK * (D_ / 2) + 255) / 256, blk, 0, stream>>>(q);
        k_rope<<<(MTOK * (D_ / 2) + 255) / 256, blk, 0, stream>>>(kk);
        {
            dim3 ga(L_, B_ * NH_);
            k_attn<<<ga, dim3(64), 0, stream>>>(o, q, kk, v);
        }
        k_gemm<1><<<g768, blk, 0, stream>>>(h, o, wo, nullptr, MTOK, D_, D_);

        k_rmsnorm<<<MTOK, blk, 0, stream>>>(hn, h, fnw);
        k_gemm<0><<<g3072, blk, 0, stream>>>(gate, hn, gw, nullptr, MTOK, DFF_, D_);
        k_gemm<2><<<g3072, blk, 0, stream>>>(gate, hn, hw, nullptr, MTOK, DFF_, D_); // gate = silu(gate)*hidden
        k_gemm<1><<<g768, blk, 0, stream>>>(h, gate, ow, nullptr, MTOK, D_, DFF_);
    }

    // ---- heads
    float* out_reward = (float*)d_out;                       // (MTOK, 2)
    float* out_label  = out_reward + (size_t)MTOK * 2;       // (MTOK, 1000)
    float* out_box    = out_label + (size_t)MTOK * 1000;     // (MTOK, 4)

    k_rmsnorm<<<MTOK, blk, 0, stream>>>(hn, h, reward_norm_w);
    k_gemm<0><<<dim3(1, MTOK / 64), blk, 0, stream>>>(out_reward, hn, reward_W, reward_b, MTOK, 2, D_);

    k_rmsnorm<<<MTOK, blk, 0, stream>>>(hn, h, label_norm_w);
    k_gemm<0><<<dim3(16, MTOK / 64), blk, 0, stream>>>(out_label, hn, label_W, label_b, MTOK, 1000, D_);

    k_rmsnorm<<<MTOK, blk, 0, stream>>>(hn, h, box_norm_w);
    k_gemm<0><<<dim3(1, MTOK / 64), blk, 0, stream>>>(out_box, hn, boxh_W, boxh_b, MTOK, 4, D_);
}

// Round 2
// 9506.008 us; speedup vs baseline: 2.4189x; 2.4189x over previous
//
#include <hip/hip_runtime.h>
#include <math.h>
#include <type_traits>

#define B_   8
#define L_   512
#define MTOK 4096           // B_*L_
#define D_   768
#define NH_  12
#define DH_  64
#define DFF_ 3072
#define NL_  12

typedef unsigned short u16;
typedef __attribute__((ext_vector_type(4))) float f32x4;
typedef __attribute__((ext_vector_type(8))) short i16x8;
typedef __attribute__((ext_vector_type(8))) __bf16 b16x8;

// Pick whichever vector type the gfx950 bf16 MFMA builtin accepts.
template <typename A, typename = void>
struct PickFrag { using type = i16x8; };
template <typename A>
struct PickFrag<A, std::void_t<decltype(__builtin_amdgcn_mfma_f32_16x16x32_bf16(
    std::declval<A>(), std::declval<A>(), std::declval<f32x4>(), 0, 0, 0))>> {
  using type = A;
};
using frag_t = typename PickFrag<b16x8>::type;

__device__ inline u16 f2bf(float f) {
    unsigned u = __float_as_uint(f);
    unsigned r = u + 0x7fffu + ((u >> 16) & 1u);
    return (u16)(r >> 16);
}
__device__ inline float bf2f(u16 b) { return __uint_as_float(((unsigned)b) << 16); }

// ---------------------------------------------------------------------------
// box sinusoid embedding -> bf16
__global__ void k_box_sin(u16* __restrict__ out, const float* __restrict__ box) {
    int idx = blockIdx.x * blockDim.x + threadIdx.x;
    if (idx >= MTOK * D_) return;
    int t = idx / D_, d = idx % D_;
    int c = d / 192, r = d % 192, j = r >> 1;
    float theta = __expf(-(float)j * (9.210340371976184f / 96.0f));
    float ang = box[t * 4 + c] * theta;
    out[idx] = f2bf((r & 1) ? sinf(ang) : cosf(ang));
}

// fp32 -> bf16 cast, 4 elems/thread
__global__ void k_cast(u16* __restrict__ out, const float* __restrict__ in, int n4) {
    int i = blockIdx.x * blockDim.x + threadIdx.x;
    if (i >= n4) return;
    float4 v = *reinterpret_cast<const float4*>(in + (size_t)i * 4);
    unsigned lo = (unsigned)f2bf(v.x) | ((unsigned)f2bf(v.y) << 16);
    unsigned hi = (unsigned)f2bf(v.z) | ((unsigned)f2bf(v.w) << 16);
    *reinterpret_cast<uint2*>(out + (size_t)i * 4) = make_uint2(lo, hi);
}

// ---------------------------------------------------------------------------
// transpose-convert: src (K,N) fp32 -> dst (Npad,K) bf16, zero rows n>=N
__global__ __launch_bounds__(256) void k_convT(u16* __restrict__ dst,
                                               const float* __restrict__ src,
                                               int K, int N, int Npad) {
    __shared__ float t[32][33];
    int bn = blockIdx.x * 32;
    int bk = blockIdx.y * 32;
    int tx = threadIdx.x % 32, ty = threadIdx.x / 32;
    #pragma unroll
    for (int i = 0; i < 4; ++i) {
        int k = bk + ty + i * 8;
        int n = bn + tx;
        t[ty + i * 8][tx] = (n < N) ? src[(size_t)k * N + n] : 0.0f;
    }
    __syncthreads();
    #pragma unroll
    for (int i = 0; i < 4; ++i) {
        int n = bn + ty + i * 8;   // dst row
        int k = bk + tx;           // dst col
        dst[(size_t)n * K + k] = f2bf(t[tx][ty + i * 8]);
    }
}

// ---------------------------------------------------------------------------
// RMSNorm: one block per token; OT = float or u16(bf16)
template <typename OT>
__global__ __launch_bounds__(256) void k_rmsnorm(OT* __restrict__ out,
                                                 const float* __restrict__ in,
                                                 const float* __restrict__ w) {
    int t = blockIdx.x;
    const float* x = in + (size_t)t * D_;
    float ss = 0.f;
    for (int i = threadIdx.x; i < D_; i += 256) { float v = x[i]; ss += v * v; }
    for (int off = 32; off > 0; off >>= 1) ss += __shfl_down(ss, off);
    __shared__ float red[4];
    int wid = threadIdx.x >> 6, lane = threadIdx.x & 63;
    if (lane == 0) red[wid] = ss;
    __syncthreads();
    float tot = red[0] + red[1] + red[2] + red[3];
    float inv = rsqrtf(tot / (float)D_ + 1e-6f);
    for (int i = threadIdx.x; i < D_; i += 256) {
        float v = x[i] * inv * w[i];
        if constexpr (std::is_same_v<OT, u16>) out[(size_t)t * D_ + i] = f2bf(v);
        else                                   out[(size_t)t * D_ + i] = v;
    }
}

// ---------------------------------------------------------------------------
// RoPE in place on qkv (MTOK, 2304): q cols 0..767, k cols 768..1535
__global__ void k_rope2(float* __restrict__ qkv) {
    int idx = blockIdx.x * blockDim.x + threadIdx.x;   // MTOK * 768 pairs
    if (idx >= MTOK * 768) return;
    int t = idx / 768, r = idx % 768;
    int head = r / 32, j = r % 32;                     // head 0..23
    int l = t % L_;
    float theta = __expf(-(float)j * (9.210340371976184f / 32.0f));
    float s, c;
    sincosf((float)l * theta, &s, &c);
    size_t base = (size_t)t * 2304 + head * 64 + 2 * j;
    float xr = qkv[base], xi = qkv[base + 1];
    qkv[base]     = xr * c - xi * s;
    qkv[base + 1] = xr * s + xi * c;
}

// ---------------------------------------------------------------------------
// bf16 MFMA GEMM: C[M x Nout](ldC) (+)= A[M,K]bf16 @ BT[Nt,K]bf16^T (+bias)
// grid = (Nt/128, M/128), 256 threads. MODE 0: C=acc(+bias) f32
// MODE 1: C+=acc(+bias) f32   MODE 3: C=acc bf16
template <int MODE>
__global__ __launch_bounds__(256) void k_gemm_bf16(void* __restrict__ Cp,
                                                   const u16* __restrict__ A,
                                                   const u16* __restrict__ BT,
                                                   const float* __restrict__ bias,
                                                   int K, int Nout, int ldC) {
    __shared__ u16 As[128 * 32];
    __shared__ u16 Bs[128 * 32];
    int tid = threadIdx.x;
    int wid = tid >> 6, lane = tid & 63;
    int row0 = blockIdx.y * 128, col0 = blockIdx.x * 128;
    int wr = wid >> 1, wc = wid & 1;

    f32x4 acc[4][4] = {};

    int lrow = lane & 15, lk = (lane >> 4) * 8;

    for (int kt = 0; kt < K; kt += 32) {
        #pragma unroll
        for (int c = 0; c < 2; ++c) {
            int chunk = tid + c * 256;          // 0..511
            int r = chunk >> 2;                 // tile row
            int kc = (chunk & 3) * 8;           // k elem offset
            uint4 av = *reinterpret_cast<const uint4*>(A + (size_t)(row0 + r) * K + kt + kc);
            *reinterpret_cast<uint4*>(&As[chunk * 8]) = av;
            uint4 bv = *reinterpret_cast<const uint4*>(BT + (size_t)(col0 + r) * K + kt + kc);
            *reinterpret_cast<uint4*>(&Bs[chunk * 8]) = bv;
        }
        __syncthreads();
        frag_t af[4], bfr[4];
        #pragma unroll
        for (int m = 0; m < 4; ++m)
            af[m] = *reinterpret_cast<const frag_t*>(&As[(wr * 64 + m * 16 + lrow) * 32 + lk]);
        #pragma unroll
        for (int n = 0; n < 4; ++n)
            bfr[n] = *reinterpret_cast<const frag_t*>(&Bs[(wc * 64 + n * 16 + lrow) * 32 + lk]);
        #pragma unroll
        for (int m = 0; m < 4; ++m)
            #pragma unroll
            for (int n = 0; n < 4; ++n)
                acc[m][n] = __builtin_amdgcn_mfma_f32_16x16x32_bf16(af[m], bfr[n], acc[m][n], 0, 0, 0);
        __syncthreads();
    }

    int lcol = lane & 15, rb = (lane >> 4) * 4;
    #pragma unroll
    for (int m = 0; m < 4; ++m) {
        #pragma unroll
        for (int n = 0; n < 4; ++n) {
            int col = col0 + wc * 64 + n * 16 + lcol;
            if (col >= Nout) continue;
            #pragma unroll
            for (int e = 0; e < 4; ++e) {
                int row = row0 + wr * 64 + m * 16 + rb + e;
                float v = acc[m][n][e];
                size_t off = (size_t)row * ldC + col;
                if (MODE == 0) {
                    if (bias) v += bias[col];
                    ((float*)Cp)[off] = v;
                } else if (MODE == 1) {
                    if (bias) v += bias[col];
                    ((float*)Cp)[off] += v;
                } else {
                    ((u16*)Cp)[off] = f2bf(v);
                }
            }
        }
    }
}

// ---------------------------------------------------------------------------
// silu-mul: out[t,j] = bf16( silu(gh[t,j]) * gh[t,3072+j] ), gh (MTOK,6144) bf16
__global__ void k_silu(u16* __restrict__ out, const u16* __restrict__ gh) {
    int idx = blockIdx.x * blockDim.x + threadIdx.x;    // MTOK*3072/8
    if (idx >= MTOK * DFF_ / 8) return;
    int t = idx / 384, j8 = (idx % 384) * 8;
    uint4 g4 = *reinterpret_cast<const uint4*>(gh + (size_t)t * 6144 + j8);
    uint4 h4 = *reinterpret_cast<const uint4*>(gh + (size_t)t * 6144 + 3072 + j8);
    const u16* gu = reinterpret_cast<const u16*>(&g4);
    const u16* hu = reinterpret_cast<const u16*>(&h4);
    u16 r[8];
    #pragma unroll
    for (int e = 0; e < 8; ++e) {
        float g = bf2f(gu[e]), hv = bf2f(hu[e]);
        float s = g / (1.0f + __expf(-g));
        r[e] = f2bf(s * hv);
    }
    *reinterpret_cast<uint4*>(out + (size_t)t * DFF_ + j8) = *reinterpret_cast<uint4*>(r);
}

// ---------------------------------------------------------------------------
// Tiled attention: grid (96 bh, 8 qblocks), 256 thr. 16 q-rows per wave.
// qkv (MTOK,2304) fp32: q@0, k@768, v@1536. out o bf16 (MTOK,768).
__global__ __launch_bounds__(256) void k_attn2(u16* __restrict__ o,
                                               const float* __restrict__ qkv) {
    int bh = blockIdx.x, qb = blockIdx.y;
    int b = bh / NH_, hh = bh % NH_;
    int tid = threadIdx.x, wid = tid >> 6, lane = tid & 63;
    __shared__ float Qs[64][68];          // stride 68 -> 16B-aligned rows
    __shared__ float Ks[64][65], Vs[64][65];
    const size_t base = (size_t)(b * L_) * 2304 + hh * 64;

    #pragma unroll
    for (int i = 0; i < 4; ++i) {
        int idx = tid + i * 256;
        int r = idx >> 4, c4 = (idx & 15) << 2;
        float4 v4 = *reinterpret_cast<const float4*>(qkv + base + (size_t)(qb * 64 + r) * 2304 + c4);
        Qs[r][c4] = v4.x; Qs[r][c4 + 1] = v4.y; Qs[r][c4 + 2] = v4.z; Qs[r][c4 + 3] = v4.w;
    }

    float acc[16], Mr[16], Sr[16];
    #pragma unroll
    for (int r = 0; r < 16; ++r) { acc[r] = 0.f; Mr[r] = -INFINITY; Sr[r] = 0.f; }

    for (int kb = 0; kb <= qb; ++kb) {
        __syncthreads();
        #pragma unroll
        for (int i = 0; i < 4; ++i) {
            int idx = tid + i * 256;
            int r = idx >> 4, c4 = (idx & 15) << 2;
            float4 kv = *reinterpret_cast<const float4*>(qkv + base + 768 + (size_t)(kb * 64 + r) * 2304 + c4);
            Ks[r][c4] = kv.x; Ks[r][c4 + 1] = kv.y; Ks[r][c4 + 2] = kv.z; Ks[r][c4 + 3] = kv.w;
            float4 vv = *reinterpret_cast<const float4*>(qkv + base + 1536 + (size_t)(kb * 64 + r) * 2304 + c4);
            Vs[r][c4] = vv.x; Vs[r][c4 + 1] = vv.y; Vs[r][c4 + 2] = vv.z; Vs[r][c4 + 3] = vv.w;
        }
        __syncthreads();
        bool diag = (kb == qb);
        #pragma unroll
        for (int r = 0; r < 16; ++r) {
            int qr = wid * 16 + r;
            float s = 0.f;
            #pragma unroll 8
            for (int d = 0; d < 64; d += 4) {
                float4 qv = *reinterpret_cast<const float4*>(&Qs[qr][d]);  // broadcast
                s = fmaf(qv.x, Ks[lane][d],     s);
                s = fmaf(qv.y, Ks[lane][d + 1], s);
                s = fmaf(qv.z, Ks[lane][d + 2], s);
                s = fmaf(qv.w, Ks[lane][d + 3], s);
            }
            s *= 0.125f;
            bool valid = !diag || (lane <= qr);
            s = valid ? s : -INFINITY;
            float mx = s;
            #pragma unroll
            for (int off = 32; off; off >>= 1) mx = fmaxf(mx, __shfl_xor(mx, off));
            float newM = fmaxf(Mr[r], mx);
            float p = valid ? __expf(s - newM) : 0.f;
            float ps = p;
            #pragma unroll
            for (int off = 32; off; off >>= 1) ps += __shfl_xor(ps, off);
            float scale = __expf(Mr[r] - newM);
            Sr[r] = Sr[r] * scale + ps;
            Mr[r] = newM;
            float a = acc[r] * scale;
            #pragma unroll 16
            for (int m = 0; m < 64; ++m)
                a = fmaf(__shfl(p, m), Vs[m][lane], a);
            acc[r] = a;
        }
    }
    #pragma unroll
    for (int r = 0; r < 16; ++r) {
        int row = b * L_ + qb * 64 + wid * 16 + r;
        o[(size_t)row * D_ + hh * 64 + lane] = f2bf(acc[r] / Sr[r]);
    }
}

// ---------------------------------------------------------------------------
// fp32 fallback GEMM (tiny heads): C[M,N] = A[M,K]@B[K,N] + bias
template <int MODE>
__global__ __launch_bounds__(256) void k_gemm(float* __restrict__ C,
                                              const float* __restrict__ A,
                                              const float* __restrict__ Bm,
                                              const float* __restrict__ bias,
                                              int M, int N, int K) {
    __shared__ float As[16][68];
    __shared__ float Bs[16][68];
    int tid = threadIdx.x;
    int row0 = blockIdx.y * 64, col0 = blockIdx.x * 64;
    int ty = tid / 16, tx = tid % 16;
    int ar = tid / 4, ac = (tid % 4) * 4;
    int br = tid / 16, bc = (tid % 16) * 4;
    float acc[4][4] = {};
    for (int kt = 0; kt < K; kt += 16) {
        const float* ap = A + (size_t)(row0 + ar) * K + kt + ac;
        float4 av = *reinterpret_cast<const float4*>(ap);
        As[ac + 0][ar] = av.x; As[ac + 1][ar] = av.y;
        As[ac + 2][ar] = av.z; As[ac + 3][ar] = av.w;
        int gb = col0 + bc;
        const float* bp = Bm + (size_t)(kt + br) * N + gb;
        #pragma unroll
        for (int j = 0; j < 4; ++j)
            Bs[br][bc + j] = (gb + j < N) ? bp[j] : 0.0f;
        __syncthreads();
        #pragma unroll
        for (int k = 0; k < 16; ++k) {
            float4 a4 = *reinterpret_cast<const float4*>(&As[k][ty * 4]);
            float4 b4 = *reinterpret_cast<const float4*>(&Bs[k][tx * 4]);
            float a[4] = {a4.x, a4.y, a4.z, a4.w};
            float b[4] = {b4.x, b4.y, b4.z, b4.w};
            #pragma unroll
            for (int i = 0; i < 4; ++i)
                #pragma unroll
                for (int j = 0; j < 4; ++j) acc[i][j] += a[i] * b[j];
        }
        __syncthreads();
    }
    #pragma unroll
    for (int i = 0; i < 4; ++i) {
        int m = row0 + ty * 4 + i;
        #pragma unroll
        for (int j = 0; j < 4; ++j) {
            int n = col0 + tx * 4 + j;
            if (n < N) {
                float v = acc[i][j];
                if (bias) v += bias[n];
                C[(size_t)m * N + n] = v;
            }
        }
    }
}

// ---------------------------------------------------------------------------
extern "C" void kernel_launch(void* const* d_in, const int* in_sizes, int n_in,
                              void* d_out, int out_size, void* d_ws, size_t ws_size,
                              hipStream_t stream) {
    const float* patch        = (const float*)d_in[0];
    const float* box          = (const float*)d_in[1];
    const float* patch_W      = (const float*)d_in[2];
    const float* patch_b      = (const float*)d_in[3];
    const float* box_W        = (const float*)d_in[4];
    const float* box_b        = (const float*)d_in[5];
    const float* Wq           = (const float*)d_in[6];
    const float* Wk           = (const float*)d_in[7];
    const float* Wv           = (const float*)d_in[8];
    const float* Wo           = (const float*)d_in[9];
    const float* attn_norm_w  = (const float*)d_in[10];
    const float* gate_W       = (const float*)d_in[11];
    const float* hidden_W     = (const float*)d_in[12];
    const float* ffn_out_W    = (const float*)d_in[13];
    const float* ffn_norm_w   = (const float*)d_in[14];
    const float* reward_norm_w= (const float*)d_in[15];
    const float* reward_W     = (const float*)d_in[16];
    const float* reward_b     = (const float*)d_in[17];
    const float* label_norm_w = (const float*)d_in[18];
    const float* label_W      = (const float*)d_in[19];
    const float* label_b      = (const float*)d_in[20];
    const float* box_norm_w   = (const float*)d_in[21];
    const float* boxh_W       = (const float*)d_in[22];
    const float* boxh_b       = (const float*)d_in[23];

    char* w = (char*)d_ws;
    auto alloc = [&](size_t bytes) { char* p = w; w += (bytes + 255) & ~(size_t)255; return p; };

    u16*  wqkv   = (u16*)alloc((size_t)2304 * 768 * 2);
    u16*  wo_l   = (u16*)alloc((size_t)768 * 768 * 2);
    u16*  wgh    = (u16*)alloc((size_t)6144 * 768 * 2);
    u16*  wfo    = (u16*)alloc((size_t)768 * 3072 * 2);
    u16*  wpat   = (u16*)alloc((size_t)768 * 768 * 2);
    u16*  wbox   = (u16*)alloc((size_t)768 * 768 * 2);
    u16*  wlab   = (u16*)alloc((size_t)1024 * 768 * 2);
    u16*  patchb = (u16*)alloc((size_t)MTOK * 768 * 2);
    u16*  bsin   = (u16*)alloc((size_t)MTOK * 768 * 2);
    float* h     = (float*)alloc((size_t)MTOK * D_ * 4);
    u16*  hn_bf  = (u16*)alloc((size_t)MTOK * D_ * 2);
    float* qkv   = (float*)alloc((size_t)MTOK * 2304 * 4);
    u16*  o_bf   = (u16*)alloc((size_t)MTOK * D_ * 2);
    u16*  gh_bf  = (u16*)alloc((size_t)MTOK * 6144 * 2);
    u16*  ga_bf  = (u16*)alloc((size_t)MTOK * DFF_ * 2);

    dim3 blk(256);

    // one-time converts
    k_convT<<<dim3(24, 24), blk, 0, stream>>>(wpat, patch_W, 768, 768, 768);
    k_convT<<<dim3(24, 24), blk, 0, stream>>>(wbox, box_W, 768, 768, 768);
    k_convT<<<dim3(32, 24), blk, 0, stream>>>(wlab, label_W, 768, 1000, 1024);
    k_cast<<<(MTOK * 768 / 4 + 255) / 256, blk, 0, stream>>>(patchb, patch, MTOK * 768 / 4);
    k_box_sin<<<(MTOK * D_ + 255) / 256, blk, 0, stream>>>(bsin, box);

    // embedding
    k_gemm_bf16<0><<<dim3(6, 32), blk, 0, stream>>>(h, patchb, wpat, patch_b, 768, 768, 768);
    k_gemm_bf16<1><<<dim3(6, 32), blk, 0, stream>>>(h, bsin,   wbox, box_b,   768, 768, 768);

    for (int ly = 0; ly < NL_; ++ly) {
        const float* wq  = Wq + (size_t)ly * D_ * D_;
        const float* wk  = Wk + (size_t)ly * D_ * D_;
        const float* wv  = Wv + (size_t)ly * D_ * D_;
        const float* wo  = Wo + (size_t)ly * D_ * D_;
        const float* anw = attn_norm_w + (size_t)ly * D_;
        const float* gw  = gate_W + (size_t)ly * D_ * DFF_;
        const float* hw  = hidden_W + (size_t)ly * D_ * DFF_;
        const float* ow  = ffn_out_W + (size_t)ly * DFF_ * D_;
        const float* fnw = ffn_norm_w + (size_t)ly * D_;

        k_convT<<<dim3(24, 24), blk, 0, stream>>>(wqkv,                wq, 768, 768, 768);
        k_convT<<<dim3(24, 24), blk, 0, stream>>>(wqkv + 768 * 768,    wk, 768, 768, 768);
        k_convT<<<dim3(24, 24), blk, 0, stream>>>(wqkv + 2 * 768 * 768, wv, 768, 768, 768);
        k_rmsnorm<u16><<<MTOK, blk, 0, stream>>>(hn_bf, h, anw);
        k_gemm_bf16<0><<<dim3(18, 32), blk, 0, stream>>>(qkv, hn_bf, wqkv, nullptr, 768, 2304, 2304);
        k_rope2<<<(MTOK * 768 + 255) / 256, blk, 0, stream>>>(qkv);
        k_attn2<<<dim3(96, 8), blk, 0, stream>>>(o_bf, qkv);
        k_convT<<<dim3(24, 24), blk, 0, stream>>>(wo_l, wo, 768, 768, 768);
        k_gemm_bf16<1><<<dim3(6, 32), blk, 0, stream>>>(h, o_bf, wo_l, nullptr, 768, 768, 768);

        k_rmsnorm<u16><<<MTOK, blk, 0, stream>>>(hn_bf, h, fnw);
        k_convT<<<dim3(96, 24), blk, 0, stream>>>(wgh,              gw, 768, 3072, 3072);
        k_convT<<<dim3(96, 24), blk, 0, stream>>>(wgh + 3072 * 768, hw, 768, 3072, 3072);
        k_gemm_bf16<3><<<dim3(48, 32), blk, 0, stream>>>(gh_bf, hn_bf, wgh, nullptr, 768, 6144, 6144);
        k_silu<<<(MTOK * DFF_ / 8 + 255) / 256, blk, 0, stream>>>(ga_bf, gh_bf);
        k_convT<<<dim3(24, 96), blk, 0, stream>>>(wfo, ow, 3072, 768, 768);
        k_gemm_bf16<1><<<dim3(6, 32), blk, 0, stream>>>(h, ga_bf, wfo, nullptr, 3072, 768, 768);
    }

    // heads
    float* out_reward = (float*)d_out;
    float* out_label  = out_reward + (size_t)MTOK * 2;
    float* out_box    = out_label + (size_t)MTOK * 1000;

    k_rmsnorm<u16><<<MTOK, blk, 0, stream>>>(hn_bf, h, label_norm_w);
    k_gemm_bf16<0><<<dim3(8, 32), blk, 0, stream>>>(out_label, hn_bf, wlab, label_b, 768, 1000, 1000);

    float* hnf = qkv;  // reuse (dead after last layer)
    k_rmsnorm<float><<<MTOK, blk, 0, stream>>>(hnf, h, reward_norm_w);
    k_gemm<0><<<dim3(1, 64), blk, 0, stream>>>(out_reward, hnf, reward_W, reward_b, MTOK, 2, 768);
    k_rmsnorm<float><<<MTOK, blk, 0, stream>>>(hnf, h, box_norm_w);
    k_gemm<0><<<dim3(1, 64), blk, 0, stream>>>(out_box, hnf, boxh_W, boxh_b, MTOK, 4, 768);
}

// Round 3
// 3940.722 us; speedup vs baseline: 5.8351x; 2.4123x over previous
//
#include <hip/hip_runtime.h>
#include <math.h>
#include <type_traits>

#define B_   8
#define L_   512
#define MTOK 4096           // B_*L_
#define D_   768
#define NH_  12
#define DH_  64
#define DFF_ 3072
#define NL_  12

typedef unsigned short u16;
typedef __attribute__((ext_vector_type(4))) float f32x4;
typedef __attribute__((ext_vector_type(8))) short i16x8;
typedef __attribute__((ext_vector_type(8))) __bf16 b16x8;

// Pick whichever vector type the gfx950 bf16 MFMA builtin accepts.
template <typename A, typename = void>
struct PickFrag { using type = i16x8; };
template <typename A>
struct PickFrag<A, std::void_t<decltype(__builtin_amdgcn_mfma_f32_16x16x32_bf16(
    std::declval<A>(), std::declval<A>(), std::declval<f32x4>(), 0, 0, 0))>> {
  using type = A;
};
using frag_t = typename PickFrag<b16x8>::type;

__device__ inline u16 f2bf(float f) {
    unsigned u = __float_as_uint(f);
    unsigned r = u + 0x7fffu + ((u >> 16) & 1u);
    return (u16)(r >> 16);
}
__device__ inline float bf2f(u16 b) { return __uint_as_float(((unsigned)b) << 16); }

// ---------------------------------------------------------------------------
// box sinusoid embedding -> bf16
__global__ void k_box_sin(u16* __restrict__ out, const float* __restrict__ box) {
    int idx = blockIdx.x * blockDim.x + threadIdx.x;
    if (idx >= MTOK * D_) return;
    int t = idx / D_, d = idx % D_;
    int c = d / 192, r = d % 192, j = r >> 1;
    float theta = __expf(-(float)j * (9.210340371976184f / 96.0f));
    float ang = box[t * 4 + c] * theta;
    out[idx] = f2bf((r & 1) ? sinf(ang) : cosf(ang));
}

// fp32 -> bf16 cast, 4 elems/thread
__global__ void k_cast(u16* __restrict__ out, const float* __restrict__ in, int n4) {
    int i = blockIdx.x * blockDim.x + threadIdx.x;
    if (i >= n4) return;
    float4 v = *reinterpret_cast<const float4*>(in + (size_t)i * 4);
    unsigned lo = (unsigned)f2bf(v.x) | ((unsigned)f2bf(v.y) << 16);
    unsigned hi = (unsigned)f2bf(v.z) | ((unsigned)f2bf(v.w) << 16);
    *reinterpret_cast<uint2*>(out + (size_t)i * 4) = make_uint2(lo, hi);
}

// ---------------------------------------------------------------------------
// transpose-convert: src (K,N) fp32 -> dst (Npad,K) bf16, zero rows n>=N
__global__ __launch_bounds__(256) void k_convT(u16* __restrict__ dst,
                                               const float* __restrict__ src,
                                               int K, int N, int Npad) {
    __shared__ float t[32][33];
    int bn = blockIdx.x * 32;
    int bk = blockIdx.y * 32;
    int tx = threadIdx.x % 32, ty = threadIdx.x / 32;
    #pragma unroll
    for (int i = 0; i < 4; ++i) {
        int k = bk + ty + i * 8;
        int n = bn + tx;
        t[ty + i * 8][tx] = (n < N) ? src[(size_t)k * N + n] : 0.0f;
    }
    __syncthreads();
    #pragma unroll
    for (int i = 0; i < 4; ++i) {
        int n = bn + ty + i * 8;   // dst row
        int k = bk + tx;           // dst col
        dst[(size_t)n * K + k] = f2bf(t[tx][ty + i * 8]);
    }
}

// ---------------------------------------------------------------------------
// RMSNorm: one block per token; OT = float or u16(bf16)
template <typename OT>
__global__ __launch_bounds__(256) void k_rmsnorm(OT* __restrict__ out,
                                                 const float* __restrict__ in,
                                                 const float* __restrict__ w) {
    int t = blockIdx.x;
    const float* x = in + (size_t)t * D_;
    float ss = 0.f;
    for (int i = threadIdx.x; i < D_; i += 256) { float v = x[i]; ss += v * v; }
    for (int off = 32; off > 0; off >>= 1) ss += __shfl_down(ss, off);
    __shared__ float red[4];
    int wid = threadIdx.x >> 6, lane = threadIdx.x & 63;
    if (lane == 0) red[wid] = ss;
    __syncthreads();
    float tot = red[0] + red[1] + red[2] + red[3];
    float inv = rsqrtf(tot / (float)D_ + 1e-6f);
    for (int i = threadIdx.x; i < D_; i += 256) {
        float v = x[i] * inv * w[i];
        if constexpr (std::is_same_v<OT, u16>) out[(size_t)t * D_ + i] = f2bf(v);
        else                                   out[(size_t)t * D_ + i] = v;
    }
}

// ---------------------------------------------------------------------------
// one-time RoPE table: tab[(l*32+j)*2] = cos(l*theta_j), +1 = sin
__global__ void k_rope_tab(float* __restrict__ tab) {
    int idx = blockIdx.x * blockDim.x + threadIdx.x;   // 512*32
    if (idx >= L_ * 32) return;
    int l = idx >> 5, j = idx & 31;
    float theta = __expf(-(float)j * (9.210340371976184f / 32.0f));
    float s, c;
    sincosf((float)l * theta, &s, &c);
    tab[idx * 2] = c;
    tab[idx * 2 + 1] = s;
}

// ---------------------------------------------------------------------------
// RoPE + relayout: qkv_bf (MTOK,2304) bf16 -> qh,kh [96][512][64] bf16 (rope'd)
__global__ void k_roper(u16* __restrict__ qh, u16* __restrict__ kh,
                        const u16* __restrict__ qkv, const float* __restrict__ tab) {
    int idx = blockIdx.x * blockDim.x + threadIdx.x;   // MTOK * 768 pairs
    if (idx >= MTOK * 768) return;
    int t = idx / 768, r = idx % 768;
    int head = r >> 5, j = r & 31;                     // head 0..23
    int l = t & (L_ - 1), b = t >> 9;
    float2 cs = *reinterpret_cast<const float2*>(tab + ((size_t)l * 32 + j) * 2);
    unsigned pk = *reinterpret_cast<const unsigned*>(qkv + (size_t)t * 2304 + head * 64 + 2 * j);
    float xr = bf2f((u16)(pk & 0xffff)), xi = bf2f((u16)(pk >> 16));
    float or_ = xr * cs.x - xi * cs.y;
    float oi_ = xr * cs.y + xi * cs.x;
    unsigned po = (unsigned)f2bf(or_) | ((unsigned)f2bf(oi_) << 16);
    u16* dst = (head < NH_) ? (qh + ((size_t)(b * NH_ + head) * L_ + l) * 64)
                            : (kh + ((size_t)(b * NH_ + head - NH_) * L_ + l) * 64);
    *reinterpret_cast<unsigned*>(dst + 2 * j) = po;
}

// ---------------------------------------------------------------------------
// V transpose: qkv_bf v-part -> vT [96][64][512] bf16
__global__ __launch_bounds__(256) void k_vt(u16* __restrict__ vT,
                                            const u16* __restrict__ qkv) {
    __shared__ u16 ts[64][40];
    int bh = blockIdx.x, lb = blockIdx.y;       // 96 heads, 16 l-blocks of 32
    int b = bh / NH_, hh = bh % NH_;
    int tid = threadIdx.x;
    {
        int r = tid >> 3, c8 = (tid & 7) * 8;   // r: l-offset 0..31, c8: d-offset
        uint4 v4 = *reinterpret_cast<const uint4*>(
            qkv + ((size_t)(b * L_ + lb * 32 + r)) * 2304 + 1536 + hh * 64 + c8);
        const u16* vv = reinterpret_cast<const u16*>(&v4);
        #pragma unroll
        for (int j = 0; j < 8; ++j) ts[c8 + j][r] = vv[j];
    }
    __syncthreads();
    {
        int d = tid >> 2, l0 = (tid & 3) * 8;
        uint4 o4 = *reinterpret_cast<const uint4*>(&ts[d][l0]);
        *reinterpret_cast<uint4*>(vT + ((size_t)bh * 64 + d) * L_ + lb * 32 + l0) = o4;
    }
}

// ---------------------------------------------------------------------------
// bf16 MFMA GEMM: C[M x Nout](ldC) (+)= A[M,K]bf16 @ BT[Nt,K]bf16^T (+bias)
// grid = (Nt/128, M/128), 256 threads. MODE 0: C=acc(+bias) f32
// MODE 1: C+=acc(+bias) f32   MODE 3: C=acc bf16
template <int MODE>
__global__ __launch_bounds__(256) void k_gemm_bf16(void* __restrict__ Cp,
                                                   const u16* __restrict__ A,
                                                   const u16* __restrict__ BT,
                                                   const float* __restrict__ bias,
                                                   int K, int Nout, int ldC) {
    __shared__ u16 As[128 * 32];
    __shared__ u16 Bs[128 * 32];
    int tid = threadIdx.x;
    int wid = tid >> 6, lane = tid & 63;
    int row0 = blockIdx.y * 128, col0 = blockIdx.x * 128;
    int wr = wid >> 1, wc = wid & 1;

    f32x4 acc[4][4] = {};

    int lrow = lane & 15, lk = (lane >> 4) * 8;

    for (int kt = 0; kt < K; kt += 32) {
        #pragma unroll
        for (int c = 0; c < 2; ++c) {
            int chunk = tid + c * 256;          // 0..511
            int r = chunk >> 2;                 // tile row
            int kc = (chunk & 3) * 8;           // k elem offset
            uint4 av = *reinterpret_cast<const uint4*>(A + (size_t)(row0 + r) * K + kt + kc);
            *reinterpret_cast<uint4*>(&As[chunk * 8]) = av;
            uint4 bv = *reinterpret_cast<const uint4*>(BT + (size_t)(col0 + r) * K + kt + kc);
            *reinterpret_cast<uint4*>(&Bs[chunk * 8]) = bv;
        }
        __syncthreads();
        frag_t af[4], bfr[4];
        #pragma unroll
        for (int m = 0; m < 4; ++m)
            af[m] = *reinterpret_cast<const frag_t*>(&As[(wr * 64 + m * 16 + lrow) * 32 + lk]);
        #pragma unroll
        for (int n = 0; n < 4; ++n)
            bfr[n] = *reinterpret_cast<const frag_t*>(&Bs[(wc * 64 + n * 16 + lrow) * 32 + lk]);
        #pragma unroll
        for (int m = 0; m < 4; ++m)
            #pragma unroll
            for (int n = 0; n < 4; ++n)
                acc[m][n] = __builtin_amdgcn_mfma_f32_16x16x32_bf16(af[m], bfr[n], acc[m][n], 0, 0, 0);
        __syncthreads();
    }

    int lcol = lane & 15, rb = (lane >> 4) * 4;
    #pragma unroll
    for (int m = 0; m < 4; ++m) {
        #pragma unroll
        for (int n = 0; n < 4; ++n) {
            int col = col0 + wc * 64 + n * 16 + lcol;
            if (col >= Nout) continue;
            #pragma unroll
            for (int e = 0; e < 4; ++e) {
                int row = row0 + wr * 64 + m * 16 + rb + e;
                float v = acc[m][n][e];
                size_t off = (size_t)row * ldC + col;
                if (MODE == 0) {
                    if (bias) v += bias[col];
                    ((float*)Cp)[off] = v;
                } else if (MODE == 1) {
                    if (bias) v += bias[col];
                    ((float*)Cp)[off] += v;
                } else {
                    ((u16*)Cp)[off] = f2bf(v);
                }
            }
        }
    }
}

// ---------------------------------------------------------------------------
// silu-mul: out[t,j] = bf16( silu(gh[t,j]) * gh[t,3072+j] ), gh (MTOK,6144) bf16
__global__ void k_silu(u16* __restrict__ out, const u16* __restrict__ gh) {
    int idx = blockIdx.x * blockDim.x + threadIdx.x;    // MTOK*3072/8
    if (idx >= MTOK * DFF_ / 8) return;
    int t = idx / 384, j8 = (idx % 384) * 8;
    uint4 g4 = *reinterpret_cast<const uint4*>(gh + (size_t)t * 6144 + j8);
    uint4 h4 = *reinterpret_cast<const uint4*>(gh + (size_t)t * 6144 + 3072 + j8);
    const u16* gu = reinterpret_cast<const u16*>(&g4);
    const u16* hu = reinterpret_cast<const u16*>(&h4);
    u16 r[8];
    #pragma unroll
    for (int e = 0; e < 8; ++e) {
        float g = bf2f(gu[e]), hv = bf2f(hu[e]);
        float s = g / (1.0f + __expf(-g));
        r[e] = f2bf(s * hv);
    }
    *reinterpret_cast<uint4*>(out + (size_t)t * DFF_ + j8) = *reinterpret_cast<uint4*>(r);
}

// ---------------------------------------------------------------------------
// MFMA flash attention. grid (96 bh, 8 qb), 256 thr = 4 waves x 16 q-rows.
// qh,kh: [96][512][64] bf16 (rope'd); vT: [96][64][512] bf16.
// o: (MTOK,768) bf16.
__global__ __launch_bounds__(256) void k_attn3(u16* __restrict__ o,
                                               const u16* __restrict__ qh,
                                               const u16* __restrict__ kh,
                                               const u16* __restrict__ vT) {
    int bh = blockIdx.x, qb = blockIdx.y;
    int b = bh / NH_, hh = bh % NH_;
    int tid = threadIdx.x, wid = tid >> 6, lane = tid & 63;
    // [64][72]: 144B row stride (16B aligned), bank stride 4 -> <=2-way conflicts
    __shared__ u16 Qs[64][72], Ks[64][72], Vs[64][72], Ps[64][72];

    #pragma unroll
    for (int i = 0; i < 2; ++i) {
        int idx = tid + i * 256;
        int r = idx >> 3, c8 = (idx & 7) * 8;
        uint4 v4 = *reinterpret_cast<const uint4*>(
            qh + ((size_t)bh * L_ + qb * 64 + r) * 64 + c8);
        *reinterpret_cast<uint4*>(&Qs[r][c8]) = v4;
    }
    __syncthreads();

    int lr = lane & 15, lg = lane >> 4;
    frag_t aq[2];
    #pragma unroll
    for (int kd = 0; kd < 2; ++kd)
        aq[kd] = *reinterpret_cast<const frag_t*>(&Qs[wid * 16 + lr][kd * 32 + lg * 8]);

    f32x4 accO[4] = {};
    float M[4], S[4];
    #pragma unroll
    for (int e = 0; e < 4; ++e) { M[e] = -INFINITY; S[e] = 0.f; }

    for (int kb = 0; kb <= qb; ++kb) {
        __syncthreads();   // protect Ks/Vs against waves still in previous PV
        #pragma unroll
        for (int i = 0; i < 2; ++i) {
            int idx = tid + i * 256;
            int r = idx >> 3, c8 = (idx & 7) * 8;
            *reinterpret_cast<uint4*>(&Ks[r][c8]) = *reinterpret_cast<const uint4*>(
                kh + ((size_t)bh * L_ + kb * 64 + r) * 64 + c8);
            *reinterpret_cast<uint4*>(&Vs[r][c8]) = *reinterpret_cast<const uint4*>(
                vT + ((size_t)bh * 64 + r) * L_ + kb * 64 + c8);
        }
        __syncthreads();

        // QK^T: S[16q x 64k] as 4 col-tiles
        f32x4 sv[4];
        #pragma unroll
        for (int ct = 0; ct < 4; ++ct) {
            frag_t bk0 = *reinterpret_cast<const frag_t*>(&Ks[ct * 16 + lr][lg * 8]);
            frag_t bk1 = *reinterpret_cast<const frag_t*>(&Ks[ct * 16 + lr][32 + lg * 8]);
            f32x4 z = {0.f, 0.f, 0.f, 0.f};
            z = __builtin_amdgcn_mfma_f32_16x16x32_bf16(aq[0], bk0, z, 0, 0, 0);
            sv[ct] = __builtin_amdgcn_mfma_f32_16x16x32_bf16(aq[1], bk1, z, 0, 0, 0);
        }

        bool diag = (kb == qb);
        float esc[4];
        #pragma unroll
        for (int e = 0; e < 4; ++e) {
            int qg = qb * 64 + wid * 16 + lg * 4 + e;   // query pos within sequence
            float mx = -1e30f;
            #pragma unroll
            for (int ct = 0; ct < 4; ++ct) {
                float s = sv[ct][e] * 0.125f;
                if (diag && (kb * 64 + ct * 16 + lr > qg)) s = -1e30f;
                sv[ct][e] = s;
                mx = fmaxf(mx, s);
            }
            #pragma unroll
            for (int msk = 8; msk; msk >>= 1) mx = fmaxf(mx, __shfl_xor(mx, msk));
            float newM = fmaxf(M[e], mx);
            float ps = 0.f;
            #pragma unroll
            for (int ct = 0; ct < 4; ++ct) {
                float p = __expf(sv[ct][e] - newM);
                sv[ct][e] = p;
                ps += p;
            }
            #pragma unroll
            for (int msk = 8; msk; msk >>= 1) ps += __shfl_xor(ps, msk);
            esc[e] = __expf(M[e] - newM);
            S[e] = S[e] * esc[e] + ps;
            M[e] = newM;
        }
        #pragma unroll
        for (int dt = 0; dt < 4; ++dt)
            #pragma unroll
            for (int e = 0; e < 4; ++e) accO[dt][e] *= esc[e];

        // P -> LDS (wave-private rows) in A-fragment layout
        #pragma unroll
        for (int ct = 0; ct < 4; ++ct)
            #pragma unroll
            for (int e = 0; e < 4; ++e)
                Ps[wid * 16 + lg * 4 + e][ct * 16 + lr] = f2bf(sv[ct][e]);

        frag_t pa0 = *reinterpret_cast<const frag_t*>(&Ps[wid * 16 + lr][lg * 8]);
        frag_t pa1 = *reinterpret_cast<const frag_t*>(&Ps[wid * 16 + lr][32 + lg * 8]);
        #pragma unroll
        for (int dt = 0; dt < 4; ++dt) {
            frag_t bv0 = *reinterpret_cast<const frag_t*>(&Vs[dt * 16 + lr][lg * 8]);
            frag_t bv1 = *reinterpret_cast<const frag_t*>(&Vs[dt * 16 + lr][32 + lg * 8]);
            accO[dt] = __builtin_amdgcn_mfma_f32_16x16x32_bf16(pa0, bv0, accO[dt], 0, 0, 0);
            accO[dt] = __builtin_amdgcn_mfma_f32_16x16x32_bf16(pa1, bv1, accO[dt], 0, 0, 0);
        }
    }

    #pragma unroll
    for (int dt = 0; dt < 4; ++dt) {
        #pragma unroll
        for (int e = 0; e < 4; ++e) {
            int row = b * L_ + qb * 64 + wid * 16 + lg * 4 + e;
            o[(size_t)row * D_ + hh * 64 + dt * 16 + lr] = f2bf(accO[dt][e] / S[e]);
        }
    }
}

// ---------------------------------------------------------------------------
// fp32 fallback GEMM (tiny heads): C[M,N] = A[M,K]@B[K,N] + bias
template <int MODE>
__global__ __launch_bounds__(256) void k_gemm(float* __restrict__ C,
                                              const float* __restrict__ A,
                                              const float* __restrict__ Bm,
                                              const float* __restrict__ bias,
                                              int M, int N, int K) {
    __shared__ float As[16][68];
    __shared__ float Bs[16][68];
    int tid = threadIdx.x;
    int row0 = blockIdx.y * 64, col0 = blockIdx.x * 64;
    int ty = tid / 16, tx = tid % 16;
    int ar = tid / 4, ac = (tid % 4) * 4;
    int br = tid / 16, bc = (tid % 16) * 4;
    float acc[4][4] = {};
    for (int kt = 0; kt < K; kt += 16) {
        const float* ap = A + (size_t)(row0 + ar) * K + kt + ac;
        float4 av = *reinterpret_cast<const float4*>(ap);
        As[ac + 0][ar] = av.x; As[ac + 1][ar] = av.y;
        As[ac + 2][ar] = av.z; As[ac + 3][ar] = av.w;
        int gb = col0 + bc;
        const float* bp = Bm + (size_t)(kt + br) * N + gb;
        #pragma unroll
        for (int j = 0; j < 4; ++j)
            Bs[br][bc + j] = (gb + j < N) ? bp[j] : 0.0f;
        __syncthreads();
        #pragma unroll
        for (int k = 0; k < 16; ++k) {
            float4 a4 = *reinterpret_cast<const float4*>(&As[k][ty * 4]);
            float4 b4 = *reinterpret_cast<const float4*>(&Bs[k][tx * 4]);
            float a[4] = {a4.x, a4.y, a4.z, a4.w};
            float b[4] = {b4.x, b4.y, b4.z, b4.w};
            #pragma unroll
            for (int i = 0; i < 4; ++i)
                #pragma unroll
                for (int j = 0; j < 4; ++j) acc[i][j] += a[i] * b[j];
        }
        __syncthreads();
    }
    #pragma unroll
    for (int i = 0; i < 4; ++i) {
        int m = row0 + ty * 4 + i;
        #pragma unroll
        for (int j = 0; j < 4; ++j) {
            int n = col0 + tx * 4 + j;
            if (n < N) {
                float v = acc[i][j];
                if (bias) v += bias[n];
                C[(size_t)m * N + n] = v;
            }
        }
    }
}

// ---------------------------------------------------------------------------
extern "C" void kernel_launch(void* const* d_in, const int* in_sizes, int n_in,
                              void* d_out, int out_size, void* d_ws, size_t ws_size,
                              hipStream_t stream) {
    const float* patch        = (const float*)d_in[0];
    const float* box          = (const float*)d_in[1];
    const float* patch_W      = (const float*)d_in[2];
    const float* patch_b      = (const float*)d_in[3];
    const float* box_W        = (const float*)d_in[4];
    const float* box_b        = (const float*)d_in[5];
    const float* Wq           = (const float*)d_in[6];
    const float* Wk           = (const float*)d_in[7];
    const float* Wv           = (const float*)d_in[8];
    const float* Wo           = (const float*)d_in[9];
    const float* attn_norm_w  = (const float*)d_in[10];
    const float* gate_W       = (const float*)d_in[11];
    const float* hidden_W     = (const float*)d_in[12];
    const float* ffn_out_W    = (const float*)d_in[13];
    const float* ffn_norm_w   = (const float*)d_in[14];
    const float* reward_norm_w= (const float*)d_in[15];
    const float* reward_W     = (const float*)d_in[16];
    const float* reward_b     = (const float*)d_in[17];
    const float* label_norm_w = (const float*)d_in[18];
    const float* label_W      = (const float*)d_in[19];
    const float* label_b      = (const float*)d_in[20];
    const float* box_norm_w   = (const float*)d_in[21];
    const float* boxh_W       = (const float*)d_in[22];
    const float* boxh_b       = (const float*)d_in[23];

    char* w = (char*)d_ws;
    auto alloc = [&](size_t bytes) { char* p = w; w += (bytes + 255) & ~(size_t)255; return p; };

    u16*  wqkv   = (u16*)alloc((size_t)2304 * 768 * 2);
    u16*  wo_l   = (u16*)alloc((size_t)768 * 768 * 2);
    u16*  wgh    = (u16*)alloc((size_t)6144 * 768 * 2);
    u16*  wfo    = (u16*)alloc((size_t)768 * 3072 * 2);
    u16*  wpat   = (u16*)alloc((size_t)768 * 768 * 2);
    u16*  wbox   = (u16*)alloc((size_t)768 * 768 * 2);
    u16*  wlab   = (u16*)alloc((size_t)1024 * 768 * 2);
    u16*  patchb = (u16*)alloc((size_t)MTOK * 768 * 2);   // reused as qh after embed
    u16*  bsin   = (u16*)alloc((size_t)MTOK * 768 * 2);   // reused as kh after embed
    float* h     = (float*)alloc((size_t)MTOK * D_ * 4);
    u16*  hn_bf  = (u16*)alloc((size_t)MTOK * D_ * 2);
    u16*  qkv_bf = (u16*)alloc((size_t)MTOK * 2304 * 2);
    u16*  vT     = (u16*)alloc((size_t)MTOK * D_ * 2);
    float* tab   = (float*)alloc((size_t)L_ * 32 * 2 * 4);
    u16*  o_bf   = (u16*)alloc((size_t)MTOK * D_ * 2);
    u16*  gh_bf  = (u16*)alloc((size_t)MTOK * 6144 * 2);  // reused as hnf at heads
    u16*  ga_bf  = (u16*)alloc((size_t)MTOK * DFF_ * 2);

    u16* qh = patchb;
    u16* kh = bsin;
    float* hnf = (float*)gh_bf;

    dim3 blk(256);

    // one-time converts
    k_convT<<<dim3(24, 24), blk, 0, stream>>>(wpat, patch_W, 768, 768, 768);
    k_convT<<<dim3(24, 24), blk, 0, stream>>>(wbox, box_W, 768, 768, 768);
    k_convT<<<dim3(32, 24), blk, 0, stream>>>(wlab, label_W, 768, 1000, 1024);
    k_rope_tab<<<(L_ * 32 + 255) / 256, blk, 0, stream>>>(tab);
    k_cast<<<(MTOK * 768 / 4 + 255) / 256, blk, 0, stream>>>(patchb, patch, MTOK * 768 / 4);
    k_box_sin<<<(MTOK * D_ + 255) / 256, blk, 0, stream>>>(bsin, box);

    // embedding
    k_gemm_bf16<0><<<dim3(6, 32), blk, 0, stream>>>(h, patchb, wpat, patch_b, 768, 768, 768);
    k_gemm_bf16<1><<<dim3(6, 32), blk, 0, stream>>>(h, bsin,   wbox, box_b,   768, 768, 768);

    for (int ly = 0; ly < NL_; ++ly) {
        const float* wq  = Wq + (size_t)ly * D_ * D_;
        const float* wk  = Wk + (size_t)ly * D_ * D_;
        const float* wv  = Wv + (size_t)ly * D_ * D_;
        const float* wo  = Wo + (size_t)ly * D_ * D_;
        const float* anw = attn_norm_w + (size_t)ly * D_;
        const float* gw  = gate_W + (size_t)ly * D_ * DFF_;
        const float* hw  = hidden_W + (size_t)ly * D_ * DFF_;
        const float* ow  = ffn_out_W + (size_t)ly * DFF_ * D_;
        const float* fnw = ffn_norm_w + (size_t)ly * D_;

        k_convT<<<dim3(24, 24), blk, 0, stream>>>(wqkv,                 wq, 768, 768, 768);
        k_convT<<<dim3(24, 24), blk, 0, stream>>>(wqkv + 768 * 768,     wk, 768, 768, 768);
        k_convT<<<dim3(24, 24), blk, 0, stream>>>(wqkv + 2 * 768 * 768, wv, 768, 768, 768);
        k_rmsnorm<u16><<<MTOK, blk, 0, stream>>>(hn_bf, h, anw);
        k_gemm_bf16<3><<<dim3(18, 32), blk, 0, stream>>>(qkv_bf, hn_bf, wqkv, nullptr, 768, 2304, 2304);
        k_roper<<<(MTOK * 768 + 255) / 256, blk, 0, stream>>>(qh, kh, qkv_bf, tab);
        k_vt<<<dim3(96, 16), blk, 0, stream>>>(vT, qkv_bf);
        k_attn3<<<dim3(96, 8), blk, 0, stream>>>(o_bf, qh, kh, vT);
        k_convT<<<dim3(24, 24), blk, 0, stream>>>(wo_l, wo, 768, 768, 768);
        k_gemm_bf16<1><<<dim3(6, 32), blk, 0, stream>>>(h, o_bf, wo_l, nullptr, 768, 768, 768);

        k_rmsnorm<u16><<<MTOK, blk, 0, stream>>>(hn_bf, h, fnw);
        k_convT<<<dim3(96, 24), blk, 0, stream>>>(wgh,              gw, 768, 3072, 3072);
        k_convT<<<dim3(96, 24), blk, 0, stream>>>(wgh + 3072 * 768, hw, 768, 3072, 3072);
        k_gemm_bf16<3><<<dim3(48, 32), blk, 0, stream>>>(gh_bf, hn_bf, wgh, nullptr, 768, 6144, 6144);
        k_silu<<<(MTOK * DFF_ / 8 + 255) / 256, blk, 0, stream>>>(ga_bf, gh_bf);
        k_convT<<<dim3(24, 96), blk, 0, stream>>>(wfo, ow, 3072, 768, 768);
        k_gemm_bf16<1><<<dim3(6, 32), blk, 0, stream>>>(h, ga_bf, wfo, nullptr, 3072, 768, 768);
    }

    // heads
    float* out_reward = (float*)d_out;
    float* out_label  = out_reward + (size_t)MTOK * 2;
    float* out_box    = out_label + (size_t)MTOK * 1000;

    k_rmsnorm<u16><<<MTOK, blk, 0, stream>>>(hn_bf, h, label_norm_w);
    k_gemm_bf16<0><<<dim3(8, 32), blk, 0, stream>>>(out_label, hn_bf, wlab, label_b, 768, 1000, 1000);

    k_rmsnorm<float><<<MTOK, blk, 0, stream>>>(hnf, h, reward_norm_w);
    k_gemm<0><<<dim3(1, 64), blk, 0, stream>>>(out_reward, hnf, reward_W, reward_b, MTOK, 2, 768);
    k_rmsnorm<float><<<MTOK, blk, 0, stream>>>(hnf, h, box_norm_w);
    k_gemm<0><<<dim3(1, 64), blk, 0, stream>>>(out_box, hnf, boxh_W, boxh_b, MTOK, 4, 768);
}

// Round 4
// 3298.405 us; speedup vs baseline: 6.9713x; 1.1947x over previous
//
#include <hip/hip_runtime.h>
#include <math.h>
#include <type_traits>

#define B_   8
#define L_   512
#define MTOK 4096           // B_*L_
#define D_   768
#define NH_  12
#define DH_  64
#define DFF_ 3072
#define NL_  12

typedef unsigned short u16;
typedef __attribute__((ext_vector_type(4))) float f32x4;
typedef __attribute__((ext_vector_type(8))) short i16x8;
typedef __attribute__((ext_vector_type(8))) __bf16 b16x8;

// Pick whichever vector type the gfx950 bf16 MFMA builtin accepts.
template <typename A, typename = void>
struct PickFrag { using type = i16x8; };
template <typename A>
struct PickFrag<A, std::void_t<decltype(__builtin_amdgcn_mfma_f32_16x16x32_bf16(
    std::declval<A>(), std::declval<A>(), std::declval<f32x4>(), 0, 0, 0))>> {
  using type = A;
};
using frag_t = typename PickFrag<b16x8>::type;

#if __has_builtin(__builtin_amdgcn_global_load_lds)
#define HAS_GLDS 1
#else
#define HAS_GLDS 0
#endif

__device__ inline u16 f2bf(float f) {
    unsigned u = __float_as_uint(f);
    unsigned r = u + 0x7fffu + ((u >> 16) & 1u);
    return (u16)(r >> 16);
}
__device__ inline float bf2f(u16 b) { return __uint_as_float(((unsigned)b) << 16); }

// ---------------------------------------------------------------------------
// box sinusoid embedding -> bf16
__global__ void k_box_sin(u16* __restrict__ out, const float* __restrict__ box) {
    int idx = blockIdx.x * blockDim.x + threadIdx.x;
    if (idx >= MTOK * D_) return;
    int t = idx / D_, d = idx % D_;
    int c = d / 192, r = d % 192, j = r >> 1;
    float theta = __expf(-(float)j * (9.210340371976184f / 96.0f));
    float ang = box[t * 4 + c] * theta;
    out[idx] = f2bf((r & 1) ? sinf(ang) : cosf(ang));
}

// fp32 -> bf16 cast, 4 elems/thread
__global__ void k_cast(u16* __restrict__ out, const float* __restrict__ in, int n4) {
    int i = blockIdx.x * blockDim.x + threadIdx.x;
    if (i >= n4) return;
    float4 v = *reinterpret_cast<const float4*>(in + (size_t)i * 4);
    unsigned lo = (unsigned)f2bf(v.x) | ((unsigned)f2bf(v.y) << 16);
    unsigned hi = (unsigned)f2bf(v.z) | ((unsigned)f2bf(v.w) << 16);
    *reinterpret_cast<uint2*>(out + (size_t)i * 4) = make_uint2(lo, hi);
}

// ---------------------------------------------------------------------------
// transpose-convert: src (K,N) fp32 -> dst (Npad,K) bf16, zero rows n>=N
__global__ __launch_bounds__(256) void k_convT(u16* __restrict__ dst,
                                               const float* __restrict__ src,
                                               int K, int N, int Npad) {
    __shared__ float t[32][33];
    int bn = blockIdx.x * 32;
    int bk = blockIdx.y * 32;
    int tx = threadIdx.x % 32, ty = threadIdx.x / 32;
    #pragma unroll
    for (int i = 0; i < 4; ++i) {
        int k = bk + ty + i * 8;
        int n = bn + tx;
        t[ty + i * 8][tx] = (n < N) ? src[(size_t)k * N + n] : 0.0f;
    }
    __syncthreads();
    #pragma unroll
    for (int i = 0; i < 4; ++i) {
        int n = bn + ty + i * 8;   // dst row
        int k = bk + tx;           // dst col
        dst[(size_t)n * K + k] = f2bf(t[tx][ty + i * 8]);
    }
}

// ---------------------------------------------------------------------------
// RMSNorm: one block per token; OT = float or u16(bf16)
template <typename OT>
__global__ __launch_bounds__(256) void k_rmsnorm(OT* __restrict__ out,
                                                 const float* __restrict__ in,
                                                 const float* __restrict__ w) {
    int t = blockIdx.x;
    const float* x = in + (size_t)t * D_;
    float ss = 0.f;
    for (int i = threadIdx.x; i < D_; i += 256) { float v = x[i]; ss += v * v; }
    for (int off = 32; off > 0; off >>= 1) ss += __shfl_down(ss, off);
    __shared__ float red[4];
    int wid = threadIdx.x >> 6, lane = threadIdx.x & 63;
    if (lane == 0) red[wid] = ss;
    __syncthreads();
    float tot = red[0] + red[1] + red[2] + red[3];
    float inv = rsqrtf(tot / (float)D_ + 1e-6f);
    for (int i = threadIdx.x; i < D_; i += 256) {
        float v = x[i] * inv * w[i];
        if constexpr (std::is_same_v<OT, u16>) out[(size_t)t * D_ + i] = f2bf(v);
        else                                   out[(size_t)t * D_ + i] = v;
    }
}

// ---------------------------------------------------------------------------
// one-time RoPE table: tab[(l*32+j)*2] = cos(l*theta_j), +1 = sin
__global__ void k_rope_tab(float* __restrict__ tab) {
    int idx = blockIdx.x * blockDim.x + threadIdx.x;   // 512*32
    if (idx >= L_ * 32) return;
    int l = idx >> 5, j = idx & 31;
    float theta = __expf(-(float)j * (9.210340371976184f / 32.0f));
    float s, c;
    sincosf((float)l * theta, &s, &c);
    tab[idx * 2] = c;
    tab[idx * 2 + 1] = s;
}

// ---------------------------------------------------------------------------
// RoPE + relayout: qkv_bf (MTOK,2304) bf16 -> qh,kh [96][512][64] bf16 (rope'd)
__global__ void k_roper(u16* __restrict__ qh, u16* __restrict__ kh,
                        const u16* __restrict__ qkv, const float* __restrict__ tab) {
    int idx = blockIdx.x * blockDim.x + threadIdx.x;   // MTOK * 768 pairs
    if (idx >= MTOK * 768) return;
    int t = idx / 768, r = idx % 768;
    int head = r >> 5, j = r & 31;                     // head 0..23
    int l = t & (L_ - 1), b = t >> 9;
    float2 cs = *reinterpret_cast<const float2*>(tab + ((size_t)l * 32 + j) * 2);
    unsigned pk = *reinterpret_cast<const unsigned*>(qkv + (size_t)t * 2304 + head * 64 + 2 * j);
    float xr = bf2f((u16)(pk & 0xffff)), xi = bf2f((u16)(pk >> 16));
    float or_ = xr * cs.x - xi * cs.y;
    float oi_ = xr * cs.y + xi * cs.x;
    unsigned po = (unsigned)f2bf(or_) | ((unsigned)f2bf(oi_) << 16);
    u16* dst = (head < NH_) ? (qh + ((size_t)(b * NH_ + head) * L_ + l) * 64)
                            : (kh + ((size_t)(b * NH_ + head - NH_) * L_ + l) * 64);
    *reinterpret_cast<unsigned*>(dst + 2 * j) = po;
}

// ---------------------------------------------------------------------------
// V transpose: qkv_bf v-part -> vT [96][64][512] bf16
__global__ __launch_bounds__(256) void k_vt(u16* __restrict__ vT,
                                            const u16* __restrict__ qkv) {
    __shared__ u16 ts[64][40];
    int bh = blockIdx.x, lb = blockIdx.y;       // 96 heads, 16 l-blocks of 32
    int b = bh / NH_, hh = bh % NH_;
    int tid = threadIdx.x;
    {
        int r = tid >> 3, c8 = (tid & 7) * 8;   // r: l-offset 0..31, c8: d-offset
        uint4 v4 = *reinterpret_cast<const uint4*>(
            qkv + ((size_t)(b * L_ + lb * 32 + r)) * 2304 + 1536 + hh * 64 + c8);
        const u16* vv = reinterpret_cast<const u16*>(&v4);
        #pragma unroll
        for (int j = 0; j < 8; ++j) ts[c8 + j][r] = vv[j];
    }
    __syncthreads();
    {
        int d = tid >> 2, l0 = (tid & 3) * 8;
        uint4 o4 = *reinterpret_cast<const uint4*>(&ts[d][l0]);
        *reinterpret_cast<uint4*>(vT + ((size_t)bh * 64 + d) * L_ + lb * 32 + l0) = o4;
    }
}

// ---------------------------------------------------------------------------
// bf16 MFMA GEMM with global_load_lds staging, XCD swizzle, optional split-K.
// C[M x Nout](ldC) (+)= A[M,K]bf16 @ BT[Nt,K]bf16^T (+bias)
// grid = (Nt/128, M/128, SPLITK), 256 threads. K % (32*SPLITK) == 0.
// MODE 0: C=acc(+bias) f32   MODE 1: C+=acc(+bias) f32   MODE 3: C=acc bf16
// MODE 4: partial fp32 store to Cp + sk*Mtot*ldC (split-K)
template <int MODE>
__global__ __launch_bounds__(256) void k_gemm_bf16(void* __restrict__ Cp,
                                                   const u16* __restrict__ A,
                                                   const u16* __restrict__ BT,
                                                   const float* __restrict__ bias,
                                                   int K, int Nout, int ldC) {
    __shared__ u16 As[128 * 32];
    __shared__ u16 Bs[128 * 32];
    int tid = threadIdx.x;
    int wid = tid >> 6, lane = tid & 63;

    // ---- XCD-aware swizzle over full 3D linear block id (nwg % 8 == 0) ----
    int nx = gridDim.x, ny = gridDim.y, nz = gridDim.z;
    int bid = ((blockIdx.z * ny) + blockIdx.y) * nx + blockIdx.x;
    int nwg = nx * ny * nz;
    int cpx = nwg >> 3;
    int swz = (bid & 7) * cpx + (bid >> 3);
    int sk  = swz / (nx * ny);
    int rem = swz % (nx * ny);
    int by = rem / nx, bx = rem % nx;
    int row0 = by * 128, col0 = bx * 128;
    int wr = wid >> 1, wc = wid & 1;

    int Klen = K / nz;          // k-range this block covers
    int kbeg = sk * Klen;

    f32x4 acc[4][4] = {};
    int lrow = lane & 15, lk = (lane >> 4) * 8;

    for (int kt = 0; kt < Klen; kt += 32) {
        #pragma unroll
        for (int i = 0; i < 2; ++i) {
            int chunk = wid * 128 + i * 64 + lane;        // 0..511
            int r = chunk >> 2;                            // tile row
            int kc = (chunk & 3) * 8;                      // k elem offset
            const u16* ga = A  + (size_t)(row0 + r) * K + kbeg + kt + kc;
            const u16* gb = BT + (size_t)(col0 + r) * K + kbeg + kt + kc;
#if HAS_GLDS
            __builtin_amdgcn_global_load_lds(
                (const __attribute__((address_space(1))) void*)ga,
                (__attribute__((address_space(3))) void*)&As[(wid * 128 + i * 64) * 8],
                16, 0, 0);
            __builtin_amdgcn_global_load_lds(
                (const __attribute__((address_space(1))) void*)gb,
                (__attribute__((address_space(3))) void*)&Bs[(wid * 128 + i * 64) * 8],
                16, 0, 0);
#else
            *reinterpret_cast<uint4*>(&As[chunk * 8]) = *reinterpret_cast<const uint4*>(ga);
            *reinterpret_cast<uint4*>(&Bs[chunk * 8]) = *reinterpret_cast<const uint4*>(gb);
#endif
        }
        __syncthreads();
        frag_t af[4], bfr[4];
        #pragma unroll
        for (int m = 0; m < 4; ++m)
            af[m] = *reinterpret_cast<const frag_t*>(&As[(wr * 64 + m * 16 + lrow) * 32 + lk]);
        #pragma unroll
        for (int n = 0; n < 4; ++n)
            bfr[n] = *reinterpret_cast<const frag_t*>(&Bs[(wc * 64 + n * 16 + lrow) * 32 + lk]);
        #pragma unroll
        for (int m = 0; m < 4; ++m)
            #pragma unroll
            for (int n = 0; n < 4; ++n)
                acc[m][n] = __builtin_amdgcn_mfma_f32_16x16x32_bf16(af[m], bfr[n], acc[m][n], 0, 0, 0);
        __syncthreads();
    }

    float* Cpart = (MODE == 4)
        ? ((float*)Cp + (size_t)sk * (size_t)(ny * 128) * ldC) : (float*)Cp;

    int lcol = lane & 15, rb = (lane >> 4) * 4;
    #pragma unroll
    for (int m = 0; m < 4; ++m) {
        #pragma unroll
        for (int n = 0; n < 4; ++n) {
            int col = col0 + wc * 64 + n * 16 + lcol;
            if (col >= Nout) continue;
            #pragma unroll
            for (int e = 0; e < 4; ++e) {
                int row = row0 + wr * 64 + m * 16 + rb + e;
                float v = acc[m][n][e];
                size_t off = (size_t)row * ldC + col;
                if (MODE == 0) {
                    if (bias) v += bias[col];
                    ((float*)Cp)[off] = v;
                } else if (MODE == 1) {
                    if (bias) v += bias[col];
                    ((float*)Cp)[off] += v;
                } else if (MODE == 3) {
                    ((u16*)Cp)[off] = f2bf(v);
                } else {
                    Cpart[off] = v;
                }
            }
        }
    }
}

// ---------------------------------------------------------------------------
// residual reduce: h[i] += sum_s part[s][i]   (n4 = elements/4)
template <int S>
__global__ void k_redadd(float* __restrict__ h, const float* __restrict__ part) {
    int i = blockIdx.x * blockDim.x + threadIdx.x;
    if (i >= MTOK * D_ / 4) return;
    float4 a = *reinterpret_cast<const float4*>(h + (size_t)i * 4);
    #pragma unroll
    for (int s = 0; s < S; ++s) {
        float4 p = *reinterpret_cast<const float4*>(part + (size_t)s * MTOK * D_ + (size_t)i * 4);
        a.x += p.x; a.y += p.y; a.z += p.z; a.w += p.w;
    }
    *reinterpret_cast<float4*>(h + (size_t)i * 4) = a;
}

// ---------------------------------------------------------------------------
// silu-mul: out[t,j] = bf16( silu(gh[t,j]) * gh[t,3072+j] ), gh (MTOK,6144) bf16
__global__ void k_silu(u16* __restrict__ out, const u16* __restrict__ gh) {
    int idx = blockIdx.x * blockDim.x + threadIdx.x;    // MTOK*3072/8
    if (idx >= MTOK * DFF_ / 8) return;
    int t = idx / 384, j8 = (idx % 384) * 8;
    uint4 g4 = *reinterpret_cast<const uint4*>(gh + (size_t)t * 6144 + j8);
    uint4 h4 = *reinterpret_cast<const uint4*>(gh + (size_t)t * 6144 + 3072 + j8);
    const u16* gu = reinterpret_cast<const u16*>(&g4);
    const u16* hu = reinterpret_cast<const u16*>(&h4);
    u16 r[8];
    #pragma unroll
    for (int e = 0; e < 8; ++e) {
        float g = bf2f(gu[e]), hv = bf2f(hu[e]);
        float s = g / (1.0f + __expf(-g));
        r[e] = f2bf(s * hv);
    }
    *reinterpret_cast<uint4*>(out + (size_t)t * DFF_ + j8) = *reinterpret_cast<uint4*>(r);
}

// ---------------------------------------------------------------------------
// MFMA flash attention. grid (96 bh, 8 qb), 256 thr = 4 waves x 16 q-rows.
// qh,kh: [96][512][64] bf16 (rope'd); vT: [96][64][512] bf16.
// o: (MTOK,768) bf16.
__global__ __launch_bounds__(256) void k_attn3(u16* __restrict__ o,
                                               const u16* __restrict__ qh,
                                               const u16* __restrict__ kh,
                                               const u16* __restrict__ vT) {
    int bh = blockIdx.x, qb = blockIdx.y;
    int b = bh / NH_, hh = bh % NH_;
    int tid = threadIdx.x, wid = tid >> 6, lane = tid & 63;
    __shared__ u16 Qs[64][72], Ks[64][72], Vs[64][72], Ps[64][72];

    #pragma unroll
    for (int i = 0; i < 2; ++i) {
        int idx = tid + i * 256;
        int r = idx >> 3, c8 = (idx & 7) * 8;
        uint4 v4 = *reinterpret_cast<const uint4*>(
            qh + ((size_t)bh * L_ + qb * 64 + r) * 64 + c8);
        *reinterpret_cast<uint4*>(&Qs[r][c8]) = v4;
    }
    __syncthreads();

    int lr = lane & 15, lg = lane >> 4;
    frag_t aq[2];
    #pragma unroll
    for (int kd = 0; kd < 2; ++kd)
        aq[kd] = *reinterpret_cast<const frag_t*>(&Qs[wid * 16 + lr][kd * 32 + lg * 8]);

    f32x4 accO[4] = {};
    float M[4], S[4];
    #pragma unroll
    for (int e = 0; e < 4; ++e) { M[e] = -INFINITY; S[e] = 0.f; }

    for (int kb = 0; kb <= qb; ++kb) {
        __syncthreads();
        #pragma unroll
        for (int i = 0; i < 2; ++i) {
            int idx = tid + i * 256;
            int r = idx >> 3, c8 = (idx & 7) * 8;
            *reinterpret_cast<uint4*>(&Ks[r][c8]) = *reinterpret_cast<const uint4*>(
                kh + ((size_t)bh * L_ + kb * 64 + r) * 64 + c8);
            *reinterpret_cast<uint4*>(&Vs[r][c8]) = *reinterpret_cast<const uint4*>(
                vT + ((size_t)bh * 64 + r) * L_ + kb * 64 + c8);
        }
        __syncthreads();

        f32x4 sv[4];
        #pragma unroll
        for (int ct = 0; ct < 4; ++ct) {
            frag_t bk0 = *reinterpret_cast<const frag_t*>(&Ks[ct * 16 + lr][lg * 8]);
            frag_t bk1 = *reinterpret_cast<const frag_t*>(&Ks[ct * 16 + lr][32 + lg * 8]);
            f32x4 z = {0.f, 0.f, 0.f, 0.f};
            z = __builtin_amdgcn_mfma_f32_16x16x32_bf16(aq[0], bk0, z, 0, 0, 0);
            sv[ct] = __builtin_amdgcn_mfma_f32_16x16x32_bf16(aq[1], bk1, z, 0, 0, 0);
        }

        bool diag = (kb == qb);
        float esc[4];
        #pragma unroll
        for (int e = 0; e < 4; ++e) {
            int qg = qb * 64 + wid * 16 + lg * 4 + e;
            float mx = -1e30f;
            #pragma unroll
            for (int ct = 0; ct < 4; ++ct) {
                float s = sv[ct][e] * 0.125f;
                if (diag && (kb * 64 + ct * 16 + lr > qg)) s = -1e30f;
                sv[ct][e] = s;
                mx = fmaxf(mx, s);
            }
            #pragma unroll
            for (int msk = 8; msk; msk >>= 1) mx = fmaxf(mx, __shfl_xor(mx, msk));
            float newM = fmaxf(M[e], mx);
            float ps = 0.f;
            #pragma unroll
            for (int ct = 0; ct < 4; ++ct) {
                float p = __expf(sv[ct][e] - newM);
                sv[ct][e] = p;
                ps += p;
            }
            #pragma unroll
            for (int msk = 8; msk; msk >>= 1) ps += __shfl_xor(ps, msk);
            esc[e] = __expf(M[e] - newM);
            S[e] = S[e] * esc[e] + ps;
            M[e] = newM;
        }
        #pragma unroll
        for (int dt = 0; dt < 4; ++dt)
            #pragma unroll
            for (int e = 0; e < 4; ++e) accO[dt][e] *= esc[e];

        #pragma unroll
        for (int ct = 0; ct < 4; ++ct)
            #pragma unroll
            for (int e = 0; e < 4; ++e)
                Ps[wid * 16 + lg * 4 + e][ct * 16 + lr] = f2bf(sv[ct][e]);

        frag_t pa0 = *reinterpret_cast<const frag_t*>(&Ps[wid * 16 + lr][lg * 8]);
        frag_t pa1 = *reinterpret_cast<const frag_t*>(&Ps[wid * 16 + lr][32 + lg * 8]);
        #pragma unroll
        for (int dt = 0; dt < 4; ++dt) {
            frag_t bv0 = *reinterpret_cast<const frag_t*>(&Vs[dt * 16 + lr][lg * 8]);
            frag_t bv1 = *reinterpret_cast<const frag_t*>(&Vs[dt * 16 + lr][32 + lg * 8]);
            accO[dt] = __builtin_amdgcn_mfma_f32_16x16x32_bf16(pa0, bv0, accO[dt], 0, 0, 0);
            accO[dt] = __builtin_amdgcn_mfma_f32_16x16x32_bf16(pa1, bv1, accO[dt], 0, 0, 0);
        }
    }

    #pragma unroll
    for (int dt = 0; dt < 4; ++dt) {
        #pragma unroll
        for (int e = 0; e < 4; ++e) {
            int row = b * L_ + qb * 64 + wid * 16 + lg * 4 + e;
            o[(size_t)row * D_ + hh * 64 + dt * 16 + lr] = f2bf(accO[dt][e] / S[e]);
        }
    }
}

// ---------------------------------------------------------------------------
// fp32 fallback GEMM (tiny heads): C[M,N] = A[M,K]@B[K,N] + bias
template <int MODE>
__global__ __launch_bounds__(256) void k_gemm(float* __restrict__ C,
                                              const float* __restrict__ A,
                                              const float* __restrict__ Bm,
                                              const float* __restrict__ bias,
                                              int M, int N, int K) {
    __shared__ float As[16][68];
    __shared__ float Bs[16][68];
    int tid = threadIdx.x;
    int row0 = blockIdx.y * 64, col0 = blockIdx.x * 64;
    int ty = tid / 16, tx = tid % 16;
    int ar = tid / 4, ac = (tid % 4) * 4;
    int br = tid / 16, bc = (tid % 16) * 4;
    float acc[4][4] = {};
    for (int kt = 0; kt < K; kt += 16) {
        const float* ap = A + (size_t)(row0 + ar) * K + kt + ac;
        float4 av = *reinterpret_cast<const float4*>(ap);
        As[ac + 0][ar] = av.x; As[ac + 1][ar] = av.y;
        As[ac + 2][ar] = av.z; As[ac + 3][ar] = av.w;
        int gb = col0 + bc;
        const float* bp = Bm + (size_t)(kt + br) * N + gb;
        #pragma unroll
        for (int j = 0; j < 4; ++j)
            Bs[br][bc + j] = (gb + j < N) ? bp[j] : 0.0f;
        __syncthreads();
        #pragma unroll
        for (int k = 0; k < 16; ++k) {
            float4 a4 = *reinterpret_cast<const float4*>(&As[k][ty * 4]);
            float4 b4 = *reinterpret_cast<const float4*>(&Bs[k][tx * 4]);
            float a[4] = {a4.x, a4.y, a4.z, a4.w};
            float b[4] = {b4.x, b4.y, b4.z, b4.w};
            #pragma unroll
            for (int i = 0; i < 4; ++i)
                #pragma unroll
                for (int j = 0; j < 4; ++j) acc[i][j] += a[i] * b[j];
        }
        __syncthreads();
    }
    #pragma unroll
    for (int i = 0; i < 4; ++i) {
        int m = row0 + ty * 4 + i;
        #pragma unroll
        for (int j = 0; j < 4; ++j) {
            int n = col0 + tx * 4 + j;
            if (n < N) {
                float v = acc[i][j];
                if (bias) v += bias[n];
                C[(size_t)m * N + n] = v;
            }
        }
    }
}

// ---------------------------------------------------------------------------
extern "C" void kernel_launch(void* const* d_in, const int* in_sizes, int n_in,
                              void* d_out, int out_size, void* d_ws, size_t ws_size,
                              hipStream_t stream) {
    const float* patch        = (const float*)d_in[0];
    const float* box          = (const float*)d_in[1];
    const float* patch_W      = (const float*)d_in[2];
    const float* patch_b      = (const float*)d_in[3];
    const float* box_W        = (const float*)d_in[4];
    const float* box_b        = (const float*)d_in[5];
    const float* Wq           = (const float*)d_in[6];
    const float* Wk           = (const float*)d_in[7];
    const float* Wv           = (const float*)d_in[8];
    const float* Wo           = (const float*)d_in[9];
    const float* attn_norm_w  = (const float*)d_in[10];
    const float* gate_W       = (const float*)d_in[11];
    const float* hidden_W     = (const float*)d_in[12];
    const float* ffn_out_W    = (const float*)d_in[13];
    const float* ffn_norm_w   = (const float*)d_in[14];
    const float* reward_norm_w= (const float*)d_in[15];
    const float* reward_W     = (const float*)d_in[16];
    const float* reward_b     = (const float*)d_in[17];
    const float* label_norm_w = (const float*)d_in[18];
    const float* label_W      = (const float*)d_in[19];
    const float* label_b      = (const float*)d_in[20];
    const float* box_norm_w   = (const float*)d_in[21];
    const float* boxh_W       = (const float*)d_in[22];
    const float* boxh_b       = (const float*)d_in[23];

    char* w = (char*)d_ws;
    auto alloc = [&](size_t bytes) { char* p = w; w += (bytes + 255) & ~(size_t)255; return p; };

    u16*  wqkv   = (u16*)alloc((size_t)2304 * 768 * 2);
    u16*  wo_l   = (u16*)alloc((size_t)768 * 768 * 2);
    u16*  wgh    = (u16*)alloc((size_t)6144 * 768 * 2);
    u16*  wfo    = (u16*)alloc((size_t)768 * 3072 * 2);
    u16*  wpat   = (u16*)alloc((size_t)768 * 768 * 2);
    u16*  wbox   = (u16*)alloc((size_t)768 * 768 * 2);
    u16*  wlab   = (u16*)alloc((size_t)1024 * 768 * 2);
    u16*  patchb = (u16*)alloc((size_t)MTOK * 768 * 2);   // reused as qh after embed
    u16*  bsin   = (u16*)alloc((size_t)MTOK * 768 * 2);   // reused as kh after embed
    float* h     = (float*)alloc((size_t)MTOK * D_ * 4);
    u16*  hn_bf  = (u16*)alloc((size_t)MTOK * D_ * 2);
    u16*  qkv_bf = (u16*)alloc((size_t)MTOK * 2304 * 2);
    u16*  vT     = (u16*)alloc((size_t)MTOK * D_ * 2);
    float* tab   = (float*)alloc((size_t)L_ * 32 * 2 * 4);
    u16*  o_bf   = (u16*)alloc((size_t)MTOK * D_ * 2);
    u16*  gh_bf  = (u16*)alloc((size_t)MTOK * 6144 * 2);  // reused as hnf at heads
    u16*  ga_bf  = (u16*)alloc((size_t)MTOK * DFF_ * 2);
    float* part  = (float*)alloc((size_t)4 * MTOK * D_ * 4);  // split-K partials

    u16* qh = patchb;
    u16* kh = bsin;
    float* hnf = (float*)gh_bf;

    dim3 blk(256);
    int redgrid = (MTOK * D_ / 4 + 255) / 256;

    // one-time converts
    k_convT<<<dim3(24, 24), blk, 0, stream>>>(wpat, patch_W, 768, 768, 768);
    k_convT<<<dim3(24, 24), blk, 0, stream>>>(wbox, box_W, 768, 768, 768);
    k_convT<<<dim3(32, 24), blk, 0, stream>>>(wlab, label_W, 768, 1000, 1024);
    k_rope_tab<<<(L_ * 32 + 255) / 256, blk, 0, stream>>>(tab);
    k_cast<<<(MTOK * 768 / 4 + 255) / 256, blk, 0, stream>>>(patchb, patch, MTOK * 768 / 4);
    k_box_sin<<<(MTOK * D_ + 255) / 256, blk, 0, stream>>>(bsin, box);

    // embedding
    k_gemm_bf16<0><<<dim3(6, 32), blk, 0, stream>>>(h, patchb, wpat, patch_b, 768, 768, 768);
    k_gemm_bf16<1><<<dim3(6, 32), blk, 0, stream>>>(h, bsin,   wbox, box_b,   768, 768, 768);

    for (int ly = 0; ly < NL_; ++ly) {
        const float* wq  = Wq + (size_t)ly * D_ * D_;
        const float* wk  = Wk + (size_t)ly * D_ * D_;
        const float* wv  = Wv + (size_t)ly * D_ * D_;
        const float* wo  = Wo + (size_t)ly * D_ * D_;
        const float* anw = attn_norm_w + (size_t)ly * D_;
        const float* gw  = gate_W + (size_t)ly * D_ * DFF_;
        const float* hw  = hidden_W + (size_t)ly * D_ * DFF_;
        const float* ow  = ffn_out_W + (size_t)ly * DFF_ * D_;
        const float* fnw = ffn_norm_w + (size_t)ly * D_;

        k_convT<<<dim3(24, 24), blk, 0, stream>>>(wqkv,                 wq, 768, 768, 768);
        k_convT<<<dim3(24, 24), blk, 0, stream>>>(wqkv + 768 * 768,     wk, 768, 768, 768);
        k_convT<<<dim3(24, 24), blk, 0, stream>>>(wqkv + 2 * 768 * 768, wv, 768, 768, 768);
        k_rmsnorm<u16><<<MTOK, blk, 0, stream>>>(hn_bf, h, anw);
        k_gemm_bf16<3><<<dim3(18, 32), blk, 0, stream>>>(qkv_bf, hn_bf, wqkv, nullptr, 768, 2304, 2304);
        k_roper<<<(MTOK * 768 + 255) / 256, blk, 0, stream>>>(qh, kh, qkv_bf, tab);
        k_vt<<<dim3(96, 16), blk, 0, stream>>>(vT, qkv_bf);
        k_attn3<<<dim3(96, 8), blk, 0, stream>>>(o_bf, qh, kh, vT);
        k_convT<<<dim3(24, 24), blk, 0, stream>>>(wo_l, wo, 768, 768, 768);
        k_gemm_bf16<4><<<dim3(6, 32, 2), blk, 0, stream>>>(part, o_bf, wo_l, nullptr, 768, 768, 768);
        k_redadd<2><<<redgrid, blk, 0, stream>>>(h, part);

        k_rmsnorm<u16><<<MTOK, blk, 0, stream>>>(hn_bf, h, fnw);
        k_convT<<<dim3(96, 24), blk, 0, stream>>>(wgh,              gw, 768, 3072, 3072);
        k_convT<<<dim3(96, 24), blk, 0, stream>>>(wgh + 3072 * 768, hw, 768, 3072, 3072);
        k_gemm_bf16<3><<<dim3(48, 32), blk, 0, stream>>>(gh_bf, hn_bf, wgh, nullptr, 768, 6144, 6144);
        k_silu<<<(MTOK * DFF_ / 8 + 255) / 256, blk, 0, stream>>>(ga_bf, gh_bf);
        k_convT<<<dim3(24, 96), blk, 0, stream>>>(wfo, ow, 3072, 768, 768);
        k_gemm_bf16<4><<<dim3(6, 32, 4), blk, 0, stream>>>(part, ga_bf, wfo, nullptr, 3072, 768, 768);
        k_redadd<4><<<redgrid, blk, 0, stream>>>(h, part);
    }

    // heads
    float* out_reward = (float*)d_out;
    float* out_label  = out_reward + (size_t)MTOK * 2;
    float* out_box    = out_label + (size_t)MTOK * 1000;

    k_rmsnorm<u16><<<MTOK, blk, 0, stream>>>(hn_bf, h, label_norm_w);
    k_gemm_bf16<0><<<dim3(8, 32), blk, 0, stream>>>(out_label, hn_bf, wlab, label_b, 768, 1000, 1000);

    k_rmsnorm<float><<<MTOK, blk, 0, stream>>>(hnf, h, reward_norm_w);
    k_gemm<0><<<dim3(1, 64), blk, 0, stream>>>(out_reward, hnf, reward_W, reward_b, MTOK, 2, 768);
    k_rmsnorm<float><<<MTOK, blk, 0, stream>>>(hnf, h, box_norm_w);
    k_gemm<0><<<dim3(1, 64), blk, 0, stream>>>(out_box, hnf, boxh_W, boxh_b, MTOK, 4, 768);
}

// Round 6
// 2915.049 us; speedup vs baseline: 7.8881x; 1.1315x over previous
//
#include <hip/hip_runtime.h>
#include <math.h>
#include <type_traits>

#define B_   8
#define L_   512
#define MTOK 4096           // B_*L_
#define D_   768
#define NH_  12
#define DH_  64
#define DFF_ 3072
#define NL_  12

typedef unsigned short u16;
typedef __attribute__((ext_vector_type(4))) float f32x4;
typedef __attribute__((ext_vector_type(8))) short i16x8;
typedef __attribute__((ext_vector_type(8))) __bf16 b16x8;

// Pick whichever vector type the gfx950 bf16 MFMA builtin accepts.
template <typename A, typename = void>
struct PickFrag { using type = i16x8; };
template <typename A>
struct PickFrag<A, std::void_t<decltype(__builtin_amdgcn_mfma_f32_16x16x32_bf16(
    std::declval<A>(), std::declval<A>(), std::declval<f32x4>(), 0, 0, 0))>> {
  using type = A;
};
using frag_t = typename PickFrag<b16x8>::type;

#if __has_builtin(__builtin_amdgcn_global_load_lds)
#define HAS_GLDS 1
#else
#define HAS_GLDS 0
#endif

__device__ inline u16 f2bf(float f) {
    unsigned u = __float_as_uint(f);
    unsigned r = u + 0x7fffu + ((u >> 16) & 1u);
    return (u16)(r >> 16);
}
__device__ inline float bf2f(u16 b) { return __uint_as_float(((unsigned)b) << 16); }

// ---------------------------------------------------------------------------
// box sinusoid embedding -> bf16 into emb[t*1536 + 768 + d]
__global__ void k_box_sin(u16* __restrict__ emb, const float* __restrict__ box) {
    int idx = blockIdx.x * blockDim.x + threadIdx.x;
    if (idx >= MTOK * D_) return;
    int t = idx / D_, d = idx % D_;
    int c = d / 192, r = d % 192, j = r >> 1;
    float theta = __expf(-(float)j * (9.210340371976184f / 96.0f));
    float ang = box[t * 4 + c] * theta;
    emb[(size_t)t * 1536 + 768 + d] = f2bf((r & 1) ? sinf(ang) : cosf(ang));
}

// fp32 patch -> bf16 into emb[t*1536 + c]
__global__ void k_cast(u16* __restrict__ emb, const float* __restrict__ in, int n4) {
    int i = blockIdx.x * blockDim.x + threadIdx.x;
    if (i >= n4) return;            // n4 = MTOK*768/4
    int t = i / 192, c4 = (i % 192) * 4;
    float4 v = *reinterpret_cast<const float4*>(in + (size_t)t * 768 + c4);
    unsigned lo = (unsigned)f2bf(v.x) | ((unsigned)f2bf(v.y) << 16);
    unsigned hi = (unsigned)f2bf(v.z) | ((unsigned)f2bf(v.w) << 16);
    *reinterpret_cast<uint2*>(emb + (size_t)t * 1536 + c4) = make_uint2(lo, hi);
}

// combined bias
__global__ void k_addb(float* __restrict__ dst, const float* __restrict__ a,
                       const float* __restrict__ b) {
    int i = blockIdx.x * blockDim.x + threadIdx.x;
    if (i < D_) dst[i] = a[i] + b[i];
}

// ---------------------------------------------------------------------------
// transpose-convert: src (K,N) fp32 -> dst[(n*rs+ro)*ld + co + k] bf16
// zero rows for n>=N (padding). ld must cover co+K.
__global__ __launch_bounds__(256) void k_convT(u16* __restrict__ dst,
                                               const float* __restrict__ src,
                                               int K, int N, int ld, int rs,
                                               int ro, int co) {
    __shared__ float t[32][33];
    int bn = blockIdx.x * 32;
    int bk = blockIdx.y * 32;
    int tx = threadIdx.x % 32, ty = threadIdx.x / 32;
    #pragma unroll
    for (int i = 0; i < 4; ++i) {
        int k = bk + ty + i * 8;
        int n = bn + tx;
        t[ty + i * 8][tx] = (n < N) ? src[(size_t)k * N + n] : 0.0f;
    }
    __syncthreads();
    #pragma unroll
    for (int i = 0; i < 4; ++i) {
        int n = bn + ty + i * 8;   // dst logical row
        int k = bk + tx;           // dst col
        dst[(size_t)(n * rs + ro) * ld + co + k] = f2bf(t[tx][ty + i * 8]);
    }
}

// ---------------------------------------------------------------------------
// RMSNorm: one block per token, bf16 out
__global__ __launch_bounds__(256) void k_rmsnorm(u16* __restrict__ out,
                                                 const float* __restrict__ in,
                                                 const float* __restrict__ w) {
    int t = blockIdx.x;
    const float* x = in + (size_t)t * D_;
    float ss = 0.f;
    for (int i = threadIdx.x; i < D_; i += 256) { float v = x[i]; ss += v * v; }
    for (int off = 32; off > 0; off >>= 1) ss += __shfl_down(ss, off);
    __shared__ float red[4];
    int wid = threadIdx.x >> 6, lane = threadIdx.x & 63;
    if (lane == 0) red[wid] = ss;
    __syncthreads();
    float tot = red[0] + red[1] + red[2] + red[3];
    float inv = rsqrtf(tot / (float)D_ + 1e-6f);
    for (int i = threadIdx.x; i < D_; i += 256)
        out[(size_t)t * D_ + i] = f2bf(x[i] * inv * w[i]);
}

// ---------------------------------------------------------------------------
// fused: h += sum_s part[s]; hn = bf16(rmsnorm(h, w)). one block per token.
template <int S>
__global__ __launch_bounds__(256) void k_fused_rr(float* __restrict__ h,
                                                  const float* __restrict__ part,
                                                  u16* __restrict__ hn,
                                                  const float* __restrict__ w) {
    int t = blockIdx.x;
    size_t base = (size_t)t * D_;
    float x[3];
    float ss = 0.f;
    #pragma unroll
    for (int c = 0; c < 3; ++c) {
        int i = threadIdx.x + c * 256;
        float v = h[base + i];
        #pragma unroll
        for (int s = 0; s < S; ++s)
            v += part[(size_t)s * MTOK * D_ + base + i];
        x[c] = v;
        h[base + i] = v;
        ss += v * v;
    }
    for (int off = 32; off > 0; off >>= 1) ss += __shfl_down(ss, off);
    __shared__ float red[4];
    int wid = threadIdx.x >> 6, lane = threadIdx.x & 63;
    if (lane == 0) red[wid] = ss;
    __syncthreads();
    float tot = red[0] + red[1] + red[2] + red[3];
    float inv = rsqrtf(tot / (float)D_ + 1e-6f);
    #pragma unroll
    for (int c = 0; c < 3; ++c) {
        int i = threadIdx.x + c * 256;
        hn[base + i] = f2bf(x[c] * inv * w[i]);
    }
}

// ---------------------------------------------------------------------------
// one-time RoPE table: tab[(l*32+j)*2] = cos(l*theta_j), +1 = sin
__global__ void k_rope_tab(float* __restrict__ tab) {
    int idx = blockIdx.x * blockDim.x + threadIdx.x;   // 512*32
    if (idx >= L_ * 32) return;
    int l = idx >> 5, j = idx & 31;
    float theta = __expf(-(float)j * (9.210340371976184f / 32.0f));
    float s, c;
    sincosf((float)l * theta, &s, &c);
    tab[idx * 2] = c;
    tab[idx * 2 + 1] = s;
}

// ---------------------------------------------------------------------------
// fused q/k rope+relayout + v transpose. grid (96 bh, 16 lb), 256 thr.
// qkv (MTOK,2304) bf16 -> qh (scaled by 1/8), kh: [96][512][64]; vT: [96][64][512]
__global__ __launch_bounds__(256) void k_qkvprep(u16* __restrict__ qh,
                                                 u16* __restrict__ kh,
                                                 u16* __restrict__ vT,
                                                 const u16* __restrict__ qkv,
                                                 const float* __restrict__ tab) {
    int bh = blockIdx.x, lb = blockIdx.y;
    int b = bh / NH_, hh = bh % NH_;
    int tid = threadIdx.x;
    int r = tid >> 3, c8 = (tid & 7) * 8;     // 32 rows x 64 cols
    int l = lb * 32 + r;
    size_t rowbase = ((size_t)(b * L_ + l)) * 2304 + hh * 64 + c8;

    float2 cs[4];
    #pragma unroll
    for (int p = 0; p < 4; ++p)
        cs[p] = *reinterpret_cast<const float2*>(tab + ((size_t)l * 32 + (c8 >> 1) + p) * 2);

    {   // Q: rope + fold 1/8 score scale
        uint4 v4 = *reinterpret_cast<const uint4*>(qkv + rowbase);
        const u16* pv = reinterpret_cast<const u16*>(&v4);
        u16 out[8];
        #pragma unroll
        for (int p = 0; p < 4; ++p) {
            float xr = bf2f(pv[2 * p]), xi = bf2f(pv[2 * p + 1]);
            out[2 * p]     = f2bf((xr * cs[p].x - xi * cs[p].y) * 0.125f);
            out[2 * p + 1] = f2bf((xr * cs[p].y + xi * cs[p].x) * 0.125f);
        }
        *reinterpret_cast<uint4*>(qh + ((size_t)bh * L_ + l) * 64 + c8) =
            *reinterpret_cast<uint4*>(out);
    }
    {   // K: rope
        uint4 v4 = *reinterpret_cast<const uint4*>(qkv + rowbase + 768);
        const u16* pv = reinterpret_cast<const u16*>(&v4);
        u16 out[8];
        #pragma unroll
        for (int p = 0; p < 4; ++p) {
            float xr = bf2f(pv[2 * p]), xi = bf2f(pv[2 * p + 1]);
            out[2 * p]     = f2bf(xr * cs[p].x - xi * cs[p].y);
            out[2 * p + 1] = f2bf(xr * cs[p].y + xi * cs[p].x);
        }
        *reinterpret_cast<uint4*>(kh + ((size_t)bh * L_ + l) * 64 + c8) =
            *reinterpret_cast<uint4*>(out);
    }
    // V transpose via LDS
    __shared__ u16 ts[64][40];
    {
        uint4 v4 = *reinterpret_cast<const uint4*>(qkv + rowbase + 1536);
        const u16* pv = reinterpret_cast<const u16*>(&v4);
        #pragma unroll
        for (int j = 0; j < 8; ++j) ts[c8 + j][r] = pv[j];
    }
    __syncthreads();
    {
        int d = tid >> 2, l0 = (tid & 3) * 8;
        uint4 o4 = *reinterpret_cast<const uint4*>(&ts[d][l0]);
        *reinterpret_cast<uint4*>(vT + ((size_t)bh * 64 + d) * L_ + lb * 32 + l0) = o4;
    }
}

// ---------------------------------------------------------------------------
// bf16 MFMA GEMM with global_load_lds staging, XCD swizzle, optional split-K.
// C[M x Nout](ldC) (+)= A[M,K]bf16 @ BT[Nt,K]bf16^T (+bias)
// grid = (Nt/128, M/128, SPLITK), 256 threads. K % (32*SPLITK) == 0.
// MODE 0: C=acc(+bias) f32   MODE 3: C=acc bf16
// MODE 4: partial fp32 store to Cp + sk*M*ldC (split-K)
// MODE 5: silu-gate pairs: C bf16 [M x Nout/2], out[:,c/2]=silu(acc_even)*acc_odd
template <int MODE>
__global__ __launch_bounds__(256) void k_gemm_bf16(void* __restrict__ Cp,
                                                   const u16* __restrict__ A,
                                                   const u16* __restrict__ BT,
                                                   const float* __restrict__ bias,
                                                   int K, int Nout, int ldC) {
    __shared__ u16 As[128 * 32];
    __shared__ u16 Bs[128 * 32];
    int tid = threadIdx.x;
    int wid = tid >> 6, lane = tid & 63;

    // ---- XCD-aware swizzle over full 3D linear block id (nwg % 8 == 0) ----
    int nx = gridDim.x, ny = gridDim.y, nz = gridDim.z;
    int bid = ((blockIdx.z * ny) + blockIdx.y) * nx + blockIdx.x;
    int nwg = nx * ny * nz;
    int cpx = nwg >> 3;
    int swz = (bid & 7) * cpx + (bid >> 3);
    int sk  = swz / (nx * ny);
    int rem = swz % (nx * ny);
    int by = rem / nx, bx = rem % nx;
    int row0 = by * 128, col0 = bx * 128;
    int wr = wid >> 1, wc = wid & 1;

    int Klen = K / nz;
    int kbeg = sk * Klen;

    f32x4 acc[4][4] = {};
    int lrow = lane & 15, lk = (lane >> 4) * 8;

    for (int kt = 0; kt < Klen; kt += 32) {
        #pragma unroll
        for (int i = 0; i < 2; ++i) {
            int chunk = wid * 128 + i * 64 + lane;        // 0..511
            int r = chunk >> 2;
            int kc = (chunk & 3) * 8;
            const u16* ga = A  + (size_t)(row0 + r) * K + kbeg + kt + kc;
            const u16* gb = BT + (size_t)(col0 + r) * K + kbeg + kt + kc;
#if HAS_GLDS
            __builtin_amdgcn_global_load_lds(
                (const __attribute__((address_space(1))) void*)ga,
                (__attribute__((address_space(3))) void*)&As[(wid * 128 + i * 64) * 8],
                16, 0, 0);
            __builtin_amdgcn_global_load_lds(
                (const __attribute__((address_space(1))) void*)gb,
                (__attribute__((address_space(3))) void*)&Bs[(wid * 128 + i * 64) * 8],
                16, 0, 0);
#else
            *reinterpret_cast<uint4*>(&As[chunk * 8]) = *reinterpret_cast<const uint4*>(ga);
            *reinterpret_cast<uint4*>(&Bs[chunk * 8]) = *reinterpret_cast<const uint4*>(gb);
#endif
        }
        __syncthreads();
        frag_t af[4], bfr[4];
        #pragma unroll
        for (int m = 0; m < 4; ++m)
            af[m] = *reinterpret_cast<const frag_t*>(&As[(wr * 64 + m * 16 + lrow) * 32 + lk]);
        #pragma unroll
        for (int n = 0; n < 4; ++n)
            bfr[n] = *reinterpret_cast<const frag_t*>(&Bs[(wc * 64 + n * 16 + lrow) * 32 + lk]);
        #pragma unroll
        for (int m = 0; m < 4; ++m)
            #pragma unroll
            for (int n = 0; n < 4; ++n)
                acc[m][n] = __builtin_amdgcn_mfma_f32_16x16x32_bf16(af[m], bfr[n], acc[m][n], 0, 0, 0);
        __syncthreads();
    }

    float* Cpart = (MODE == 4)
        ? ((float*)Cp + (size_t)sk * (size_t)(ny * 128) * ldC) : (float*)Cp;

    int lcol = lane & 15, rb = (lane >> 4) * 4;
    #pragma unroll
    for (int m = 0; m < 4; ++m) {
        #pragma unroll
        for (int n = 0; n < 4; ++n) {
            int col = col0 + wc * 64 + n * 16 + lcol;
            if (col >= Nout) continue;
            #pragma unroll
            for (int e = 0; e < 4; ++e) {
                int row = row0 + wr * 64 + m * 16 + rb + e;
                float v = acc[m][n][e];
                size_t off = (size_t)row * ldC + col;
                if (MODE == 0) {
                    if (bias) v += bias[col];
                    ((float*)Cp)[off] = v;
                } else if (MODE == 3) {
                    ((u16*)Cp)[off] = f2bf(v);
                } else if (MODE == 4) {
                    Cpart[off] = v;
                } else if (MODE == 5) {
                    float other = __shfl_xor(v, 1);
                    if ((lcol & 1) == 0) {
                        float s = v / (1.0f + __expf(-v));
                        ((u16*)Cp)[(size_t)row * ldC + (col >> 1)] = f2bf(s * other);
                    }
                }
            }
        }
    }
}

// ---------------------------------------------------------------------------
// MFMA flash attention. grid (96 bh, 8 qb), 256 thr = 4 waves x 16 q-rows.
// qh (pre-scaled 1/8), kh: [96][512][64] bf16; vT: [96][64][512] bf16.
__global__ __launch_bounds__(256) void k_attn3(u16* __restrict__ o,
                                               const u16* __restrict__ qh,
                                               const u16* __restrict__ kh,
                                               const u16* __restrict__ vT) {
    int bh = blockIdx.x, qb = blockIdx.y;
    int b = bh / NH_, hh = bh % NH_;
    int tid = threadIdx.x, wid = tid >> 6, lane = tid & 63;
    __shared__ u16 Qs[64][72], Ks[64][72], Vs[64][72], Ps[64][72];

    #pragma unroll
    for (int i = 0; i < 2; ++i) {
        int idx = tid + i * 256;
        int r = idx >> 3, c8 = (idx & 7) * 8;
        uint4 v4 = *reinterpret_cast<const uint4*>(
            qh + ((size_t)bh * L_ + qb * 64 + r) * 64 + c8);
        *reinterpret_cast<uint4*>(&Qs[r][c8]) = v4;
    }
    __syncthreads();

    int lr = lane & 15, lg = lane >> 4;
    frag_t aq[2];
    #pragma unroll
    for (int kd = 0; kd < 2; ++kd)
        aq[kd] = *reinterpret_cast<const frag_t*>(&Qs[wid * 16 + lr][kd * 32 + lg * 8]);

    f32x4 accO[4] = {};
    float M[4], S[4];
    #pragma unroll
    for (int e = 0; e < 4; ++e) { M[e] = -INFINITY; S[e] = 0.f; }

    for (int kb = 0; kb <= qb; ++kb) {
        __syncthreads();
        #pragma unroll
        for (int i = 0; i < 2; ++i) {
            int idx = tid + i * 256;
            int r = idx >> 3, c8 = (idx & 7) * 8;
            *reinterpret_cast<uint4*>(&Ks[r][c8]) = *reinterpret_cast<const uint4*>(
                kh + ((size_t)bh * L_ + kb * 64 + r) * 64 + c8);
            *reinterpret_cast<uint4*>(&Vs[r][c8]) = *reinterpret_cast<const uint4*>(
                vT + ((size_t)bh * 64 + r) * L_ + kb * 64 + c8);
        }
        __syncthreads();

        f32x4 sv[4];
        #pragma unroll
        for (int ct = 0; ct < 4; ++ct) {
            frag_t bk0 = *reinterpret_cast<const frag_t*>(&Ks[ct * 16 + lr][lg * 8]);
            frag_t bk1 = *reinterpret_cast<const frag_t*>(&Ks[ct * 16 + lr][32 + lg * 8]);
            f32x4 z = {0.f, 0.f, 0.f, 0.f};
            z = __builtin_amdgcn_mfma_f32_16x16x32_bf16(aq[0], bk0, z, 0, 0, 0);
            sv[ct] = __builtin_amdgcn_mfma_f32_16x16x32_bf16(aq[1], bk1, z, 0, 0, 0);
        }

        bool diag = (kb == qb);
        float esc[4];
        #pragma unroll
        for (int e = 0; e < 4; ++e) {
            int qg = qb * 64 + wid * 16 + lg * 4 + e;
            float mx = -1e30f;
            #pragma unroll
            for (int ct = 0; ct < 4; ++ct) {
                float s = sv[ct][e];
                if (diag && (kb * 64 + ct * 16 + lr > qg)) s = -1e30f;
                sv[ct][e] = s;
                mx = fmaxf(mx, s);
            }
            #pragma unroll
            for (int msk = 8; msk; msk >>= 1) mx = fmaxf(mx, __shfl_xor(mx, msk));
            float newM = fmaxf(M[e], mx);
            float ps = 0.f;
            #pragma unroll
            for (int ct = 0; ct < 4; ++ct) {
                float p = __expf(sv[ct][e] - newM);
                sv[ct][e] = p;
                ps += p;
            }
            #pragma unroll
            for (int msk = 8; msk; msk >>= 1) ps += __shfl_xor(ps, msk);
            esc[e] = __expf(M[e] - newM);
            S[e] = S[e] * esc[e] + ps;
            M[e] = newM;
        }
        #pragma unroll
        for (int dt = 0; dt < 4; ++dt)
            #pragma unroll
            for (int e = 0; e < 4; ++e) accO[dt][e] *= esc[e];

        #pragma unroll
        for (int ct = 0; ct < 4; ++ct)
            #pragma unroll
            for (int e = 0; e < 4; ++e)
                Ps[wid * 16 + lg * 4 + e][ct * 16 + lr] = f2bf(sv[ct][e]);

        frag_t pa0 = *reinterpret_cast<const frag_t*>(&Ps[wid * 16 + lr][lg * 8]);
        frag_t pa1 = *reinterpret_cast<const frag_t*>(&Ps[wid * 16 + lr][32 + lg * 8]);
        #pragma unroll
        for (int dt = 0; dt < 4; ++dt) {
            frag_t bv0 = *reinterpret_cast<const frag_t*>(&Vs[dt * 16 + lr][lg * 8]);
            frag_t bv1 = *reinterpret_cast<const frag_t*>(&Vs[dt * 16 + lr][32 + lg * 8]);
            accO[dt] = __builtin_amdgcn_mfma_f32_16x16x32_bf16(pa0, bv0, accO[dt], 0, 0, 0);
            accO[dt] = __builtin_amdgcn_mfma_f32_16x16x32_bf16(pa1, bv1, accO[dt], 0, 0, 0);
        }
    }

    #pragma unroll
    for (int dt = 0; dt < 4; ++dt) {
        #pragma unroll
        for (int e = 0; e < 4; ++e) {
            int row = b * L_ + qb * 64 + wid * 16 + lg * 4 + e;
            o[(size_t)row * D_ + hh * 64 + dt * 16 + lr] = f2bf(accO[dt][e] / S[e]);
        }
    }
}

// ---------------------------------------------------------------------------
// tiny heads: per token, shared rsqrt; reward (2) + box (4) dot products.
__global__ __launch_bounds__(256) void k_heads3(float* __restrict__ out_reward,
                                                float* __restrict__ out_box,
                                                const float* __restrict__ h,
                                                const float* __restrict__ rnw,
                                                const float* __restrict__ rW,
                                                const float* __restrict__ rb,
                                                const float* __restrict__ bnw,
                                                const float* __restrict__ bW,
                                                const float* __restrict__ bb) {
    int t = blockIdx.x;
    size_t base = (size_t)t * D_;
    float x[3];
    float ss = 0.f;
    #pragma unroll
    for (int c = 0; c < 3; ++c) {
        int i = threadIdx.x + c * 256;
        x[c] = h[base + i];
        ss += x[c] * x[c];
    }
    for (int off = 32; off > 0; off >>= 1) ss += __shfl_down(ss, off);
    __shared__ float red[4];
    int wid = threadIdx.x >> 6, lane = threadIdx.x & 63;
    if (lane == 0) red[wid] = ss;
    __syncthreads();
    float inv = rsqrtf((red[0] + red[1] + red[2] + red[3]) / (float)D_ + 1e-6f);

    float a[6] = {};
    #pragma unroll
    for (int c = 0; c < 3; ++c) {
        int i = threadIdx.x + c * 256;
        float xr = x[c] * inv;
        float xw = xr * rnw[i];
        a[0] += xw * rW[i * 2];
        a[1] += xw * rW[i * 2 + 1];
        float xb = xr * bnw[i];
        #pragma unroll
        for (int j = 0; j < 4; ++j) a[2 + j] += xb * bW[i * 4 + j];
    }
    #pragma unroll
    for (int j = 0; j < 6; ++j)
        for (int off = 32; off > 0; off >>= 1) a[j] += __shfl_down(a[j], off);
    __shared__ float red2[4][6];
    if (lane == 0)
        #pragma unroll
        for (int j = 0; j < 6; ++j) red2[wid][j] = a[j];
    __syncthreads();
    if (threadIdx.x < 6) {
        float s = red2[0][threadIdx.x] + red2[1][threadIdx.x] +
                  red2[2][threadIdx.x] + red2[3][threadIdx.x];
        if (threadIdx.x < 2) out_reward[(size_t)t * 2 + threadIdx.x] = s + rb[threadIdx.x];
        else                 out_box[(size_t)t * 4 + threadIdx.x - 2] = s + bb[threadIdx.x - 2];
    }
}

// ---------------------------------------------------------------------------
extern "C" void kernel_launch(void* const* d_in, const int* in_sizes, int n_in,
                              void* d_out, int out_size, void* d_ws, size_t ws_size,
                              hipStream_t stream) {
    const float* patch        = (const float*)d_in[0];
    const float* box          = (const float*)d_in[1];
    const float* patch_W      = (const float*)d_in[2];
    const float* patch_b      = (const float*)d_in[3];
    const float* box_W        = (const float*)d_in[4];
    const float* box_b        = (const float*)d_in[5];
    const float* Wq           = (const float*)d_in[6];
    const float* Wk           = (const float*)d_in[7];
    const float* Wv           = (const float*)d_in[8];
    const float* Wo           = (const float*)d_in[9];
    const float* attn_norm_w  = (const float*)d_in[10];
    const float* gate_W       = (const float*)d_in[11];
    const float* hidden_W     = (const float*)d_in[12];
    const float* ffn_out_W    = (const float*)d_in[13];
    const float* ffn_norm_w   = (const float*)d_in[14];
    const float* reward_norm_w= (const float*)d_in[15];
    const float* reward_W     = (const float*)d_in[16];
    const float* reward_b     = (const float*)d_in[17];
    const float* label_norm_w = (const float*)d_in[18];
    const float* label_W      = (const float*)d_in[19];
    const float* label_b      = (const float*)d_in[20];
    const float* box_norm_w   = (const float*)d_in[21];
    const float* boxh_W       = (const float*)d_in[22];
    const float* boxh_b       = (const float*)d_in[23];

    char* w = (char*)d_ws;
    auto alloc = [&](size_t bytes) { char* p = w; w += (bytes + 255) & ~(size_t)255; return p; };

    u16*  wqkv   = (u16*)alloc((size_t)2304 * 768 * 2);
    u16*  wo_l   = (u16*)alloc((size_t)768 * 768 * 2);
    u16*  wgh    = (u16*)alloc((size_t)6144 * 768 * 2);   // interleaved gate/hidden
    u16*  wfo    = (u16*)alloc((size_t)768 * 3072 * 2);
    u16*  wcat   = (u16*)alloc((size_t)768 * 1536 * 2);   // patch|box weights
    u16*  wlab   = (u16*)alloc((size_t)1024 * 768 * 2);
    float* bias_c= (float*)alloc((size_t)768 * 4);
    u16*  emb    = (u16*)alloc((size_t)MTOK * 1536 * 2);  // reused as qh|kh
    float* h     = (float*)alloc((size_t)MTOK * D_ * 4);
    u16*  hn_bf  = (u16*)alloc((size_t)MTOK * D_ * 2);
    u16*  qkv_bf = (u16*)alloc((size_t)MTOK * 2304 * 2);
    u16*  vT     = (u16*)alloc((size_t)MTOK * D_ * 2);
    float* tab   = (float*)alloc((size_t)L_ * 32 * 2 * 4);
    u16*  o_bf   = (u16*)alloc((size_t)MTOK * D_ * 2);
    u16*  ga_bf  = (u16*)alloc((size_t)MTOK * DFF_ * 2);
    float* part  = (float*)alloc((size_t)4 * MTOK * D_ * 4);

    u16* qh = emb;                       // emb dead after embedding GEMM
    u16* kh = emb + (size_t)MTOK * 768;

    dim3 blk(256);

    // one-time converts
    k_convT<<<dim3(24, 24), blk, 0, stream>>>(wcat, patch_W, 768, 768, 1536, 1, 0, 0);
    k_convT<<<dim3(24, 24), blk, 0, stream>>>(wcat, box_W,   768, 768, 1536, 1, 0, 768);
    k_convT<<<dim3(32, 24), blk, 0, stream>>>(wlab, label_W, 768, 1000, 768, 1, 0, 0);
    k_addb<<<3, blk, 0, stream>>>(bias_c, patch_b, box_b);
    k_rope_tab<<<(L_ * 32 + 255) / 256, blk, 0, stream>>>(tab);
    k_cast<<<(MTOK * 768 / 4 + 255) / 256, blk, 0, stream>>>(emb, patch, MTOK * 768 / 4);
    k_box_sin<<<(MTOK * D_ + 255) / 256, blk, 0, stream>>>(emb, box);

    // embedding: h = [patch|box_sin] @ [patch_W; box_W] + (patch_b+box_b)
    k_gemm_bf16<0><<<dim3(6, 32), blk, 0, stream>>>(h, emb, wcat, bias_c, 1536, 768, 768);
    k_rmsnorm<<<MTOK, blk, 0, stream>>>(hn_bf, h, attn_norm_w);

    for (int ly = 0; ly < NL_; ++ly) {
        const float* wq  = Wq + (size_t)ly * D_ * D_;
        const float* wk  = Wk + (size_t)ly * D_ * D_;
        const float* wv  = Wv + (size_t)ly * D_ * D_;
        const float* wo  = Wo + (size_t)ly * D_ * D_;
        const float* gw  = gate_W + (size_t)ly * D_ * DFF_;
        const float* hw  = hidden_W + (size_t)ly * D_ * DFF_;
        const float* ow  = ffn_out_W + (size_t)ly * DFF_ * D_;
        const float* fnw = ffn_norm_w + (size_t)ly * D_;
        const float* nxt = (ly + 1 < NL_) ? attn_norm_w + (size_t)(ly + 1) * D_
                                          : label_norm_w;

        k_convT<<<dim3(24, 24), blk, 0, stream>>>(wqkv,                 wq, 768, 768, 768, 1, 0, 0);
        k_convT<<<dim3(24, 24), blk, 0, stream>>>(wqkv + 768 * 768,     wk, 768, 768, 768, 1, 0, 0);
        k_convT<<<dim3(24, 24), blk, 0, stream>>>(wqkv + 2 * 768 * 768, wv, 768, 768, 768, 1, 0, 0);
        k_gemm_bf16<3><<<dim3(18, 32), blk, 0, stream>>>(qkv_bf, hn_bf, wqkv, nullptr, 768, 2304, 2304);
        k_qkvprep<<<dim3(96, 16), blk, 0, stream>>>(qh, kh, vT, qkv_bf, tab);
        k_attn3<<<dim3(96, 8), blk, 0, stream>>>(o_bf, qh, kh, vT);
        k_convT<<<dim3(24, 24), blk, 0, stream>>>(wo_l, wo, 768, 768, 768, 1, 0, 0);
        k_gemm_bf16<4><<<dim3(6, 32, 2), blk, 0, stream>>>(part, o_bf, wo_l, nullptr, 768, 768, 768);
        k_fused_rr<2><<<MTOK, blk, 0, stream>>>(h, part, hn_bf, fnw);

        k_convT<<<dim3(96, 24), blk, 0, stream>>>(wgh, gw, 768, 3072, 768, 2, 0, 0);
        k_convT<<<dim3(96, 24), blk, 0, stream>>>(wgh, hw, 768, 3072, 768, 2, 1, 0);
        k_gemm_bf16<5><<<dim3(48, 32), blk, 0, stream>>>(ga_bf, hn_bf, wgh, nullptr, 768, 6144, 3072);
        k_convT<<<dim3(24, 96), blk, 0, stream>>>(wfo, ow, 3072, 768, 3072, 1, 0, 0);
        k_gemm_bf16<4><<<dim3(6, 32, 4), blk, 0, stream>>>(part, ga_bf, wfo, nullptr, 3072, 768, 768);
        k_fused_rr<4><<<MTOK, blk, 0, stream>>>(h, part, hn_bf, nxt);
    }

    // heads: hn_bf already = rmsnorm(h, label_norm_w)
    float* out_reward = (float*)d_out;
    float* out_label  = out_reward + (size_t)MTOK * 2;
    float* out_box    = out_label + (size_t)MTOK * 1000;

    k_gemm_bf16<0><<<dim3(8, 32), blk, 0, stream>>>(out_label, hn_bf, wlab, label_b, 768, 1000, 1000);
    k_heads3<<<MTOK, blk, 0, stream>>>(out_reward, out_box, h,
                                       reward_norm_w, reward_W, reward_b,
                                       box_norm_w, boxh_W, boxh_b);
}

// Round 7
// 2528.223 us; speedup vs baseline: 9.0951x; 1.1530x over previous
//
#include <hip/hip_runtime.h>
#include <math.h>
#include <type_traits>

#define B_   8
#define L_   512
#define MTOK 4096           // B_*L_
#define D_   768
#define NH_  12
#define DH_  64
#define DFF_ 3072
#define NL_  12

typedef unsigned short u16;
typedef __attribute__((ext_vector_type(4))) float f32x4;
typedef __attribute__((ext_vector_type(8))) short i16x8;
typedef __attribute__((ext_vector_type(8))) __bf16 b16x8;

// Pick whichever vector type the gfx950 bf16 MFMA builtin accepts.
template <typename A, typename = void>
struct PickFrag { using type = i16x8; };
template <typename A>
struct PickFrag<A, std::void_t<decltype(__builtin_amdgcn_mfma_f32_16x16x32_bf16(
    std::declval<A>(), std::declval<A>(), std::declval<f32x4>(), 0, 0, 0))>> {
  using type = A;
};
using frag_t = typename PickFrag<b16x8>::type;

#if __has_builtin(__builtin_amdgcn_global_load_lds)
#define HAS_GLDS 1
#else
#define HAS_GLDS 0
#endif

__device__ inline u16 f2bf(float f) {
    unsigned u = __float_as_uint(f);
    unsigned r = u + 0x7fffu + ((u >> 16) & 1u);
    return (u16)(r >> 16);
}
__device__ inline float bf2f(u16 b) { return __uint_as_float(((unsigned)b) << 16); }

// ---------------------------------------------------------------------------
// box sinusoid embedding -> bf16 into emb[t*1536 + 768 + d]
__global__ void k_box_sin(u16* __restrict__ emb, const float* __restrict__ box) {
    int idx = blockIdx.x * blockDim.x + threadIdx.x;
    if (idx >= MTOK * D_) return;
    int t = idx / D_, d = idx % D_;
    int c = d / 192, r = d % 192, j = r >> 1;
    float theta = __expf(-(float)j * (9.210340371976184f / 96.0f));
    float ang = box[t * 4 + c] * theta;
    emb[(size_t)t * 1536 + 768 + d] = f2bf((r & 1) ? sinf(ang) : cosf(ang));
}

// fp32 patch -> bf16 into emb[t*1536 + c]
__global__ void k_cast(u16* __restrict__ emb, const float* __restrict__ in, int n4) {
    int i = blockIdx.x * blockDim.x + threadIdx.x;
    if (i >= n4) return;            // n4 = MTOK*768/4
    int t = i / 192, c4 = (i % 192) * 4;
    float4 v = *reinterpret_cast<const float4*>(in + (size_t)t * 768 + c4);
    unsigned lo = (unsigned)f2bf(v.x) | ((unsigned)f2bf(v.y) << 16);
    unsigned hi = (unsigned)f2bf(v.z) | ((unsigned)f2bf(v.w) << 16);
    *reinterpret_cast<uint2*>(emb + (size_t)t * 1536 + c4) = make_uint2(lo, hi);
}

// combined bias
__global__ void k_addb(float* __restrict__ dst, const float* __restrict__ a,
                       const float* __restrict__ b) {
    int i = blockIdx.x * blockDim.x + threadIdx.x;
    if (i < D_) dst[i] = a[i] + b[i];
}

// ---------------------------------------------------------------------------
// generic transpose-convert: src (K,N) fp32 -> dst[(n*rs+ro)*ld + co + k] bf16
// zero rows for n>=N (padding). ld must cover co+K.
__global__ __launch_bounds__(256) void k_convT(u16* __restrict__ dst,
                                               const float* __restrict__ src,
                                               int K, int N, int ld, int rs,
                                               int ro, int co) {
    __shared__ float t[32][33];
    int bn = blockIdx.x * 32;
    int bk = blockIdx.y * 32;
    int tx = threadIdx.x % 32, ty = threadIdx.x / 32;
    #pragma unroll
    for (int i = 0; i < 4; ++i) {
        int k = bk + ty + i * 8;
        int n = bn + tx;
        t[ty + i * 8][tx] = (n < N) ? src[(size_t)k * N + n] : 0.0f;
    }
    __syncthreads();
    #pragma unroll
    for (int i = 0; i < 4; ++i) {
        int n = bn + ty + i * 8;   // dst logical row
        int k = bk + tx;           // dst col
        dst[(size_t)(n * rs + ro) * ld + co + k] = f2bf(t[tx][ty + i * 8]);
    }
}

// merged QKV convert: grid (24,24,3). srcs (768,768) -> dst + z*768*768, (768,768)^T
__global__ __launch_bounds__(256) void k_convT_qkv(u16* __restrict__ dst,
                                                   const float* __restrict__ s0,
                                                   const float* __restrict__ s1,
                                                   const float* __restrict__ s2) {
    __shared__ float t[32][33];
    const float* src = blockIdx.z == 0 ? s0 : (blockIdx.z == 1 ? s1 : s2);
    u16* d = dst + (size_t)blockIdx.z * 768 * 768;
    int bn = blockIdx.x * 32, bk = blockIdx.y * 32;
    int tx = threadIdx.x % 32, ty = threadIdx.x / 32;
    #pragma unroll
    for (int i = 0; i < 4; ++i)
        t[ty + i * 8][tx] = src[(size_t)(bk + ty + i * 8) * 768 + bn + tx];
    __syncthreads();
    #pragma unroll
    for (int i = 0; i < 4; ++i) {
        int n = bn + ty + i * 8, k = bk + tx;
        d[(size_t)n * 768 + k] = f2bf(t[tx][ty + i * 8]);
    }
}

// merged gate/hidden convert with 16-col group interleave:
// grid (96,24,2). srcs (768,3072). logical col n -> dst row (n>>4)*32 + (n&15) + z*16
__global__ __launch_bounds__(256) void k_convT_gh(u16* __restrict__ dst,
                                                  const float* __restrict__ g,
                                                  const float* __restrict__ h) {
    __shared__ float t[32][33];
    const float* src = blockIdx.z ? h : g;
    int ro = blockIdx.z * 16;
    int bn = blockIdx.x * 32, bk = blockIdx.y * 32;
    int tx = threadIdx.x % 32, ty = threadIdx.x / 32;
    #pragma unroll
    for (int i = 0; i < 4; ++i)
        t[ty + i * 8][tx] = src[(size_t)(bk + ty + i * 8) * 3072 + bn + tx];
    __syncthreads();
    #pragma unroll
    for (int i = 0; i < 4; ++i) {
        int n = bn + ty + i * 8, k = bk + tx;
        int row = ((n >> 4) << 5) + (n & 15) + ro;
        dst[(size_t)row * 768 + k] = f2bf(t[tx][ty + i * 8]);
    }
}

// ---------------------------------------------------------------------------
// RMSNorm: one block per token, bf16 out
__global__ __launch_bounds__(256) void k_rmsnorm(u16* __restrict__ out,
                                                 const float* __restrict__ in,
                                                 const float* __restrict__ w) {
    int t = blockIdx.x;
    const float* x = in + (size_t)t * D_;
    float ss = 0.f;
    for (int i = threadIdx.x; i < D_; i += 256) { float v = x[i]; ss += v * v; }
    for (int off = 32; off > 0; off >>= 1) ss += __shfl_down(ss, off);
    __shared__ float red[4];
    int wid = threadIdx.x >> 6, lane = threadIdx.x & 63;
    if (lane == 0) red[wid] = ss;
    __syncthreads();
    float tot = red[0] + red[1] + red[2] + red[3];
    float inv = rsqrtf(tot / (float)D_ + 1e-6f);
    for (int i = threadIdx.x; i < D_; i += 256)
        out[(size_t)t * D_ + i] = f2bf(x[i] * inv * w[i]);
}

// ---------------------------------------------------------------------------
// fused: h += sum_s part[s]; hn = bf16(rmsnorm(h, w)). one block per token.
template <int S>
__global__ __launch_bounds__(256) void k_fused_rr(float* __restrict__ h,
                                                  const float* __restrict__ part,
                                                  u16* __restrict__ hn,
                                                  const float* __restrict__ w) {
    int t = blockIdx.x;
    size_t base = (size_t)t * D_;
    float x[3];
    float ss = 0.f;
    #pragma unroll
    for (int c = 0; c < 3; ++c) {
        int i = threadIdx.x + c * 256;
        float v = h[base + i];
        #pragma unroll
        for (int s = 0; s < S; ++s)
            v += part[(size_t)s * MTOK * D_ + base + i];
        x[c] = v;
        h[base + i] = v;
        ss += v * v;
    }
    for (int off = 32; off > 0; off >>= 1) ss += __shfl_down(ss, off);
    __shared__ float red[4];
    int wid = threadIdx.x >> 6, lane = threadIdx.x & 63;
    if (lane == 0) red[wid] = ss;
    __syncthreads();
    float tot = red[0] + red[1] + red[2] + red[3];
    float inv = rsqrtf(tot / (float)D_ + 1e-6f);
    #pragma unroll
    for (int c = 0; c < 3; ++c) {
        int i = threadIdx.x + c * 256;
        hn[base + i] = f2bf(x[c] * inv * w[i]);
    }
}

// ---------------------------------------------------------------------------
// one-time RoPE table: tab[(l*32+j)*2] = cos(l*theta_j), +1 = sin
__global__ void k_rope_tab(float* __restrict__ tab) {
    int idx = blockIdx.x * blockDim.x + threadIdx.x;   // 512*32
    if (idx >= L_ * 32) return;
    int l = idx >> 5, j = idx & 31;
    float theta = __expf(-(float)j * (9.210340371976184f / 32.0f));
    float s, c;
    sincosf((float)l * theta, &s, &c);
    tab[idx * 2] = c;
    tab[idx * 2 + 1] = s;
}

// ---------------------------------------------------------------------------
// fused q/k rope+relayout + v transpose. grid (96 bh, 16 lb), 256 thr.
// qkv (MTOK,2304) bf16 -> qh (scaled by 1/8), kh: [96][512][64]; vT: [96][64][512]
__global__ __launch_bounds__(256) void k_qkvprep(u16* __restrict__ qh,
                                                 u16* __restrict__ kh,
                                                 u16* __restrict__ vT,
                                                 const u16* __restrict__ qkv,
                                                 const float* __restrict__ tab) {
    int bh = blockIdx.x, lb = blockIdx.y;
    int b = bh / NH_, hh = bh % NH_;
    int tid = threadIdx.x;
    int r = tid >> 3, c8 = (tid & 7) * 8;     // 32 rows x 64 cols
    int l = lb * 32 + r;
    size_t rowbase = ((size_t)(b * L_ + l)) * 2304 + hh * 64 + c8;

    float2 cs[4];
    #pragma unroll
    for (int p = 0; p < 4; ++p)
        cs[p] = *reinterpret_cast<const float2*>(tab + ((size_t)l * 32 + (c8 >> 1) + p) * 2);

    {   // Q: rope + fold 1/8 score scale
        uint4 v4 = *reinterpret_cast<const uint4*>(qkv + rowbase);
        const u16* pv = reinterpret_cast<const u16*>(&v4);
        u16 out[8];
        #pragma unroll
        for (int p = 0; p < 4; ++p) {
            float xr = bf2f(pv[2 * p]), xi = bf2f(pv[2 * p + 1]);
            out[2 * p]     = f2bf((xr * cs[p].x - xi * cs[p].y) * 0.125f);
            out[2 * p + 1] = f2bf((xr * cs[p].y + xi * cs[p].x) * 0.125f);
        }
        *reinterpret_cast<uint4*>(qh + ((size_t)bh * L_ + l) * 64 + c8) =
            *reinterpret_cast<uint4*>(out);
    }
    {   // K: rope
        uint4 v4 = *reinterpret_cast<const uint4*>(qkv + rowbase + 768);
        const u16* pv = reinterpret_cast<const u16*>(&v4);
        u16 out[8];
        #pragma unroll
        for (int p = 0; p < 4; ++p) {
            float xr = bf2f(pv[2 * p]), xi = bf2f(pv[2 * p + 1]);
            out[2 * p]     = f2bf(xr * cs[p].x - xi * cs[p].y);
            out[2 * p + 1] = f2bf(xr * cs[p].y + xi * cs[p].x);
        }
        *reinterpret_cast<uint4*>(kh + ((size_t)bh * L_ + l) * 64 + c8) =
            *reinterpret_cast<uint4*>(out);
    }
    // V transpose via LDS
    __shared__ u16 ts[64][40];
    {
        uint4 v4 = *reinterpret_cast<const uint4*>(qkv + rowbase + 1536);
        const u16* pv = reinterpret_cast<const u16*>(&v4);
        #pragma unroll
        for (int j = 0; j < 8; ++j) ts[c8 + j][r] = pv[j];
    }
    __syncthreads();
    {
        int d = tid >> 2, l0 = (tid & 3) * 8;
        uint4 o4 = *reinterpret_cast<const uint4*>(&ts[d][l0]);
        *reinterpret_cast<uint4*>(vT + ((size_t)bh * 64 + d) * L_ + lb * 32 + l0) = o4;
    }
}

// ---------------------------------------------------------------------------
// bf16 MFMA GEMM, double-buffered (stage-early) global_load_lds staging,
// XCD swizzle, optional split-K.
// C[M x Nout](ldC) (+)= A[M,K]bf16 @ BT[Nt,K]bf16^T (+bias)
// grid = (Nt/128, M/128, SPLITK), 256 threads. K % (32*SPLITK) == 0.
// MODE 0: C=acc(+bias) f32   MODE 3: C=acc bf16
// MODE 4: partial fp32 store to Cp + sk*M*ldC (split-K)
// MODE 5: silu-gate 16-col interleave: BT rows (n>>4)*32+(n&15) gate / +16 hidden.
//         C bf16 [M x Nout/2] (ldC = Nout/2): out = silu(gate)*hidden.
template <int MODE>
__global__ __launch_bounds__(256) void k_gemm_bf16(void* __restrict__ Cp,
                                                   const u16* __restrict__ A,
                                                   const u16* __restrict__ BT,
                                                   const float* __restrict__ bias,
                                                   int K, int Nout, int ldC) {
    __shared__ u16 As[2][128 * 32];
    __shared__ u16 Bs[2][128 * 32];
    int tid = threadIdx.x;
    int wid = tid >> 6, lane = tid & 63;

    // ---- XCD-aware swizzle over full 3D linear block id (nwg % 8 == 0) ----
    int nx = gridDim.x, ny = gridDim.y, nz = gridDim.z;
    int bid = ((blockIdx.z * ny) + blockIdx.y) * nx + blockIdx.x;
    int nwg = nx * ny * nz;
    int cpx = nwg >> 3;
    int swz = (bid & 7) * cpx + (bid >> 3);
    int sk  = swz / (nx * ny);
    int rem = swz % (nx * ny);
    int by = rem / nx, bx = rem % nx;
    int row0 = by * 128, col0 = bx * 128;
    int wr = wid >> 1, wc = wid & 1;

    int Klen = K / nz;
    int kbeg = sk * Klen;

    // staging chunk geometry (each lane moves 16 B per load, 4 loads/step)
    int c0 = wid * 128 + lane;          // 0..511
    int c1 = c0 + 64;
    int r0 = c0 >> 2, kc0 = (c0 & 3) * 8;
    int r1 = c1 >> 2, kc1 = (c1 & 3) * 8;
    const u16* gA0 = A  + (size_t)(row0 + r0) * K + kbeg + kc0;
    const u16* gA1 = A  + (size_t)(row0 + r1) * K + kbeg + kc1;
    const u16* gB0 = BT + (size_t)(col0 + r0) * K + kbeg + kc0;
    const u16* gB1 = BT + (size_t)(col0 + r1) * K + kbeg + kc1;

    auto stage = [&](int buf, int kt) {
#if HAS_GLDS
        __builtin_amdgcn_global_load_lds(
            (const __attribute__((address_space(1))) void*)(gA0 + kt),
            (__attribute__((address_space(3))) void*)&As[buf][c0 * 8], 16, 0, 0);
        __builtin_amdgcn_global_load_lds(
            (const __attribute__((address_space(1))) void*)(gA1 + kt),
            (__attribute__((address_space(3))) void*)&As[buf][c1 * 8], 16, 0, 0);
        __builtin_amdgcn_global_load_lds(
            (const __attribute__((address_space(1))) void*)(gB0 + kt),
            (__attribute__((address_space(3))) void*)&Bs[buf][c0 * 8], 16, 0, 0);
        __builtin_amdgcn_global_load_lds(
            (const __attribute__((address_space(1))) void*)(gB1 + kt),
            (__attribute__((address_space(3))) void*)&Bs[buf][c1 * 8], 16, 0, 0);
#else
        *reinterpret_cast<uint4*>(&As[buf][c0 * 8]) = *reinterpret_cast<const uint4*>(gA0 + kt);
        *reinterpret_cast<uint4*>(&As[buf][c1 * 8]) = *reinterpret_cast<const uint4*>(gA1 + kt);
        *reinterpret_cast<uint4*>(&Bs[buf][c0 * 8]) = *reinterpret_cast<const uint4*>(gB0 + kt);
        *reinterpret_cast<uint4*>(&Bs[buf][c1 * 8]) = *reinterpret_cast<const uint4*>(gB1 + kt);
#endif
    };

    f32x4 acc[4][4] = {};
    int lrow = lane & 15, lk = (lane >> 4) * 8;

    stage(0, 0);
    __syncthreads();               // drains vmcnt: buf0 ready
    int cur = 0;
    for (int kt = 0; kt < Klen; kt += 32) {
        if (kt + 32 < Klen) stage(cur ^ 1, kt + 32);   // prefetch next tile
        frag_t af[4], bfr[4];
        #pragma unroll
        for (int m = 0; m < 4; ++m)
            af[m] = *reinterpret_cast<const frag_t*>(&As[cur][(wr * 64 + m * 16 + lrow) * 32 + lk]);
        #pragma unroll
        for (int n = 0; n < 4; ++n)
            bfr[n] = *reinterpret_cast<const frag_t*>(&Bs[cur][(wc * 64 + n * 16 + lrow) * 32 + lk]);
        #pragma unroll
        for (int m = 0; m < 4; ++m)
            #pragma unroll
            for (int n = 0; n < 4; ++n)
                acc[m][n] = __builtin_amdgcn_mfma_f32_16x16x32_bf16(af[m], bfr[n], acc[m][n], 0, 0, 0);
        __syncthreads();           // all reads of cur done; prefetch landed
        cur ^= 1;
    }

    int lcol = lane & 15, rb = (lane >> 4) * 4;
    if (MODE == 5) {
        #pragma unroll
        for (int m = 0; m < 4; ++m) {
            #pragma unroll
            for (int np = 0; np < 2; ++np) {
                int ocol = (col0 >> 1) + wc * 32 + np * 16 + lcol;
                #pragma unroll
                for (int e = 0; e < 4; ++e) {
                    int row = row0 + wr * 64 + m * 16 + rb + e;
                    float g = acc[m][2 * np][e], hv = acc[m][2 * np + 1][e];
                    float s = g / (1.0f + __expf(-g));
                    ((u16*)Cp)[(size_t)row * ldC + ocol] = f2bf(s * hv);
                }
            }
        }
        return;
    }

    float* Cpart = (MODE == 4)
        ? ((float*)Cp + (size_t)sk * (size_t)(ny * 128) * ldC) : (float*)Cp;
    #pragma unroll
    for (int m = 0; m < 4; ++m) {
        #pragma unroll
        for (int n = 0; n < 4; ++n) {
            int col = col0 + wc * 64 + n * 16 + lcol;
            if (col >= Nout) continue;
            #pragma unroll
            for (int e = 0; e < 4; ++e) {
                int row = row0 + wr * 64 + m * 16 + rb + e;
                float v = acc[m][n][e];
                size_t off = (size_t)row * ldC + col;
                if (MODE == 0) {
                    if (bias) v += bias[col];
                    ((float*)Cp)[off] = v;
                } else if (MODE == 3) {
                    ((u16*)Cp)[off] = f2bf(v);
                } else if (MODE == 4) {
                    Cpart[off] = v;
                }
            }
        }
    }
}

// ---------------------------------------------------------------------------
// MFMA flash attention. grid (96 bh, 8 qb), 256 thr = 4 waves x 16 q-rows.
// qh (pre-scaled 1/8), kh: [96][512][64] bf16; vT: [96][64][512] bf16.
__global__ __launch_bounds__(256) void k_attn3(u16* __restrict__ o,
                                               const u16* __restrict__ qh,
                                               const u16* __restrict__ kh,
                                               const u16* __restrict__ vT) {
    int bh = blockIdx.x, qb = blockIdx.y;
    int b = bh / NH_, hh = bh % NH_;
    int tid = threadIdx.x, wid = tid >> 6, lane = tid & 63;
    __shared__ u16 Qs[64][72], Ks[64][72], Vs[64][72], Ps[64][72];

    #pragma unroll
    for (int i = 0; i < 2; ++i) {
        int idx = tid + i * 256;
        int r = idx >> 3, c8 = (idx & 7) * 8;
        uint4 v4 = *reinterpret_cast<const uint4*>(
            qh + ((size_t)bh * L_ + qb * 64 + r) * 64 + c8);
        *reinterpret_cast<uint4*>(&Qs[r][c8]) = v4;
    }
    __syncthreads();

    int lr = lane & 15, lg = lane >> 4;
    frag_t aq[2];
    #pragma unroll
    for (int kd = 0; kd < 2; ++kd)
        aq[kd] = *reinterpret_cast<const frag_t*>(&Qs[wid * 16 + lr][kd * 32 + lg * 8]);

    f32x4 accO[4] = {};
    float M[4], S[4];
    #pragma unroll
    for (int e = 0; e < 4; ++e) { M[e] = -INFINITY; S[e] = 0.f; }

    for (int kb = 0; kb <= qb; ++kb) {
        __syncthreads();
        #pragma unroll
        for (int i = 0; i < 2; ++i) {
            int idx = tid + i * 256;
            int r = idx >> 3, c8 = (idx & 7) * 8;
            *reinterpret_cast<uint4*>(&Ks[r][c8]) = *reinterpret_cast<const uint4*>(
                kh + ((size_t)bh * L_ + kb * 64 + r) * 64 + c8);
            *reinterpret_cast<uint4*>(&Vs[r][c8]) = *reinterpret_cast<const uint4*>(
                vT + ((size_t)bh * 64 + r) * L_ + kb * 64 + c8);
        }
        __syncthreads();

        f32x4 sv[4];
        #pragma unroll
        for (int ct = 0; ct < 4; ++ct) {
            frag_t bk0 = *reinterpret_cast<const frag_t*>(&Ks[ct * 16 + lr][lg * 8]);
            frag_t bk1 = *reinterpret_cast<const frag_t*>(&Ks[ct * 16 + lr][32 + lg * 8]);
            f32x4 z = {0.f, 0.f, 0.f, 0.f};
            z = __builtin_amdgcn_mfma_f32_16x16x32_bf16(aq[0], bk0, z, 0, 0, 0);
            sv[ct] = __builtin_amdgcn_mfma_f32_16x16x32_bf16(aq[1], bk1, z, 0, 0, 0);
        }

        bool diag = (kb == qb);
        float esc[4];
        #pragma unroll
        for (int e = 0; e < 4; ++e) {
            int qg = qb * 64 + wid * 16 + lg * 4 + e;
            float mx = -1e30f;
            #pragma unroll
            for (int ct = 0; ct < 4; ++ct) {
                float s = sv[ct][e];
                if (diag && (kb * 64 + ct * 16 + lr > qg)) s = -1e30f;
                sv[ct][e] = s;
                mx = fmaxf(mx, s);
            }
            #pragma unroll
            for (int msk = 8; msk; msk >>= 1) mx = fmaxf(mx, __shfl_xor(mx, msk));
            float newM = fmaxf(M[e], mx);
            float ps = 0.f;
            #pragma unroll
            for (int ct = 0; ct < 4; ++ct) {
                float p = __expf(sv[ct][e] - newM);
                sv[ct][e] = p;
                ps += p;
            }
            #pragma unroll
            for (int msk = 8; msk; msk >>= 1) ps += __shfl_xor(ps, msk);
            esc[e] = __expf(M[e] - newM);
            S[e] = S[e] * esc[e] + ps;
            M[e] = newM;
        }
        #pragma unroll
        for (int dt = 0; dt < 4; ++dt)
            #pragma unroll
            for (int e = 0; e < 4; ++e) accO[dt][e] *= esc[e];

        #pragma unroll
        for (int ct = 0; ct < 4; ++ct)
            #pragma unroll
            for (int e = 0; e < 4; ++e)
                Ps[wid * 16 + lg * 4 + e][ct * 16 + lr] = f2bf(sv[ct][e]);

        frag_t pa0 = *reinterpret_cast<const frag_t*>(&Ps[wid * 16 + lr][lg * 8]);
        frag_t pa1 = *reinterpret_cast<const frag_t*>(&Ps[wid * 16 + lr][32 + lg * 8]);
        #pragma unroll
        for (int dt = 0; dt < 4; ++dt) {
            frag_t bv0 = *reinterpret_cast<const frag_t*>(&Vs[dt * 16 + lr][lg * 8]);
            frag_t bv1 = *reinterpret_cast<const frag_t*>(&Vs[dt * 16 + lr][32 + lg * 8]);
            accO[dt] = __builtin_amdgcn_mfma_f32_16x16x32_bf16(pa0, bv0, accO[dt], 0, 0, 0);
            accO[dt] = __builtin_amdgcn_mfma_f32_16x16x32_bf16(pa1, bv1, accO[dt], 0, 0, 0);
        }
    }

    #pragma unroll
    for (int dt = 0; dt < 4; ++dt) {
        #pragma unroll
        for (int e = 0; e < 4; ++e) {
            int row = b * L_ + qb * 64 + wid * 16 + lg * 4 + e;
            o[(size_t)row * D_ + hh * 64 + dt * 16 + lr] = f2bf(accO[dt][e] / S[e]);
        }
    }
}

// ---------------------------------------------------------------------------
// tiny heads: per token, shared rsqrt; reward (2) + box (4) dot products.
__global__ __launch_bounds__(256) void k_heads3(float* __restrict__ out_reward,
                                                float* __restrict__ out_box,
                                                const float* __restrict__ h,
                                                const float* __restrict__ rnw,
                                                const float* __restrict__ rW,
                                                const float* __restrict__ rb,
                                                const float* __restrict__ bnw,
                                                const float* __restrict__ bW,
                                                const float* __restrict__ bb) {
    int t = blockIdx.x;
    size_t base = (size_t)t * D_;
    float x[3];
    float ss = 0.f;
    #pragma unroll
    for (int c = 0; c < 3; ++c) {
        int i = threadIdx.x + c * 256;
        x[c] = h[base + i];
        ss += x[c] * x[c];
    }
    for (int off = 32; off > 0; off >>= 1) ss += __shfl_down(ss, off);
    __shared__ float red[4];
    int wid = threadIdx.x >> 6, lane = threadIdx.x & 63;
    if (lane == 0) red[wid] = ss;
    __syncthreads();
    float inv = rsqrtf((red[0] + red[1] + red[2] + red[3]) / (float)D_ + 1e-6f);

    float a[6] = {};
    #pragma unroll
    for (int c = 0; c < 3; ++c) {
        int i = threadIdx.x + c * 256;
        float xr = x[c] * inv;
        float xw = xr * rnw[i];
        a[0] += xw * rW[i * 2];
        a[1] += xw * rW[i * 2 + 1];
        float xb = xr * bnw[i];
        #pragma unroll
        for (int j = 0; j < 4; ++j) a[2 + j] += xb * bW[i * 4 + j];
    }
    #pragma unroll
    for (int j = 0; j < 6; ++j)
        for (int off = 32; off > 0; off >>= 1) a[j] += __shfl_down(a[j], off);
    __shared__ float red2[4][6];
    if (lane == 0)
        #pragma unroll
        for (int j = 0; j < 6; ++j) red2[wid][j] = a[j];
    __syncthreads();
    if (threadIdx.x < 6) {
        float s = red2[0][threadIdx.x] + red2[1][threadIdx.x] +
                  red2[2][threadIdx.x] + red2[3][threadIdx.x];
        if (threadIdx.x < 2) out_reward[(size_t)t * 2 + threadIdx.x] = s + rb[threadIdx.x];
        else                 out_box[(size_t)t * 4 + threadIdx.x - 2] = s + bb[threadIdx.x - 2];
    }
}

// ---------------------------------------------------------------------------
extern "C" void kernel_launch(void* const* d_in, const int* in_sizes, int n_in,
                              void* d_out, int out_size, void* d_ws, size_t ws_size,
                              hipStream_t stream) {
    const float* patch        = (const float*)d_in[0];
    const float* box          = (const float*)d_in[1];
    const float* patch_W      = (const float*)d_in[2];
    const float* patch_b      = (const float*)d_in[3];
    const float* box_W        = (const float*)d_in[4];
    const float* box_b        = (const float*)d_in[5];
    const float* Wq           = (const float*)d_in[6];
    const float* Wk           = (const float*)d_in[7];
    const float* Wv           = (const float*)d_in[8];
    const float* Wo           = (const float*)d_in[9];
    const float* attn_norm_w  = (const float*)d_in[10];
    const float* gate_W       = (const float*)d_in[11];
    const float* hidden_W     = (const float*)d_in[12];
    const float* ffn_out_W    = (const float*)d_in[13];
    const float* ffn_norm_w   = (const float*)d_in[14];
    const float* reward_norm_w= (const float*)d_in[15];
    const float* reward_W     = (const float*)d_in[16];
    const float* reward_b     = (const float*)d_in[17];
    const float* label_norm_w = (const float*)d_in[18];
    const float* label_W      = (const float*)d_in[19];
    const float* label_b      = (const float*)d_in[20];
    const float* box_norm_w   = (const float*)d_in[21];
    const float* boxh_W       = (const float*)d_in[22];
    const float* boxh_b       = (const float*)d_in[23];

    char* w = (char*)d_ws;
    auto alloc = [&](size_t bytes) { char* p = w; w += (bytes + 255) & ~(size_t)255; return p; };

    u16*  wqkv   = (u16*)alloc((size_t)2304 * 768 * 2);
    u16*  wo_l   = (u16*)alloc((size_t)768 * 768 * 2);
    u16*  wgh    = (u16*)alloc((size_t)6144 * 768 * 2);   // 16-col-group interleaved
    u16*  wfo    = (u16*)alloc((size_t)768 * 3072 * 2);
    u16*  wcat   = (u16*)alloc((size_t)768 * 1536 * 2);   // patch|box weights
    u16*  wlab   = (u16*)alloc((size_t)1024 * 768 * 2);
    float* bias_c= (float*)alloc((size_t)768 * 4);
    u16*  emb    = (u16*)alloc((size_t)MTOK * 1536 * 2);  // reused as qh|kh
    float* h     = (float*)alloc((size_t)MTOK * D_ * 4);
    u16*  hn_bf  = (u16*)alloc((size_t)MTOK * D_ * 2);
    u16*  qkv_bf = (u16*)alloc((size_t)MTOK * 2304 * 2);
    u16*  vT     = (u16*)alloc((size_t)MTOK * D_ * 2);
    float* tab   = (float*)alloc((size_t)L_ * 32 * 2 * 4);
    u16*  o_bf   = (u16*)alloc((size_t)MTOK * D_ * 2);
    u16*  ga_bf  = (u16*)alloc((size_t)MTOK * DFF_ * 2);
    float* part  = (float*)alloc((size_t)4 * MTOK * D_ * 4);

    u16* qh = emb;                       // emb dead after embedding GEMM
    u16* kh = emb + (size_t)MTOK * 768;

    dim3 blk(256);

    // one-time converts
    k_convT<<<dim3(24, 24), blk, 0, stream>>>(wcat, patch_W, 768, 768, 1536, 1, 0, 0);
    k_convT<<<dim3(24, 24), blk, 0, stream>>>(wcat, box_W,   768, 768, 1536, 1, 0, 768);
    k_convT<<<dim3(32, 24), blk, 0, stream>>>(wlab, label_W, 768, 1000, 768, 1, 0, 0);
    k_addb<<<3, blk, 0, stream>>>(bias_c, patch_b, box_b);
    k_rope_tab<<<(L_ * 32 + 255) / 256, blk, 0, stream>>>(tab);
    k_cast<<<(MTOK * 768 / 4 + 255) / 256, blk, 0, stream>>>(emb, patch, MTOK * 768 / 4);
    k_box_sin<<<(MTOK * D_ + 255) / 256, blk, 0, stream>>>(emb, box);

    // embedding: h = [patch|box_sin] @ [patch_W; box_W] + (patch_b+box_b)
    k_gemm_bf16<0><<<dim3(6, 32), blk, 0, stream>>>(h, emb, wcat, bias_c, 1536, 768, 768);
    k_rmsnorm<<<MTOK, blk, 0, stream>>>(hn_bf, h, attn_norm_w);

    for (int ly = 0; ly < NL_; ++ly) {
        const float* wq  = Wq + (size_t)ly * D_ * D_;
        const float* wk  = Wk + (size_t)ly * D_ * D_;
        const float* wv  = Wv + (size_t)ly * D_ * D_;
        const float* wo  = Wo + (size_t)ly * D_ * D_;
        const float* gw  = gate_W + (size_t)ly * D_ * DFF_;
        const float* hw  = hidden_W + (size_t)ly * D_ * DFF_;
        const float* ow  = ffn_out_W + (size_t)ly * DFF_ * D_;
        const float* fnw = ffn_norm_w + (size_t)ly * D_;
        const float* nxt = (ly + 1 < NL_) ? attn_norm_w + (size_t)(ly + 1) * D_
                                          : label_norm_w;

        k_convT_qkv<<<dim3(24, 24, 3), blk, 0, stream>>>(wqkv, wq, wk, wv);
        k_gemm_bf16<3><<<dim3(18, 32), blk, 0, stream>>>(qkv_bf, hn_bf, wqkv, nullptr, 768, 2304, 2304);
        k_qkvprep<<<dim3(96, 16), blk, 0, stream>>>(qh, kh, vT, qkv_bf, tab);
        k_attn3<<<dim3(96, 8), blk, 0, stream>>>(o_bf, qh, kh, vT);
        k_convT<<<dim3(24, 24), blk, 0, stream>>>(wo_l, wo, 768, 768, 768, 1, 0, 0);
        k_gemm_bf16<4><<<dim3(6, 32, 2), blk, 0, stream>>>(part, o_bf, wo_l, nullptr, 768, 768, 768);
        k_fused_rr<2><<<MTOK, blk, 0, stream>>>(h, part, hn_bf, fnw);

        k_convT_gh<<<dim3(96, 24, 2), blk, 0, stream>>>(wgh, gw, hw);
        k_gemm_bf16<5><<<dim3(48, 32), blk, 0, stream>>>(ga_bf, hn_bf, wgh, nullptr, 768, 6144, 3072);
        k_convT<<<dim3(24, 96), blk, 0, stream>>>(wfo, ow, 3072, 768, 3072, 1, 0, 0);
        k_gemm_bf16<4><<<dim3(6, 32, 4), blk, 0, stream>>>(part, ga_bf, wfo, nullptr, 3072, 768, 768);
        k_fused_rr<4><<<MTOK, blk, 0, stream>>>(h, part, hn_bf, nxt);
    }

    // heads: hn_bf already = rmsnorm(h, label_norm_w)
    float* out_reward = (float*)d_out;
    float* out_label  = out_reward + (size_t)MTOK * 2;
    float* out_box    = out_label + (size_t)MTOK * 1000;

    k_gemm_bf16<0><<<dim3(8, 32), blk, 0, stream>>>(out_label, hn_bf, wlab, label_b, 768, 1000, 1000);
    k_heads3<<<MTOK, blk, 0, stream>>>(out_reward, out_box, h,
                                       reward_norm_w, reward_W, reward_b,
                                       box_norm_w, boxh_W, boxh_b);
}

// Round 8
// 2466.195 us; speedup vs baseline: 9.3238x; 1.0252x over previous
//
#include <hip/hip_runtime.h>
#include <math.h>
#include <type_traits>

#define B_   8
#define L_   512
#define MTOK 4096           // B_*L_
#define D_   768
#define NH_  12
#define DH_  64
#define DFF_ 3072
#define NL_  12

typedef unsigned short u16;
typedef __attribute__((ext_vector_type(4))) float f32x4;
typedef __attribute__((ext_vector_type(8))) short i16x8;
typedef __attribute__((ext_vector_type(8))) __bf16 b16x8;

// Pick whichever vector type the gfx950 bf16 MFMA builtin accepts.
template <typename A, typename = void>
struct PickFrag { using type = i16x8; };
template <typename A>
struct PickFrag<A, std::void_t<decltype(__builtin_amdgcn_mfma_f32_16x16x32_bf16(
    std::declval<A>(), std::declval<A>(), std::declval<f32x4>(), 0, 0, 0))>> {
  using type = A;
};
using frag_t = typename PickFrag<b16x8>::type;

#if __has_builtin(__builtin_amdgcn_global_load_lds)
#define HAS_GLDS 1
#else
#define HAS_GLDS 0
#endif

__device__ inline u16 f2bf(float f) {
    unsigned u = __float_as_uint(f);
    unsigned r = u + 0x7fffu + ((u >> 16) & 1u);
    return (u16)(r >> 16);
}
__device__ inline float bf2f(u16 b) { return __uint_as_float(((unsigned)b) << 16); }

// compiler-fenced raw barrier (no vmcnt drain, unlike __syncthreads)
__device__ inline void bar_raw() {
    asm volatile("" ::: "memory");
    __builtin_amdgcn_s_barrier();
    asm volatile("" ::: "memory");
}

// ---------------------------------------------------------------------------
// box sinusoid embedding -> bf16 into emb[t*1536 + 768 + d]
__global__ void k_box_sin(u16* __restrict__ emb, const float* __restrict__ box) {
    int idx = blockIdx.x * blockDim.x + threadIdx.x;
    if (idx >= MTOK * D_) return;
    int t = idx / D_, d = idx % D_;
    int c = d / 192, r = d % 192, j = r >> 1;
    float theta = __expf(-(float)j * (9.210340371976184f / 96.0f));
    float ang = box[t * 4 + c] * theta;
    emb[(size_t)t * 1536 + 768 + d] = f2bf((r & 1) ? sinf(ang) : cosf(ang));
}

// fp32 patch -> bf16 into emb[t*1536 + c]
__global__ void k_cast(u16* __restrict__ emb, const float* __restrict__ in, int n4) {
    int i = blockIdx.x * blockDim.x + threadIdx.x;
    if (i >= n4) return;            // n4 = MTOK*768/4
    int t = i / 192, c4 = (i % 192) * 4;
    float4 v = *reinterpret_cast<const float4*>(in + (size_t)t * 768 + c4);
    unsigned lo = (unsigned)f2bf(v.x) | ((unsigned)f2bf(v.y) << 16);
    unsigned hi = (unsigned)f2bf(v.z) | ((unsigned)f2bf(v.w) << 16);
    *reinterpret_cast<uint2*>(emb + (size_t)t * 1536 + c4) = make_uint2(lo, hi);
}

// combined bias
__global__ void k_addb(float* __restrict__ dst, const float* __restrict__ a,
                       const float* __restrict__ b) {
    int i = blockIdx.x * blockDim.x + threadIdx.x;
    if (i < D_) dst[i] = a[i] + b[i];
}

// ---------------------------------------------------------------------------
// generic transpose-convert: src (K,N) fp32 -> dst[(n*rs+ro)*ld + co + k] bf16
__global__ __launch_bounds__(256) void k_convT(u16* __restrict__ dst,
                                               const float* __restrict__ src,
                                               int K, int N, int ld, int rs,
                                               int ro, int co) {
    __shared__ float t[32][33];
    int bn = blockIdx.x * 32;
    int bk = blockIdx.y * 32;
    int tx = threadIdx.x % 32, ty = threadIdx.x / 32;
    #pragma unroll
    for (int i = 0; i < 4; ++i) {
        int k = bk + ty + i * 8;
        int n = bn + tx;
        t[ty + i * 8][tx] = (n < N) ? src[(size_t)k * N + n] : 0.0f;
    }
    __syncthreads();
    #pragma unroll
    for (int i = 0; i < 4; ++i) {
        int n = bn + ty + i * 8;   // dst logical row
        int k = bk + tx;           // dst col
        dst[(size_t)(n * rs + ro) * ld + co + k] = f2bf(t[tx][ty + i * 8]);
    }
}

// batched single-weight transpose: z = layer. src (K,N) per layer -> dst [N][K]
__global__ __launch_bounds__(256) void k_convT_b1(u16* __restrict__ dst,
                                                  const float* __restrict__ src,
                                                  int K, int N) {
    __shared__ float t[32][33];
    const float* s = src + (size_t)blockIdx.z * K * N;
    u16* d = dst + (size_t)blockIdx.z * K * N;
    int bn = blockIdx.x * 32, bk = blockIdx.y * 32;
    int tx = threadIdx.x % 32, ty = threadIdx.x / 32;
    #pragma unroll
    for (int i = 0; i < 4; ++i)
        t[ty + i * 8][tx] = s[(size_t)(bk + ty + i * 8) * N + bn + tx];
    __syncthreads();
    #pragma unroll
    for (int i = 0; i < 4; ++i) {
        int n = bn + ty + i * 8, k = bk + tx;
        d[(size_t)n * K + k] = f2bf(t[tx][ty + i * 8]);
    }
}

// batched QKV transpose: z = layer*3 + which. dst layer block = [3][768][768]
__global__ __launch_bounds__(256) void k_convT_qkv(u16* __restrict__ dst,
                                                   const float* __restrict__ s0,
                                                   const float* __restrict__ s1,
                                                   const float* __restrict__ s2) {
    __shared__ float t[32][33];
    int ly = blockIdx.z / 3, which = blockIdx.z % 3;
    const float* src = (which == 0 ? s0 : (which == 1 ? s1 : s2)) + (size_t)ly * 768 * 768;
    u16* d = dst + ((size_t)ly * 3 + which) * 768 * 768;
    int bn = blockIdx.x * 32, bk = blockIdx.y * 32;
    int tx = threadIdx.x % 32, ty = threadIdx.x / 32;
    #pragma unroll
    for (int i = 0; i < 4; ++i)
        t[ty + i * 8][tx] = src[(size_t)(bk + ty + i * 8) * 768 + bn + tx];
    __syncthreads();
    #pragma unroll
    for (int i = 0; i < 4; ++i) {
        int n = bn + ty + i * 8, k = bk + tx;
        d[(size_t)n * 768 + k] = f2bf(t[tx][ty + i * 8]);
    }
}

// batched gate/hidden transpose, 16-col group interleave. z = layer*2 + which.
// logical col n -> dst row (n>>4)*32 + (n&15) + which*16, layer block 6144x768
__global__ __launch_bounds__(256) void k_convT_gh(u16* __restrict__ dst,
                                                  const float* __restrict__ g,
                                                  const float* __restrict__ h) {
    __shared__ float t[32][33];
    int ly = blockIdx.z >> 1, which = blockIdx.z & 1;
    const float* src = (which ? h : g) + (size_t)ly * 768 * 3072;
    u16* d = dst + (size_t)ly * 6144 * 768;
    int ro = which * 16;
    int bn = blockIdx.x * 32, bk = blockIdx.y * 32;
    int tx = threadIdx.x % 32, ty = threadIdx.x / 32;
    #pragma unroll
    for (int i = 0; i < 4; ++i)
        t[ty + i * 8][tx] = src[(size_t)(bk + ty + i * 8) * 3072 + bn + tx];
    __syncthreads();
    #pragma unroll
    for (int i = 0; i < 4; ++i) {
        int n = bn + ty + i * 8, k = bk + tx;
        int row = ((n >> 4) << 5) + (n & 15) + ro;
        d[(size_t)row * 768 + k] = f2bf(t[tx][ty + i * 8]);
    }
}

// ---------------------------------------------------------------------------
// RMSNorm: one block per token, bf16 out
__global__ __launch_bounds__(256) void k_rmsnorm(u16* __restrict__ out,
                                                 const float* __restrict__ in,
                                                 const float* __restrict__ w) {
    int t = blockIdx.x;
    const float* x = in + (size_t)t * D_;
    float ss = 0.f;
    for (int i = threadIdx.x; i < D_; i += 256) { float v = x[i]; ss += v * v; }
    for (int off = 32; off > 0; off >>= 1) ss += __shfl_down(ss, off);
    __shared__ float red[4];
    int wid = threadIdx.x >> 6, lane = threadIdx.x & 63;
    if (lane == 0) red[wid] = ss;
    __syncthreads();
    float tot = red[0] + red[1] + red[2] + red[3];
    float inv = rsqrtf(tot / (float)D_ + 1e-6f);
    for (int i = threadIdx.x; i < D_; i += 256)
        out[(size_t)t * D_ + i] = f2bf(x[i] * inv * w[i]);
}

// ---------------------------------------------------------------------------
// fused: h += sum_s part[s]; hn = bf16(rmsnorm(h, w)). one block per token.
template <int S>
__global__ __launch_bounds__(256) void k_fused_rr(float* __restrict__ h,
                                                  const float* __restrict__ part,
                                                  u16* __restrict__ hn,
                                                  const float* __restrict__ w) {
    int t = blockIdx.x;
    size_t base = (size_t)t * D_;
    float x[3];
    float ss = 0.f;
    #pragma unroll
    for (int c = 0; c < 3; ++c) {
        int i = threadIdx.x + c * 256;
        float v = h[base + i];
        #pragma unroll
        for (int s = 0; s < S; ++s)
            v += part[(size_t)s * MTOK * D_ + base + i];
        x[c] = v;
        h[base + i] = v;
        ss += v * v;
    }
    for (int off = 32; off > 0; off >>= 1) ss += __shfl_down(ss, off);
    __shared__ float red[4];
    int wid = threadIdx.x >> 6, lane = threadIdx.x & 63;
    if (lane == 0) red[wid] = ss;
    __syncthreads();
    float tot = red[0] + red[1] + red[2] + red[3];
    float inv = rsqrtf(tot / (float)D_ + 1e-6f);
    #pragma unroll
    for (int c = 0; c < 3; ++c) {
        int i = threadIdx.x + c * 256;
        hn[base + i] = f2bf(x[c] * inv * w[i]);
    }
}

// ---------------------------------------------------------------------------
// one-time RoPE table: tab[(l*32+j)*2] = cos(l*theta_j), +1 = sin
__global__ void k_rope_tab(float* __restrict__ tab) {
    int idx = blockIdx.x * blockDim.x + threadIdx.x;   // 512*32
    if (idx >= L_ * 32) return;
    int l = idx >> 5, j = idx & 31;
    float theta = __expf(-(float)j * (9.210340371976184f / 32.0f));
    float s, c;
    sincosf((float)l * theta, &s, &c);
    tab[idx * 2] = c;
    tab[idx * 2 + 1] = s;
}

// ---------------------------------------------------------------------------
// fused q/k rope+relayout + v transpose. grid (96 bh, 16 lb), 256 thr.
// qkv (MTOK,2304) bf16 -> qh (scaled by 1/8), kh: [96][512][64]; vT: [96][64][512]
__global__ __launch_bounds__(256) void k_qkvprep(u16* __restrict__ qh,
                                                 u16* __restrict__ kh,
                                                 u16* __restrict__ vT,
                                                 const u16* __restrict__ qkv,
                                                 const float* __restrict__ tab) {
    int bh = blockIdx.x, lb = blockIdx.y;
    int b = bh / NH_, hh = bh % NH_;
    int tid = threadIdx.x;
    int r = tid >> 3, c8 = (tid & 7) * 8;     // 32 rows x 64 cols
    int l = lb * 32 + r;
    size_t rowbase = ((size_t)(b * L_ + l)) * 2304 + hh * 64 + c8;

    float2 cs[4];
    #pragma unroll
    for (int p = 0; p < 4; ++p)
        cs[p] = *reinterpret_cast<const float2*>(tab + ((size_t)l * 32 + (c8 >> 1) + p) * 2);

    {   // Q: rope + fold 1/8 score scale
        uint4 v4 = *reinterpret_cast<const uint4*>(qkv + rowbase);
        const u16* pv = reinterpret_cast<const u16*>(&v4);
        u16 out[8];
        #pragma unroll
        for (int p = 0; p < 4; ++p) {
            float xr = bf2f(pv[2 * p]), xi = bf2f(pv[2 * p + 1]);
            out[2 * p]     = f2bf((xr * cs[p].x - xi * cs[p].y) * 0.125f);
            out[2 * p + 1] = f2bf((xr * cs[p].y + xi * cs[p].x) * 0.125f);
        }
        *reinterpret_cast<uint4*>(qh + ((size_t)bh * L_ + l) * 64 + c8) =
            *reinterpret_cast<uint4*>(out);
    }
    {   // K: rope
        uint4 v4 = *reinterpret_cast<const uint4*>(qkv + rowbase + 768);
        const u16* pv = reinterpret_cast<const u16*>(&v4);
        u16 out[8];
        #pragma unroll
        for (int p = 0; p < 4; ++p) {
            float xr = bf2f(pv[2 * p]), xi = bf2f(pv[2 * p + 1]);
            out[2 * p]     = f2bf(xr * cs[p].x - xi * cs[p].y);
            out[2 * p + 1] = f2bf(xr * cs[p].y + xi * cs[p].x);
        }
        *reinterpret_cast<uint4*>(kh + ((size_t)bh * L_ + l) * 64 + c8) =
            *reinterpret_cast<uint4*>(out);
    }
    // V transpose via LDS
    __shared__ u16 ts[64][40];
    {
        uint4 v4 = *reinterpret_cast<const uint4*>(qkv + rowbase + 1536);
        const u16* pv = reinterpret_cast<const u16*>(&v4);
        #pragma unroll
        for (int j = 0; j < 8; ++j) ts[c8 + j][r] = pv[j];
    }
    __syncthreads();
    {
        int d = tid >> 2, l0 = (tid & 3) * 8;
        uint4 o4 = *reinterpret_cast<const uint4*>(&ts[d][l0]);
        *reinterpret_cast<uint4*>(vT + ((size_t)bh * 64 + d) * L_ + lb * 32 + l0) = o4;
    }
}

// ---------------------------------------------------------------------------
// bf16 MFMA GEMM, double-buffered, counted-vmcnt pipeline (T4), XCD swizzle,
// optional split-K.
// C[M x Nout](ldC) (+)= A[M,K]bf16 @ BT[Nt,K]bf16^T (+bias)
// grid = (Nt/128, M/128, SPLITK), 256 threads. K % (32*SPLITK) == 0.
// MODE 0: C=acc(+bias) f32   MODE 3: C=acc bf16
// MODE 4: partial fp32 store to Cp + sk*M*ldC (split-K)
// MODE 5: silu-gate 16-col interleave: C bf16 [M x Nout/2], out=silu(g)*h
template <int MODE>
__global__ __launch_bounds__(256) void k_gemm_bf16(void* __restrict__ Cp,
                                                   const u16* __restrict__ A,
                                                   const u16* __restrict__ BT,
                                                   const float* __restrict__ bias,
                                                   int K, int Nout, int ldC) {
    __shared__ u16 As[2][128 * 32];
    __shared__ u16 Bs[2][128 * 32];
    int tid = threadIdx.x;
    int wid = tid >> 6, lane = tid & 63;

    // ---- XCD-aware swizzle over full 3D linear block id (nwg % 8 == 0) ----
    int nx = gridDim.x, ny = gridDim.y, nz = gridDim.z;
    int bid = ((blockIdx.z * ny) + blockIdx.y) * nx + blockIdx.x;
    int nwg = nx * ny * nz;
    int cpx = nwg >> 3;
    int swz = (bid & 7) * cpx + (bid >> 3);
    int sk  = swz / (nx * ny);
    int rem = swz % (nx * ny);
    int by = rem / nx, bx = rem % nx;
    int row0 = by * 128, col0 = bx * 128;
    int wr = wid >> 1, wc = wid & 1;

    int Klen = K / nz;
    int kbeg = sk * Klen;

    // staging chunk geometry (each lane moves 16 B per load, 4 loads/step)
    int c0 = wid * 128 + lane;          // 0..511
    int c1 = c0 + 64;
    int r0 = c0 >> 2, kc0 = (c0 & 3) * 8;
    int r1 = c1 >> 2, kc1 = (c1 & 3) * 8;
    const u16* gA0 = A  + (size_t)(row0 + r0) * K + kbeg + kc0;
    const u16* gA1 = A  + (size_t)(row0 + r1) * K + kbeg + kc1;
    const u16* gB0 = BT + (size_t)(col0 + r0) * K + kbeg + kc0;
    const u16* gB1 = BT + (size_t)(col0 + r1) * K + kbeg + kc1;

    auto stage = [&](int buf, int kt) {
#if HAS_GLDS
        __builtin_amdgcn_global_load_lds(
            (const __attribute__((address_space(1))) void*)(gA0 + kt),
            (__attribute__((address_space(3))) void*)&As[buf][c0 * 8], 16, 0, 0);
        __builtin_amdgcn_global_load_lds(
            (const __attribute__((address_space(1))) void*)(gA1 + kt),
            (__attribute__((address_space(3))) void*)&As[buf][c1 * 8], 16, 0, 0);
        __builtin_amdgcn_global_load_lds(
            (const __attribute__((address_space(1))) void*)(gB0 + kt),
            (__attribute__((address_space(3))) void*)&Bs[buf][c0 * 8], 16, 0, 0);
        __builtin_amdgcn_global_load_lds(
            (const __attribute__((address_space(1))) void*)(gB1 + kt),
            (__attribute__((address_space(3))) void*)&Bs[buf][c1 * 8], 16, 0, 0);
#else
        *reinterpret_cast<uint4*>(&As[buf][c0 * 8]) = *reinterpret_cast<const uint4*>(gA0 + kt);
        *reinterpret_cast<uint4*>(&As[buf][c1 * 8]) = *reinterpret_cast<const uint4*>(gA1 + kt);
        *reinterpret_cast<uint4*>(&Bs[buf][c0 * 8]) = *reinterpret_cast<const uint4*>(gB0 + kt);
        *reinterpret_cast<uint4*>(&Bs[buf][c1 * 8]) = *reinterpret_cast<const uint4*>(gB1 + kt);
#endif
    };

    f32x4 acc[4][4] = {};
    int lrow = lane & 15, lk = (lane >> 4) * 8;

    stage(0, 0);
    int cur = 0;
    for (int kt = 0; kt < Klen; kt += 32) {
        bool has_next = (kt + 32 < Klen);
        if (has_next) stage(cur ^ 1, kt + 32);      // prefetch stays in flight
        // wait ONLY for cur buffer's 4 loads (issued last iter / prologue)
        if (has_next) asm volatile("s_waitcnt vmcnt(4) lgkmcnt(0)" ::: "memory");
        else          asm volatile("s_waitcnt vmcnt(0) lgkmcnt(0)" ::: "memory");
        __builtin_amdgcn_sched_barrier(0);
        bar_raw();                                   // all waves: cur ready
        frag_t af[4], bfr[4];
        #pragma unroll
        for (int m = 0; m < 4; ++m)
            af[m] = *reinterpret_cast<const frag_t*>(&As[cur][(wr * 64 + m * 16 + lrow) * 32 + lk]);
        #pragma unroll
        for (int n = 0; n < 4; ++n)
            bfr[n] = *reinterpret_cast<const frag_t*>(&Bs[cur][(wc * 64 + n * 16 + lrow) * 32 + lk]);
        #pragma unroll
        for (int m = 0; m < 4; ++m)
            #pragma unroll
            for (int n = 0; n < 4; ++n)
                acc[m][n] = __builtin_amdgcn_mfma_f32_16x16x32_bf16(af[m], bfr[n], acc[m][n], 0, 0, 0);
        bar_raw();                                   // reads of cur done everywhere
        cur ^= 1;
    }

    int lcol = lane & 15, rb = (lane >> 4) * 4;
    if (MODE == 5) {
        #pragma unroll
        for (int m = 0; m < 4; ++m) {
            #pragma unroll
            for (int np = 0; np < 2; ++np) {
                int ocol = (col0 >> 1) + wc * 32 + np * 16 + lcol;
                #pragma unroll
                for (int e = 0; e < 4; ++e) {
                    int row = row0 + wr * 64 + m * 16 + rb + e;
                    float g = acc[m][2 * np][e], hv = acc[m][2 * np + 1][e];
                    float s = g / (1.0f + __expf(-g));
                    ((u16*)Cp)[(size_t)row * ldC + ocol] = f2bf(s * hv);
                }
            }
        }
        return;
    }

    float* Cpart = (MODE == 4)
        ? ((float*)Cp + (size_t)sk * (size_t)(ny * 128) * ldC) : (float*)Cp;
    #pragma unroll
    for (int m = 0; m < 4; ++m) {
        #pragma unroll
        for (int n = 0; n < 4; ++n) {
            int col = col0 + wc * 64 + n * 16 + lcol;
            if (col >= Nout) continue;
            #pragma unroll
            for (int e = 0; e < 4; ++e) {
                int row = row0 + wr * 64 + m * 16 + rb + e;
                float v = acc[m][n][e];
                size_t off = (size_t)row * ldC + col;
                if (MODE == 0) {
                    if (bias) v += bias[col];
                    ((float*)Cp)[off] = v;
                } else if (MODE == 3) {
                    ((u16*)Cp)[off] = f2bf(v);
                } else if (MODE == 4) {
                    Cpart[off] = v;
                }
            }
        }
    }
}

// ---------------------------------------------------------------------------
// MFMA flash attention. grid (96 bh, 8 qb), 256 thr = 4 waves x 16 q-rows.
// qh (pre-scaled 1/8), kh: [96][512][64] bf16; vT: [96][64][512] bf16.
__global__ __launch_bounds__(256) void k_attn3(u16* __restrict__ o,
                                               const u16* __restrict__ qh,
                                               const u16* __restrict__ kh,
                                               const u16* __restrict__ vT) {
    int bh = blockIdx.x, qb = blockIdx.y;
    int b = bh / NH_, hh = bh % NH_;
    int tid = threadIdx.x, wid = tid >> 6, lane = tid & 63;
    __shared__ u16 Qs[64][72], Ks[64][72], Vs[64][72], Ps[64][72];

    #pragma unroll
    for (int i = 0; i < 2; ++i) {
        int idx = tid + i * 256;
        int r = idx >> 3, c8 = (idx & 7) * 8;
        uint4 v4 = *reinterpret_cast<const uint4*>(
            qh + ((size_t)bh * L_ + qb * 64 + r) * 64 + c8);
        *reinterpret_cast<uint4*>(&Qs[r][c8]) = v4;
    }
    __syncthreads();

    int lr = lane & 15, lg = lane >> 4;
    frag_t aq[2];
    #pragma unroll
    for (int kd = 0; kd < 2; ++kd)
        aq[kd] = *reinterpret_cast<const frag_t*>(&Qs[wid * 16 + lr][kd * 32 + lg * 8]);

    f32x4 accO[4] = {};
    float M[4], S[4];
    #pragma unroll
    for (int e = 0; e < 4; ++e) { M[e] = -INFINITY; S[e] = 0.f; }

    for (int kb = 0; kb <= qb; ++kb) {
        __syncthreads();
        #pragma unroll
        for (int i = 0; i < 2; ++i) {
            int idx = tid + i * 256;
            int r = idx >> 3, c8 = (idx & 7) * 8;
            *reinterpret_cast<uint4*>(&Ks[r][c8]) = *reinterpret_cast<const uint4*>(
                kh + ((size_t)bh * L_ + kb * 64 + r) * 64 + c8);
            *reinterpret_cast<uint4*>(&Vs[r][c8]) = *reinterpret_cast<const uint4*>(
                vT + ((size_t)bh * 64 + r) * L_ + kb * 64 + c8);
        }
        __syncthreads();

        f32x4 sv[4];
        #pragma unroll
        for (int ct = 0; ct < 4; ++ct) {
            frag_t bk0 = *reinterpret_cast<const frag_t*>(&Ks[ct * 16 + lr][lg * 8]);
            frag_t bk1 = *reinterpret_cast<const frag_t*>(&Ks[ct * 16 + lr][32 + lg * 8]);
            f32x4 z = {0.f, 0.f, 0.f, 0.f};
            z = __builtin_amdgcn_mfma_f32_16x16x32_bf16(aq[0], bk0, z, 0, 0, 0);
            sv[ct] = __builtin_amdgcn_mfma_f32_16x16x32_bf16(aq[1], bk1, z, 0, 0, 0);
        }

        bool diag = (kb == qb);
        float esc[4];
        #pragma unroll
        for (int e = 0; e < 4; ++e) {
            int qg = qb * 64 + wid * 16 + lg * 4 + e;
            float mx = -1e30f;
            #pragma unroll
            for (int ct = 0; ct < 4; ++ct) {
                float s = sv[ct][e];
                if (diag && (kb * 64 + ct * 16 + lr > qg)) s = -1e30f;
                sv[ct][e] = s;
                mx = fmaxf(mx, s);
            }
            #pragma unroll
            for (int msk = 8; msk; msk >>= 1) mx = fmaxf(mx, __shfl_xor(mx, msk));
            float newM = fmaxf(M[e], mx);
            float ps = 0.f;
            #pragma unroll
            for (int ct = 0; ct < 4; ++ct) {
                float p = __expf(sv[ct][e] - newM);
                sv[ct][e] = p;
                ps += p;
            }
            #pragma unroll
            for (int msk = 8; msk; msk >>= 1) ps += __shfl_xor(ps, msk);
            esc[e] = __expf(M[e] - newM);
            S[e] = S[e] * esc[e] + ps;
            M[e] = newM;
        }
        #pragma unroll
        for (int dt = 0; dt < 4; ++dt)
            #pragma unroll
            for (int e = 0; e < 4; ++e) accO[dt][e] *= esc[e];

        #pragma unroll
        for (int ct = 0; ct < 4; ++ct)
            #pragma unroll
            for (int e = 0; e < 4; ++e)
                Ps[wid * 16 + lg * 4 + e][ct * 16 + lr] = f2bf(sv[ct][e]);

        frag_t pa0 = *reinterpret_cast<const frag_t*>(&Ps[wid * 16 + lr][lg * 8]);
        frag_t pa1 = *reinterpret_cast<const frag_t*>(&Ps[wid * 16 + lr][32 + lg * 8]);
        #pragma unroll
        for (int dt = 0; dt < 4; ++dt) {
            frag_t bv0 = *reinterpret_cast<const frag_t*>(&Vs[dt * 16 + lr][lg * 8]);
            frag_t bv1 = *reinterpret_cast<const frag_t*>(&Vs[dt * 16 + lr][32 + lg * 8]);
            accO[dt] = __builtin_amdgcn_mfma_f32_16x16x32_bf16(pa0, bv0, accO[dt], 0, 0, 0);
            accO[dt] = __builtin_amdgcn_mfma_f32_16x16x32_bf16(pa1, bv1, accO[dt], 0, 0, 0);
        }
    }

    #pragma unroll
    for (int dt = 0; dt < 4; ++dt) {
        #pragma unroll
        for (int e = 0; e < 4; ++e) {
            int row = b * L_ + qb * 64 + wid * 16 + lg * 4 + e;
            o[(size_t)row * D_ + hh * 64 + dt * 16 + lr] = f2bf(accO[dt][e] / S[e]);
        }
    }
}

// ---------------------------------------------------------------------------
// tiny heads: per token, shared rsqrt; reward (2) + box (4) dot products.
__global__ __launch_bounds__(256) void k_heads3(float* __restrict__ out_reward,
                                                float* __restrict__ out_box,
                                                const float* __restrict__ h,
                                                const float* __restrict__ rnw,
                                                const float* __restrict__ rW,
                                                const float* __restrict__ rb,
                                                const float* __restrict__ bnw,
                                                const float* __restrict__ bW,
                                                const float* __restrict__ bb) {
    int t = blockIdx.x;
    size_t base = (size_t)t * D_;
    float x[3];
    float ss = 0.f;
    #pragma unroll
    for (int c = 0; c < 3; ++c) {
        int i = threadIdx.x + c * 256;
        x[c] = h[base + i];
        ss += x[c] * x[c];
    }
    for (int off = 32; off > 0; off >>= 1) ss += __shfl_down(ss, off);
    __shared__ float red[4];
    int wid = threadIdx.x >> 6, lane = threadIdx.x & 63;
    if (lane == 0) red[wid] = ss;
    __syncthreads();
    float inv = rsqrtf((red[0] + red[1] + red[2] + red[3]) / (float)D_ + 1e-6f);

    float a[6] = {};
    #pragma unroll
    for (int c = 0; c < 3; ++c) {
        int i = threadIdx.x + c * 256;
        float xr = x[c] * inv;
        float xw = xr * rnw[i];
        a[0] += xw * rW[i * 2];
        a[1] += xw * rW[i * 2 + 1];
        float xb = xr * bnw[i];
        #pragma unroll
        for (int j = 0; j < 4; ++j) a[2 + j] += xb * bW[i * 4 + j];
    }
    #pragma unroll
    for (int j = 0; j < 6; ++j)
        for (int off = 32; off > 0; off >>= 1) a[j] += __shfl_down(a[j], off);
    __shared__ float red2[4][6];
    if (lane == 0)
        #pragma unroll
        for (int j = 0; j < 6; ++j) red2[wid][j] = a[j];
    __syncthreads();
    if (threadIdx.x < 6) {
        float s = red2[0][threadIdx.x] + red2[1][threadIdx.x] +
                  red2[2][threadIdx.x] + red2[3][threadIdx.x];
        if (threadIdx.x < 2) out_reward[(size_t)t * 2 + threadIdx.x] = s + rb[threadIdx.x];
        else                 out_box[(size_t)t * 4 + threadIdx.x - 2] = s + bb[threadIdx.x - 2];
    }
}

// ---------------------------------------------------------------------------
extern "C" void kernel_launch(void* const* d_in, const int* in_sizes, int n_in,
                              void* d_out, int out_size, void* d_ws, size_t ws_size,
                              hipStream_t stream) {
    const float* patch        = (const float*)d_in[0];
    const float* box          = (const float*)d_in[1];
    const float* patch_W      = (const float*)d_in[2];
    const float* patch_b      = (const float*)d_in[3];
    const float* box_W        = (const float*)d_in[4];
    const float* box_b        = (const float*)d_in[5];
    const float* Wq           = (const float*)d_in[6];
    const float* Wk           = (const float*)d_in[7];
    const float* Wv           = (const float*)d_in[8];
    const float* Wo           = (const float*)d_in[9];
    const float* attn_norm_w  = (const float*)d_in[10];
    const float* gate_W       = (const float*)d_in[11];
    const float* hidden_W     = (const float*)d_in[12];
    const float* ffn_out_W    = (const float*)d_in[13];
    const float* ffn_norm_w   = (const float*)d_in[14];
    const float* reward_norm_w= (const float*)d_in[15];
    const float* reward_W     = (const float*)d_in[16];
    const float* reward_b     = (const float*)d_in[17];
    const float* label_norm_w = (const float*)d_in[18];
    const float* label_W      = (const float*)d_in[19];
    const float* label_b      = (const float*)d_in[20];
    const float* box_norm_w   = (const float*)d_in[21];
    const float* boxh_W       = (const float*)d_in[22];
    const float* boxh_b       = (const float*)d_in[23];

    char* w = (char*)d_ws;
    auto alloc = [&](size_t bytes) { char* p = w; w += (bytes + 255) & ~(size_t)255; return p; };

    // all-layer converted weights (~226 MB; d_ws observed >= ~450 MB)
    u16*  wqkv_a = (u16*)alloc((size_t)NL_ * 2304 * 768 * 2);
    u16*  wo_a   = (u16*)alloc((size_t)NL_ * 768 * 768 * 2);
    u16*  wgh_a  = (u16*)alloc((size_t)NL_ * 6144 * 768 * 2);
    u16*  wfo_a  = (u16*)alloc((size_t)NL_ * 768 * 3072 * 2);
    u16*  wcat   = (u16*)alloc((size_t)768 * 1536 * 2);
    u16*  wlab   = (u16*)alloc((size_t)1024 * 768 * 2);
    float* bias_c= (float*)alloc((size_t)768 * 4);
    u16*  emb    = (u16*)alloc((size_t)MTOK * 1536 * 2);  // reused as qh|kh
    float* h     = (float*)alloc((size_t)MTOK * D_ * 4);
    u16*  hn_bf  = (u16*)alloc((size_t)MTOK * D_ * 2);
    u16*  qkv_bf = (u16*)alloc((size_t)MTOK * 2304 * 2);
    u16*  vT     = (u16*)alloc((size_t)MTOK * D_ * 2);
    float* tab   = (float*)alloc((size_t)L_ * 32 * 2 * 4);
    u16*  o_bf   = (u16*)alloc((size_t)MTOK * D_ * 2);
    u16*  ga_bf  = (u16*)alloc((size_t)MTOK * DFF_ * 2);
    float* part  = (float*)alloc((size_t)4 * MTOK * D_ * 4);

    u16* qh = emb;                       // emb dead after embedding GEMM
    u16* kh = emb + (size_t)MTOK * 768;

    dim3 blk(256);

    // one-time converts (all layers, batched)
    k_convT<<<dim3(24, 24), blk, 0, stream>>>(wcat, patch_W, 768, 768, 1536, 1, 0, 0);
    k_convT<<<dim3(24, 24), blk, 0, stream>>>(wcat, box_W,   768, 768, 1536, 1, 0, 768);
    k_convT<<<dim3(32, 24), blk, 0, stream>>>(wlab, label_W, 768, 1000, 768, 1, 0, 0);
    k_addb<<<3, blk, 0, stream>>>(bias_c, patch_b, box_b);
    k_rope_tab<<<(L_ * 32 + 255) / 256, blk, 0, stream>>>(tab);
    k_convT_qkv<<<dim3(24, 24, 36), blk, 0, stream>>>(wqkv_a, Wq, Wk, Wv);
    k_convT_b1<<<dim3(24, 24, 12), blk, 0, stream>>>(wo_a, Wo, 768, 768);
    k_convT_gh<<<dim3(96, 24, 24), blk, 0, stream>>>(wgh_a, gate_W, hidden_W);
    k_convT_b1<<<dim3(24, 96, 12), blk, 0, stream>>>(wfo_a, ffn_out_W, 3072, 768);
    k_cast<<<(MTOK * 768 / 4 + 255) / 256, blk, 0, stream>>>(emb, patch, MTOK * 768 / 4);
    k_box_sin<<<(MTOK * D_ + 255) / 256, blk, 0, stream>>>(emb, box);

    // embedding: h = [patch|box_sin] @ [patch_W; box_W] + (patch_b+box_b)
    k_gemm_bf16<0><<<dim3(6, 32), blk, 0, stream>>>(h, emb, wcat, bias_c, 1536, 768, 768);
    k_rmsnorm<<<MTOK, blk, 0, stream>>>(hn_bf, h, attn_norm_w);

    for (int ly = 0; ly < NL_; ++ly) {
        const u16* wqkv = wqkv_a + (size_t)ly * 2304 * 768;
        const u16* wo_l = wo_a   + (size_t)ly * 768 * 768;
        const u16* wgh  = wgh_a  + (size_t)ly * 6144 * 768;
        const u16* wfo  = wfo_a  + (size_t)ly * 768 * 3072;
        const float* fnw = ffn_norm_w + (size_t)ly * D_;
        const float* nxt = (ly + 1 < NL_) ? attn_norm_w + (size_t)(ly + 1) * D_
                                          : label_norm_w;

        k_gemm_bf16<3><<<dim3(18, 32), blk, 0, stream>>>(qkv_bf, hn_bf, wqkv, nullptr, 768, 2304, 2304);
        k_qkvprep<<<dim3(96, 16), blk, 0, stream>>>(qh, kh, vT, qkv_bf, tab);
        k_attn3<<<dim3(96, 8), blk, 0, stream>>>(o_bf, qh, kh, vT);
        k_gemm_bf16<4><<<dim3(6, 32, 2), blk, 0, stream>>>(part, o_bf, wo_l, nullptr, 768, 768, 768);
        k_fused_rr<2><<<MTOK, blk, 0, stream>>>(h, part, hn_bf, fnw);

        k_gemm_bf16<5><<<dim3(48, 32), blk, 0, stream>>>(ga_bf, hn_bf, wgh, nullptr, 768, 6144, 3072);
        k_gemm_bf16<4><<<dim3(6, 32, 4), blk, 0, stream>>>(part, ga_bf, wfo, nullptr, 3072, 768, 768);
        k_fused_rr<4><<<MTOK, blk, 0, stream>>>(h, part, hn_bf, nxt);
    }

    // heads: hn_bf already = rmsnorm(h, label_norm_w)
    float* out_reward = (float*)d_out;
    float* out_label  = out_reward + (size_t)MTOK * 2;
    float* out_box    = out_label + (size_t)MTOK * 1000;

    k_gemm_bf16<0><<<dim3(8, 32), blk, 0, stream>>>(out_label, hn_bf, wlab, label_b, 768, 1000, 1000);
    k_heads3<<<MTOK, blk, 0, stream>>>(out_reward, out_box, h,
                                       reward_norm_w, reward_W, reward_b,
                                       box_norm_w, boxh_W, boxh_b);
}

// Round 9
// 2316.741 us; speedup vs baseline: 9.9253x; 1.0645x over previous
//
#include <hip/hip_runtime.h>
#include <math.h>
#include <type_traits>

#define B_   8
#define L_   512
#define MTOK 4096           // B_*L_
#define D_   768
#define NH_  12
#define DH_  64
#define DFF_ 3072
#define NL_  12

typedef unsigned short u16;
typedef __attribute__((ext_vector_type(4))) float f32x4;
typedef __attribute__((ext_vector_type(8))) short i16x8;
typedef __attribute__((ext_vector_type(8))) __bf16 b16x8;

// Pick whichever vector type the gfx950 bf16 MFMA builtin accepts.
template <typename A, typename = void>
struct PickFrag { using type = i16x8; };
template <typename A>
struct PickFrag<A, std::void_t<decltype(__builtin_amdgcn_mfma_f32_16x16x32_bf16(
    std::declval<A>(), std::declval<A>(), std::declval<f32x4>(), 0, 0, 0))>> {
  using type = A;
};
using frag_t = typename PickFrag<b16x8>::type;

#if __has_builtin(__builtin_amdgcn_global_load_lds)
#define HAS_GLDS 1
#else
#define HAS_GLDS 0
#endif

__device__ inline u16 f2bf(float f) {
    unsigned u = __float_as_uint(f);
    unsigned r = u + 0x7fffu + ((u >> 16) & 1u);
    return (u16)(r >> 16);
}
__device__ inline float bf2f(u16 b) { return __uint_as_float(((unsigned)b) << 16); }

// compiler-fenced raw barrier (no vmcnt drain, unlike __syncthreads)
__device__ inline void bar_raw() {
    asm volatile("" ::: "memory");
    __builtin_amdgcn_s_barrier();
    asm volatile("" ::: "memory");
}

// ---------------------------------------------------------------------------
// box sinusoid embedding -> bf16 into emb[t*1536 + 768 + d]
__global__ void k_box_sin(u16* __restrict__ emb, const float* __restrict__ box) {
    int idx = blockIdx.x * blockDim.x + threadIdx.x;
    if (idx >= MTOK * D_) return;
    int t = idx / D_, d = idx % D_;
    int c = d / 192, r = d % 192, j = r >> 1;
    float theta = __expf(-(float)j * (9.210340371976184f / 96.0f));
    float ang = box[t * 4 + c] * theta;
    emb[(size_t)t * 1536 + 768 + d] = f2bf((r & 1) ? sinf(ang) : cosf(ang));
}

// fp32 patch -> bf16 into emb[t*1536 + c]
__global__ void k_cast(u16* __restrict__ emb, const float* __restrict__ in, int n4) {
    int i = blockIdx.x * blockDim.x + threadIdx.x;
    if (i >= n4) return;            // n4 = MTOK*768/4
    int t = i / 192, c4 = (i % 192) * 4;
    float4 v = *reinterpret_cast<const float4*>(in + (size_t)t * 768 + c4);
    unsigned lo = (unsigned)f2bf(v.x) | ((unsigned)f2bf(v.y) << 16);
    unsigned hi = (unsigned)f2bf(v.z) | ((unsigned)f2bf(v.w) << 16);
    *reinterpret_cast<uint2*>(emb + (size_t)t * 1536 + c4) = make_uint2(lo, hi);
}

// combined bias
__global__ void k_addb(float* __restrict__ dst, const float* __restrict__ a,
                       const float* __restrict__ b) {
    int i = blockIdx.x * blockDim.x + threadIdx.x;
    if (i < D_) dst[i] = a[i] + b[i];
}

// ---------------------------------------------------------------------------
// generic transpose-convert (small one-offs): src (K,N) fp32
// -> dst[(n*rs+ro)*ld + co + k] bf16; zero rows for n>=N.
__global__ __launch_bounds__(256) void k_convT(u16* __restrict__ dst,
                                               const float* __restrict__ src,
                                               int K, int N, int ld, int rs,
                                               int ro, int co) {
    __shared__ float t[32][33];
    int bn = blockIdx.x * 32;
    int bk = blockIdx.y * 32;
    int tx = threadIdx.x % 32, ty = threadIdx.x / 32;
    #pragma unroll
    for (int i = 0; i < 4; ++i) {
        int k = bk + ty + i * 8;
        int n = bn + tx;
        t[ty + i * 8][tx] = (n < N) ? src[(size_t)k * N + n] : 0.0f;
    }
    __syncthreads();
    #pragma unroll
    for (int i = 0; i < 4; ++i) {
        int n = bn + ty + i * 8;
        int k = bk + tx;
        dst[(size_t)(n * rs + ro) * ld + co + k] = f2bf(t[tx][ty + i * 8]);
    }
}

// ---------------------------------------------------------------------------
// vectorized batched transposers: 32n x 64k tiles, uint4 (16B) writes.
// grid (N/32, K/64, Z). Read coalesced 128B rows; write 128B per dst row.

// plain: src[z] (K,N) -> dst[z] (N,K)
__global__ __launch_bounds__(256) void k_convT64(u16* __restrict__ dst,
                                                 const float* __restrict__ src,
                                                 int K, int N) {
    __shared__ float ts[32][65];
    const float* s = src + (size_t)blockIdx.z * K * N;
    u16* d = dst + (size_t)blockIdx.z * K * N;
    int bn = blockIdx.x * 32, bk = blockIdx.y * 64;
    int t = threadIdx.x, rn = t & 31;
    #pragma unroll
    for (int p = 0; p < 8; ++p) {
        int k = p * 8 + (t >> 5);
        ts[rn][k] = s[(size_t)(bk + k) * N + bn + rn];
    }
    __syncthreads();
    int n = t >> 3, kc = (t & 7) * 8;
    u16 tmp[8];
    #pragma unroll
    for (int j = 0; j < 8; ++j) tmp[j] = f2bf(ts[n][kc + j]);
    *reinterpret_cast<uint4*>(&d[(size_t)(bn + n) * K + bk + kc]) =
        *reinterpret_cast<uint4*>(tmp);
}

// QKV: z = ly*3 + which; dst slab [3][768][768] per layer
__global__ __launch_bounds__(256) void k_convT64_qkv(u16* __restrict__ dst,
                                                     const float* __restrict__ s0,
                                                     const float* __restrict__ s1,
                                                     const float* __restrict__ s2) {
    __shared__ float ts[32][65];
    int ly = blockIdx.z / 3, which = blockIdx.z % 3;
    const float* s = (which == 0 ? s0 : (which == 1 ? s1 : s2)) + (size_t)ly * 768 * 768;
    u16* d = dst + ((size_t)ly * 3 + which) * 768 * 768;
    int bn = blockIdx.x * 32, bk = blockIdx.y * 64;
    int t = threadIdx.x, rn = t & 31;
    #pragma unroll
    for (int p = 0; p < 8; ++p) {
        int k = p * 8 + (t >> 5);
        ts[rn][k] = s[(size_t)(bk + k) * 768 + bn + rn];
    }
    __syncthreads();
    int n = t >> 3, kc = (t & 7) * 8;
    u16 tmp[8];
    #pragma unroll
    for (int j = 0; j < 8; ++j) tmp[j] = f2bf(ts[n][kc + j]);
    *reinterpret_cast<uint4*>(&d[(size_t)(bn + n) * 768 + bk + kc]) =
        *reinterpret_cast<uint4*>(tmp);
}

// gate/hidden 16-col interleave: z = ly*2 + which; col n -> row (n>>4)*32+(n&15)+which*16
__global__ __launch_bounds__(256) void k_convT64_gh(u16* __restrict__ dst,
                                                    const float* __restrict__ g,
                                                    const float* __restrict__ h) {
    __shared__ float ts[32][65];
    int ly = blockIdx.z >> 1, which = blockIdx.z & 1;
    const float* s = (which ? h : g) + (size_t)ly * 768 * 3072;
    u16* d = dst + (size_t)ly * 6144 * 768;
    int bn = blockIdx.x * 32, bk = blockIdx.y * 64;
    int t = threadIdx.x, rn = t & 31;
    #pragma unroll
    for (int p = 0; p < 8; ++p) {
        int k = p * 8 + (t >> 5);
        ts[rn][k] = s[(size_t)(bk + k) * 3072 + bn + rn];
    }
    __syncthreads();
    int n = t >> 3, kc = (t & 7) * 8;
    int ng = bn + n;
    int row = ((ng >> 4) << 5) + (ng & 15) + which * 16;
    u16 tmp[8];
    #pragma unroll
    for (int j = 0; j < 8; ++j) tmp[j] = f2bf(ts[n][kc + j]);
    *reinterpret_cast<uint4*>(&d[(size_t)row * 768 + bk + kc]) =
        *reinterpret_cast<uint4*>(tmp);
}

// ---------------------------------------------------------------------------
// RMSNorm: one block per token, bf16 out
__global__ __launch_bounds__(256) void k_rmsnorm(u16* __restrict__ out,
                                                 const float* __restrict__ in,
                                                 const float* __restrict__ w) {
    int t = blockIdx.x;
    const float* x = in + (size_t)t * D_;
    float ss = 0.f;
    for (int i = threadIdx.x; i < D_; i += 256) { float v = x[i]; ss += v * v; }
    for (int off = 32; off > 0; off >>= 1) ss += __shfl_down(ss, off);
    __shared__ float red[4];
    int wid = threadIdx.x >> 6, lane = threadIdx.x & 63;
    if (lane == 0) red[wid] = ss;
    __syncthreads();
    float tot = red[0] + red[1] + red[2] + red[3];
    float inv = rsqrtf(tot / (float)D_ + 1e-6f);
    for (int i = threadIdx.x; i < D_; i += 256)
        out[(size_t)t * D_ + i] = f2bf(x[i] * inv * w[i]);
}

// ---------------------------------------------------------------------------
// fused: h += sum_s part[s]; hn = bf16(rmsnorm(h, w)). one block per token.
template <int S>
__global__ __launch_bounds__(256) void k_fused_rr(float* __restrict__ h,
                                                  const float* __restrict__ part,
                                                  u16* __restrict__ hn,
                                                  const float* __restrict__ w) {
    int t = blockIdx.x;
    size_t base = (size_t)t * D_;
    float x[3];
    float ss = 0.f;
    #pragma unroll
    for (int c = 0; c < 3; ++c) {
        int i = threadIdx.x + c * 256;
        float v = h[base + i];
        #pragma unroll
        for (int s = 0; s < S; ++s)
            v += part[(size_t)s * MTOK * D_ + base + i];
        x[c] = v;
        h[base + i] = v;
        ss += v * v;
    }
    for (int off = 32; off > 0; off >>= 1) ss += __shfl_down(ss, off);
    __shared__ float red[4];
    int wid = threadIdx.x >> 6, lane = threadIdx.x & 63;
    if (lane == 0) red[wid] = ss;
    __syncthreads();
    float tot = red[0] + red[1] + red[2] + red[3];
    float inv = rsqrtf(tot / (float)D_ + 1e-6f);
    #pragma unroll
    for (int c = 0; c < 3; ++c) {
        int i = threadIdx.x + c * 256;
        hn[base + i] = f2bf(x[c] * inv * w[i]);
    }
}

// ---------------------------------------------------------------------------
// one-time RoPE table: tab[(l*32+j)*2] = cos(l*theta_j), +1 = sin
__global__ void k_rope_tab(float* __restrict__ tab) {
    int idx = blockIdx.x * blockDim.x + threadIdx.x;   // 512*32
    if (idx >= L_ * 32) return;
    int l = idx >> 5, j = idx & 31;
    float theta = __expf(-(float)j * (9.210340371976184f / 32.0f));
    float s, c;
    sincosf((float)l * theta, &s, &c);
    tab[idx * 2] = c;
    tab[idx * 2 + 1] = s;
}

// ---------------------------------------------------------------------------
// bf16 MFMA GEMM, double-buffered, counted-vmcnt, XCD swizzle, split-K.
// C[M x Nout](ldC) (+)= A[M,K]bf16 @ BT[Nt,K]bf16^T (+bias)
// grid = (Nt/128, M/128, SPLITK), 256 threads. K % (32*SPLITK) == 0.
// MODE 0: C=acc(+bias) f32   MODE 3: C=acc bf16
// MODE 4: partial fp32 store to Cp + sk*M*ldC (split-K)
// MODE 5: silu-gate 16-col interleave: C bf16 [M x Nout/2], out=silu(g)*h
// MODE 6: fused QKV epilogue. Cp = qkvh base ([q|k|vT] each MTOK*768 u16),
//         bias = rope table (float2[512][32]). Q cols 0-767 rope*0.125,
//         K cols 768-1535 rope, V cols 1536+ transposed to [96][64][512].
template <int MODE>
__global__ __launch_bounds__(256) void k_gemm_bf16(void* __restrict__ Cp,
                                                   const u16* __restrict__ A,
                                                   const u16* __restrict__ BT,
                                                   const float* __restrict__ bias,
                                                   int K, int Nout, int ldC) {
    __shared__ u16 smem[16384];          // As[2][4096] | Bs[2][4096]
    int tid = threadIdx.x;
    int wid = tid >> 6, lane = tid & 63;

    // ---- XCD-aware swizzle over full 3D linear block id (nwg % 8 == 0) ----
    int nx = gridDim.x, ny = gridDim.y, nz = gridDim.z;
    int bid = ((blockIdx.z * ny) + blockIdx.y) * nx + blockIdx.x;
    int nwg = nx * ny * nz;
    int cpx = nwg >> 3;
    int swz = (bid & 7) * cpx + (bid >> 3);
    int sk  = swz / (nx * ny);
    int rem = swz % (nx * ny);
    int by = rem / nx, bx = rem % nx;
    int row0 = by * 128, col0 = bx * 128;
    int wr = wid >> 1, wc = wid & 1;

    int Klen = K / nz;
    int kbeg = sk * Klen;

    int c0 = wid * 128 + lane;          // 0..511
    int c1 = c0 + 64;
    int r0 = c0 >> 2, kc0 = (c0 & 3) * 8;
    int r1 = c1 >> 2, kc1 = (c1 & 3) * 8;
    const u16* gA0 = A  + (size_t)(row0 + r0) * K + kbeg + kc0;
    const u16* gA1 = A  + (size_t)(row0 + r1) * K + kbeg + kc1;
    const u16* gB0 = BT + (size_t)(col0 + r0) * K + kbeg + kc0;
    const u16* gB1 = BT + (size_t)(col0 + r1) * K + kbeg + kc1;

    auto stage = [&](int buf, int kt) {
        u16* Asb = smem + buf * 4096;
        u16* Bsb = smem + 8192 + buf * 4096;
#if HAS_GLDS
        __builtin_amdgcn_global_load_lds(
            (const __attribute__((address_space(1))) void*)(gA0 + kt),
            (__attribute__((address_space(3))) void*)&Asb[c0 * 8], 16, 0, 0);
        __builtin_amdgcn_global_load_lds(
            (const __attribute__((address_space(1))) void*)(gA1 + kt),
            (__attribute__((address_space(3))) void*)&Asb[c1 * 8], 16, 0, 0);
        __builtin_amdgcn_global_load_lds(
            (const __attribute__((address_space(1))) void*)(gB0 + kt),
            (__attribute__((address_space(3))) void*)&Bsb[c0 * 8], 16, 0, 0);
        __builtin_amdgcn_global_load_lds(
            (const __attribute__((address_space(1))) void*)(gB1 + kt),
            (__attribute__((address_space(3))) void*)&Bsb[c1 * 8], 16, 0, 0);
#else
        *reinterpret_cast<uint4*>(&Asb[c0 * 8]) = *reinterpret_cast<const uint4*>(gA0 + kt);
        *reinterpret_cast<uint4*>(&Asb[c1 * 8]) = *reinterpret_cast<const uint4*>(gA1 + kt);
        *reinterpret_cast<uint4*>(&Bsb[c0 * 8]) = *reinterpret_cast<const uint4*>(gB0 + kt);
        *reinterpret_cast<uint4*>(&Bsb[c1 * 8]) = *reinterpret_cast<const uint4*>(gB1 + kt);
#endif
    };

    f32x4 acc[4][4] = {};
    int lrow = lane & 15, lk = (lane >> 4) * 8;

    stage(0, 0);
    int cur = 0;
    for (int kt = 0; kt < Klen; kt += 32) {
        bool has_next = (kt + 32 < Klen);
        if (has_next) stage(cur ^ 1, kt + 32);
        if (has_next) asm volatile("s_waitcnt vmcnt(4) lgkmcnt(0)" ::: "memory");
        else          asm volatile("s_waitcnt vmcnt(0) lgkmcnt(0)" ::: "memory");
        __builtin_amdgcn_sched_barrier(0);
        bar_raw();
        const u16* Asb = smem + cur * 4096;
        const u16* Bsb = smem + 8192 + cur * 4096;
        frag_t af[4], bfr[4];
        #pragma unroll
        for (int m = 0; m < 4; ++m)
            af[m] = *reinterpret_cast<const frag_t*>(&Asb[(wr * 64 + m * 16 + lrow) * 32 + lk]);
        #pragma unroll
        for (int n = 0; n < 4; ++n)
            bfr[n] = *reinterpret_cast<const frag_t*>(&Bsb[(wc * 64 + n * 16 + lrow) * 32 + lk]);
        #pragma unroll
        for (int m = 0; m < 4; ++m)
            #pragma unroll
            for (int n = 0; n < 4; ++n)
                acc[m][n] = __builtin_amdgcn_mfma_f32_16x16x32_bf16(af[m], bfr[n], acc[m][n], 0, 0, 0);
        bar_raw();
        cur ^= 1;
    }

    int lcol = lane & 15, rb = (lane >> 4) * 4;

    if (MODE == 6) {
        u16* qkvh = (u16*)Cp;
        const float* tab = bias;
        if (col0 >= 1536) {
            // ---- V: transpose via LDS -> vT [96][64][512] ----
            int head_base = (col0 - 1536) >> 6;
            int bb = row0 >> 9;
            int l0 = row0 & 511;
            #pragma unroll
            for (int pass = 0; pass < 2; ++pass) {
                if (wc == pass) {
                    #pragma unroll
                    for (int m = 0; m < 4; ++m) {
                        #pragma unroll
                        for (int n = 0; n < 4; ++n) {
                            int dl = n * 16 + lcol;
                            int rl = wr * 64 + m * 16 + rb;
                            u16 tmp[4];
                            #pragma unroll
                            for (int e = 0; e < 4; ++e) tmp[e] = f2bf(acc[m][n][e]);
                            *reinterpret_cast<uint2*>(&smem[dl * 136 + rl]) =
                                *reinterpret_cast<uint2*>(tmp);
                        }
                    }
                }
                __syncthreads();
                int head = head_base + pass;
                size_t vbase = (size_t)2 * MTOK * 768 +
                               ((size_t)(bb * NH_ + head) * 64) * 512;
                #pragma unroll
                for (int it = 0; it < 4; ++it) {
                    int dd = it * 16 + (tid >> 4);
                    int rr = (tid & 15) * 8;
                    uint4 v4 = *reinterpret_cast<const uint4*>(&smem[dd * 136 + rr]);
                    *reinterpret_cast<uint4*>(&qkvh[vbase + (size_t)dd * 512 + l0 + rr]) = v4;
                }
                __syncthreads();
            }
        } else {
            // ---- Q/K: rope in-register, write head layout ----
            int sec = col0 / 768;               // 0=Q, 1=K (uniform per block)
            float qscale = (sec == 0) ? 0.125f : 1.0f;
            #pragma unroll
            for (int m = 0; m < 4; ++m) {
                #pragma unroll
                for (int n = 0; n < 4; ++n) {
                    int col = col0 + wc * 64 + n * 16 + lcol;
                    int head = (col % 768) >> 6;
                    int d = col & 63;
                    #pragma unroll
                    for (int e = 0; e < 4; ++e) {
                        int row = row0 + wr * 64 + m * 16 + rb + e;
                        int bb = row >> 9, l = row & 511;
                        float v = acc[m][n][e];
                        float p = __shfl_xor(v, 1);
                        float2 cs = *reinterpret_cast<const float2*>(
                            tab + ((size_t)l * 32 + (d >> 1)) * 2);
                        float r = (d & 1) ? (p * cs.y + v * cs.x)
                                          : (v * cs.x - p * cs.y);
                        r *= qscale;
                        qkvh[(size_t)sec * MTOK * 768 +
                             ((size_t)(bb * NH_ + head) * 512 + l) * 64 + d] = f2bf(r);
                    }
                }
            }
        }
        return;
    }

    if (MODE == 5) {
        #pragma unroll
        for (int m = 0; m < 4; ++m) {
            #pragma unroll
            for (int np = 0; np < 2; ++np) {
                int ocol = (col0 >> 1) + wc * 32 + np * 16 + lcol;
                #pragma unroll
                for (int e = 0; e < 4; ++e) {
                    int row = row0 + wr * 64 + m * 16 + rb + e;
                    float g = acc[m][2 * np][e], hv = acc[m][2 * np + 1][e];
                    float s = g / (1.0f + __expf(-g));
                    ((u16*)Cp)[(size_t)row * ldC + ocol] = f2bf(s * hv);
                }
            }
        }
        return;
    }

    float* Cpart = (MODE == 4)
        ? ((float*)Cp + (size_t)sk * (size_t)(ny * 128) * ldC) : (float*)Cp;
    #pragma unroll
    for (int m = 0; m < 4; ++m) {
        #pragma unroll
        for (int n = 0; n < 4; ++n) {
            int col = col0 + wc * 64 + n * 16 + lcol;
            if (col >= Nout) continue;
            #pragma unroll
            for (int e = 0; e < 4; ++e) {
                int row = row0 + wr * 64 + m * 16 + rb + e;
                float v = acc[m][n][e];
                size_t off = (size_t)row * ldC + col;
                if (MODE == 0) {
                    if (bias) v += bias[col];
                    ((float*)Cp)[off] = v;
                } else if (MODE == 3) {
                    ((u16*)Cp)[off] = f2bf(v);
                } else if (MODE == 4) {
                    Cpart[off] = v;
                }
            }
        }
    }
}

// ---------------------------------------------------------------------------
// MFMA flash attention. grid (96 bh, 8 qb), 256 thr = 4 waves x 16 q-rows.
// qh (pre-scaled 1/8), kh: [96][512][64] bf16; vT: [96][64][512] bf16.
__global__ __launch_bounds__(256) void k_attn3(u16* __restrict__ o,
                                               const u16* __restrict__ qh,
                                               const u16* __restrict__ kh,
                                               const u16* __restrict__ vT) {
    int bh = blockIdx.x, qb = blockIdx.y;
    int b = bh / NH_, hh = bh % NH_;
    int tid = threadIdx.x, wid = tid >> 6, lane = tid & 63;
    __shared__ u16 Qs[64][72], Ks[64][72], Vs[64][72], Ps[64][72];

    #pragma unroll
    for (int i = 0; i < 2; ++i) {
        int idx = tid + i * 256;
        int r = idx >> 3, c8 = (idx & 7) * 8;
        uint4 v4 = *reinterpret_cast<const uint4*>(
            qh + ((size_t)bh * L_ + qb * 64 + r) * 64 + c8);
        *reinterpret_cast<uint4*>(&Qs[r][c8]) = v4;
    }
    __syncthreads();

    int lr = lane & 15, lg = lane >> 4;
    frag_t aq[2];
    #pragma unroll
    for (int kd = 0; kd < 2; ++kd)
        aq[kd] = *reinterpret_cast<const frag_t*>(&Qs[wid * 16 + lr][kd * 32 + lg * 8]);

    f32x4 accO[4] = {};
    float M[4], S[4];
    #pragma unroll
    for (int e = 0; e < 4; ++e) { M[e] = -INFINITY; S[e] = 0.f; }

    for (int kb = 0; kb <= qb; ++kb) {
        __syncthreads();
        #pragma unroll
        for (int i = 0; i < 2; ++i) {
            int idx = tid + i * 256;
            int r = idx >> 3, c8 = (idx & 7) * 8;
            *reinterpret_cast<uint4*>(&Ks[r][c8]) = *reinterpret_cast<const uint4*>(
                kh + ((size_t)bh * L_ + kb * 64 + r) * 64 + c8);
            *reinterpret_cast<uint4*>(&Vs[r][c8]) = *reinterpret_cast<const uint4*>(
                vT + ((size_t)bh * 64 + r) * L_ + kb * 64 + c8);
        }
        __syncthreads();

        f32x4 sv[4];
        __builtin_amdgcn_s_setprio(1);
        #pragma unroll
        for (int ct = 0; ct < 4; ++ct) {
            frag_t bk0 = *reinterpret_cast<const frag_t*>(&Ks[ct * 16 + lr][lg * 8]);
            frag_t bk1 = *reinterpret_cast<const frag_t*>(&Ks[ct * 16 + lr][32 + lg * 8]);
            f32x4 z = {0.f, 0.f, 0.f, 0.f};
            z = __builtin_amdgcn_mfma_f32_16x16x32_bf16(aq[0], bk0, z, 0, 0, 0);
            sv[ct] = __builtin_amdgcn_mfma_f32_16x16x32_bf16(aq[1], bk1, z, 0, 0, 0);
        }
        __builtin_amdgcn_s_setprio(0);

        bool diag = (kb == qb);
        float esc[4];
        #pragma unroll
        for (int e = 0; e < 4; ++e) {
            int qg = qb * 64 + wid * 16 + lg * 4 + e;
            float mx = -1e30f;
            #pragma unroll
            for (int ct = 0; ct < 4; ++ct) {
                float s = sv[ct][e];
                if (diag && (kb * 64 + ct * 16 + lr > qg)) s = -1e30f;
                sv[ct][e] = s;
                mx = fmaxf(mx, s);
            }
            #pragma unroll
            for (int msk = 8; msk; msk >>= 1) mx = fmaxf(mx, __shfl_xor(mx, msk));
            float newM = fmaxf(M[e], mx);
            float ps = 0.f;
            #pragma unroll
            for (int ct = 0; ct < 4; ++ct) {
                float p = __expf(sv[ct][e] - newM);
                sv[ct][e] = p;
                ps += p;
            }
            #pragma unroll
            for (int msk = 8; msk; msk >>= 1) ps += __shfl_xor(ps, msk);
            esc[e] = __expf(M[e] - newM);
            S[e] = S[e] * esc[e] + ps;
            M[e] = newM;
        }
        #pragma unroll
        for (int dt = 0; dt < 4; ++dt)
            #pragma unroll
            for (int e = 0; e < 4; ++e) accO[dt][e] *= esc[e];

        #pragma unroll
        for (int ct = 0; ct < 4; ++ct)
            #pragma unroll
            for (int e = 0; e < 4; ++e)
                Ps[wid * 16 + lg * 4 + e][ct * 16 + lr] = f2bf(sv[ct][e]);

        frag_t pa0 = *reinterpret_cast<const frag_t*>(&Ps[wid * 16 + lr][lg * 8]);
        frag_t pa1 = *reinterpret_cast<const frag_t*>(&Ps[wid * 16 + lr][32 + lg * 8]);
        __builtin_amdgcn_s_setprio(1);
        #pragma unroll
        for (int dt = 0; dt < 4; ++dt) {
            frag_t bv0 = *reinterpret_cast<const frag_t*>(&Vs[dt * 16 + lr][lg * 8]);
            frag_t bv1 = *reinterpret_cast<const frag_t*>(&Vs[dt * 16 + lr][32 + lg * 8]);
            accO[dt] = __builtin_amdgcn_mfma_f32_16x16x32_bf16(pa0, bv0, accO[dt], 0, 0, 0);
            accO[dt] = __builtin_amdgcn_mfma_f32_16x16x32_bf16(pa1, bv1, accO[dt], 0, 0, 0);
        }
        __builtin_amdgcn_s_setprio(0);
    }

    #pragma unroll
    for (int dt = 0; dt < 4; ++dt) {
        #pragma unroll
        for (int e = 0; e < 4; ++e) {
            int row = b * L_ + qb * 64 + wid * 16 + lg * 4 + e;
            o[(size_t)row * D_ + hh * 64 + dt * 16 + lr] = f2bf(accO[dt][e] / S[e]);
        }
    }
}

// ---------------------------------------------------------------------------
// tiny heads: per token, shared rsqrt; reward (2) + box (4) dot products.
__global__ __launch_bounds__(256) void k_heads3(float* __restrict__ out_reward,
                                                float* __restrict__ out_box,
                                                const float* __restrict__ h,
                                                const float* __restrict__ rnw,
                                                const float* __restrict__ rW,
                                                const float* __restrict__ rb,
                                                const float* __restrict__ bnw,
                                                const float* __restrict__ bW,
                                                const float* __restrict__ bb) {
    int t = blockIdx.x;
    size_t base = (size_t)t * D_;
    float x[3];
    float ss = 0.f;
    #pragma unroll
    for (int c = 0; c < 3; ++c) {
        int i = threadIdx.x + c * 256;
        x[c] = h[base + i];
        ss += x[c] * x[c];
    }
    for (int off = 32; off > 0; off >>= 1) ss += __shfl_down(ss, off);
    __shared__ float red[4];
    int wid = threadIdx.x >> 6, lane = threadIdx.x & 63;
    if (lane == 0) red[wid] = ss;
    __syncthreads();
    float inv = rsqrtf((red[0] + red[1] + red[2] + red[3]) / (float)D_ + 1e-6f);

    float a[6] = {};
    #pragma unroll
    for (int c = 0; c < 3; ++c) {
        int i = threadIdx.x + c * 256;
        float xr = x[c] * inv;
        float xw = xr * rnw[i];
        a[0] += xw * rW[i * 2];
        a[1] += xw * rW[i * 2 + 1];
        float xb = xr * bnw[i];
        #pragma unroll
        for (int j = 0; j < 4; ++j) a[2 + j] += xb * bW[i * 4 + j];
    }
    #pragma unroll
    for (int j = 0; j < 6; ++j)
        for (int off = 32; off > 0; off >>= 1) a[j] += __shfl_down(a[j], off);
    __shared__ float red2[4][6];
    if (lane == 0)
        #pragma unroll
        for (int j = 0; j < 6; ++j) red2[wid][j] = a[j];
    __syncthreads();
    if (threadIdx.x < 6) {
        float s = red2[0][threadIdx.x] + red2[1][threadIdx.x] +
                  red2[2][threadIdx.x] + red2[3][threadIdx.x];
        if (threadIdx.x < 2) out_reward[(size_t)t * 2 + threadIdx.x] = s + rb[threadIdx.x];
        else                 out_box[(size_t)t * 4 + threadIdx.x - 2] = s + bb[threadIdx.x - 2];
    }
}

// ---------------------------------------------------------------------------
extern "C" void kernel_launch(void* const* d_in, const int* in_sizes, int n_in,
                              void* d_out, int out_size, void* d_ws, size_t ws_size,
                              hipStream_t stream) {
    const float* patch        = (const float*)d_in[0];
    const float* box          = (const float*)d_in[1];
    const float* patch_W      = (const float*)d_in[2];
    const float* patch_b      = (const float*)d_in[3];
    const float* box_W        = (const float*)d_in[4];
    const float* box_b        = (const float*)d_in[5];
    const float* Wq           = (const float*)d_in[6];
    const float* Wk           = (const float*)d_in[7];
    const float* Wv           = (const float*)d_in[8];
    const float* Wo           = (const float*)d_in[9];
    const float* attn_norm_w  = (const float*)d_in[10];
    const float* gate_W       = (const float*)d_in[11];
    const float* hidden_W     = (const float*)d_in[12];
    const float* ffn_out_W    = (const float*)d_in[13];
    const float* ffn_norm_w   = (const float*)d_in[14];
    const float* reward_norm_w= (const float*)d_in[15];
    const float* reward_W     = (const float*)d_in[16];
    const float* reward_b     = (const float*)d_in[17];
    const float* label_norm_w = (const float*)d_in[18];
    const float* label_W      = (const float*)d_in[19];
    const float* label_b      = (const float*)d_in[20];
    const float* box_norm_w   = (const float*)d_in[21];
    const float* boxh_W       = (const float*)d_in[22];
    const float* boxh_b       = (const float*)d_in[23];

    char* w = (char*)d_ws;
    auto alloc = [&](size_t bytes) { char* p = w; w += (bytes + 255) & ~(size_t)255; return p; };

    u16*  wqkv_a = (u16*)alloc((size_t)NL_ * 2304 * 768 * 2);
    u16*  wo_a   = (u16*)alloc((size_t)NL_ * 768 * 768 * 2);
    u16*  wgh_a  = (u16*)alloc((size_t)NL_ * 6144 * 768 * 2);
    u16*  wfo_a  = (u16*)alloc((size_t)NL_ * 768 * 3072 * 2);
    u16*  wcat   = (u16*)alloc((size_t)768 * 1536 * 2);
    u16*  wlab   = (u16*)alloc((size_t)1024 * 768 * 2);
    float* bias_c= (float*)alloc((size_t)768 * 4);
    u16*  emb    = (u16*)alloc((size_t)MTOK * 1536 * 2);
    float* h     = (float*)alloc((size_t)MTOK * D_ * 4);
    u16*  hn_bf  = (u16*)alloc((size_t)MTOK * D_ * 2);
    u16*  qkvh   = (u16*)alloc((size_t)MTOK * 2304 * 2);  // [q|k|vT] heads layout
    float* tab   = (float*)alloc((size_t)L_ * 32 * 2 * 4);
    u16*  o_bf   = (u16*)alloc((size_t)MTOK * D_ * 2);
    u16*  ga_bf  = (u16*)alloc((size_t)MTOK * DFF_ * 2);
    float* part  = (float*)alloc((size_t)4 * MTOK * D_ * 4);

    u16* qh = qkvh;
    u16* kh = qkvh + (size_t)MTOK * 768;
    u16* vT = qkvh + (size_t)2 * MTOK * 768;

    dim3 blk(256);

    // one-time converts (all layers, batched, vectorized writes)
    k_convT<<<dim3(24, 24), blk, 0, stream>>>(wcat, patch_W, 768, 768, 1536, 1, 0, 0);
    k_convT<<<dim3(24, 24), blk, 0, stream>>>(wcat, box_W,   768, 768, 1536, 1, 0, 768);
    k_convT<<<dim3(32, 24), blk, 0, stream>>>(wlab, label_W, 768, 1000, 768, 1, 0, 0);
    k_addb<<<3, blk, 0, stream>>>(bias_c, patch_b, box_b);
    k_rope_tab<<<(L_ * 32 + 255) / 256, blk, 0, stream>>>(tab);
    k_convT64_qkv<<<dim3(24, 12, 36), blk, 0, stream>>>(wqkv_a, Wq, Wk, Wv);
    k_convT64<<<dim3(24, 12, 12), blk, 0, stream>>>(wo_a, Wo, 768, 768);
    k_convT64_gh<<<dim3(96, 12, 24), blk, 0, stream>>>(wgh_a, gate_W, hidden_W);
    k_convT64<<<dim3(24, 48, 12), blk, 0, stream>>>(wfo_a, ffn_out_W, 3072, 768);
    k_cast<<<(MTOK * 768 / 4 + 255) / 256, blk, 0, stream>>>(emb, patch, MTOK * 768 / 4);
    k_box_sin<<<(MTOK * D_ + 255) / 256, blk, 0, stream>>>(emb, box);

    // embedding: h = [patch|box_sin] @ [patch_W; box_W] + (patch_b+box_b)
    k_gemm_bf16<0><<<dim3(6, 32), blk, 0, stream>>>(h, emb, wcat, bias_c, 1536, 768, 768);
    k_rmsnorm<<<MTOK, blk, 0, stream>>>(hn_bf, h, attn_norm_w);

    for (int ly = 0; ly < NL_; ++ly) {
        const u16* wqkv = wqkv_a + (size_t)ly * 2304 * 768;
        const u16* wo_l = wo_a   + (size_t)ly * 768 * 768;
        const u16* wgh  = wgh_a  + (size_t)ly * 6144 * 768;
        const u16* wfo  = wfo_a  + (size_t)ly * 768 * 3072;
        const float* fnw = ffn_norm_w + (size_t)ly * D_;
        const float* nxt = (ly + 1 < NL_) ? attn_norm_w + (size_t)(ly + 1) * D_
                                          : label_norm_w;

        // QKV GEMM with fused rope + head relayout + V transpose
        k_gemm_bf16<6><<<dim3(18, 32), blk, 0, stream>>>(qkvh, hn_bf, wqkv, tab, 768, 2304, 2304);
        k_attn3<<<dim3(96, 8), blk, 0, stream>>>(o_bf, qh, kh, vT);
        k_gemm_bf16<4><<<dim3(6, 32, 2), blk, 0, stream>>>(part, o_bf, wo_l, nullptr, 768, 768, 768);
        k_fused_rr<2><<<MTOK, blk, 0, stream>>>(h, part, hn_bf, fnw);

        k_gemm_bf16<5><<<dim3(48, 32), blk, 0, stream>>>(ga_bf, hn_bf, wgh, nullptr, 768, 6144, 3072);
        k_gemm_bf16<4><<<dim3(6, 32, 4), blk, 0, stream>>>(part, ga_bf, wfo, nullptr, 3072, 768, 768);
        k_fused_rr<4><<<MTOK, blk, 0, stream>>>(h, part, hn_bf, nxt);
    }

    // heads: hn_bf already = rmsnorm(h, label_norm_w)
    float* out_reward = (float*)d_out;
    float* out_label  = out_reward + (size_t)MTOK * 2;
    float* out_box    = out_label + (size_t)MTOK * 1000;

    k_gemm_bf16<0><<<dim3(8, 32), blk, 0, stream>>>(out_label, hn_bf, wlab, label_b, 768, 1000, 1000);
    k_heads3<<<MTOK, blk, 0, stream>>>(out_reward, out_box, h,
                                       reward_norm_w, reward_W, reward_b,
                                       box_norm_w, boxh_W, boxh_b);
}